// Round 3
// baseline (1150.392 us; speedup 1.0000x reference)
//
#include <hip/hip_runtime.h>
#include <hip/hip_bf16.h>
#include <math.h>

#define BATCH 16
#define L_SEQ 196
#define PATCH_DIM 768
#define D_MODEL 512
#define D_INNER 1024
#define D_STATE 16
#define D_CONV 4
#define DT_RANK 32
#define N_LAYERS 4
#define N_CLASSES 1000
#define ROWS (BATCH * L_SEQ)   // 3136
#define ROWSP 3200             // padded to multiple of 128

typedef __hip_bfloat16 bf16;
typedef __attribute__((ext_vector_type(8))) __bf16 bf16x8;
typedef __attribute__((ext_vector_type(4))) float f32x4;

__device__ __forceinline__ void gload_lds16(const void* g, void* l) {
    __builtin_amdgcn_global_load_lds((const __attribute__((address_space(1))) void*)g,
                                     (__attribute__((address_space(3))) void*)l, 16, 0, 0);
}

// ---------------------------------------------------------------------------
__global__ void posemb_kernel(float* __restrict__ pos) {
    int idx = blockIdx.x * 256 + threadIdx.x;
    if (idx >= L_SEQ * D_MODEL) return;
    int l = idx >> 9, col = idx & 511;
    int q = col >> 7, wi = col & 127;
    float omega = powf(10000.f, -(float)wi / 127.f);
    float yv = (float)(l / 14), xv = (float)(l % 14);
    float arg = (q < 2 ? xv : yv) * omega;
    pos[idx] = (q & 1) ? cosf(arg) : sinf(arg);
}

// patchify: x[B,224,224,3] -> p[3136,768] bf16
__global__ void patchify_kernel(const float* __restrict__ x, bf16* __restrict__ p) {
    int idx = blockIdx.x * 256 + threadIdx.x;
    if (idx >= ROWS * PATCH_DIM) return;
    int k = idx % PATCH_DIM, row = idx / PATCH_DIM;
    int b = row / L_SEQ, l = row % L_SEQ;
    int i = l / 14, j = l % 14;
    int ph = k / 48, r = k % 48, pw = r / 3, c = r % 3;
    size_t src = (((size_t)b * 224 + i * 16 + ph) * 224 + (j * 16 + pw)) * 3 + c;
    p[idx] = __float2bfloat16(x[src]);
}

// transpose-convert: src[K][N] f32 -> dst[Npad][K] bf16 (zero-fill n>=N), per-layer z
__global__ __launch_bounds__(256) void transpose_bf16_kernel(
    const float* __restrict__ src, bf16* __restrict__ dst,
    int K, int N, int Npad, size_t src_lstride, size_t dst_lstride)
{
    src += (size_t)blockIdx.z * src_lstride;
    dst += (size_t)blockIdx.z * dst_lstride;
    __shared__ float tile[32][33];
    int kb = blockIdx.y * 32, nb = blockIdx.x * 32;
    int tx = threadIdx.x & 31, ty = threadIdx.x >> 5;  // 32 x 8
    #pragma unroll
    for (int i = 0; i < 4; ++i) {
        int k = kb + ty + 8 * i, n = nb + tx;
        tile[ty + 8 * i][tx] = (k < K && n < N) ? src[(size_t)k * N + n] : 0.f;
    }
    __syncthreads();
    #pragma unroll
    for (int i = 0; i < 4; ++i) {
        int n = nb + ty + 8 * i, k = kb + tx;
        if (n < Npad && k < K) dst[(size_t)n * K + k] = __float2bfloat16(tile[tx][ty + 8 * i]);
    }
}

// ---------------------------------------------------------------------------
// bf16 MFMA GEMM, m97-structure: BM=BN=128, BK=32, 4 waves (2x2), 16x16x32 MFMA.
// MODE 0: Cb = bf16(acc); 1: Cf = acc; 2: Cf = acc+bias+pos; 3: Cf += acc
template<int MODE>
__global__ __launch_bounds__(256) void gemm_mfma(
    const bf16* __restrict__ A, const bf16* __restrict__ Wt,
    int K, int Nstore, int M, int ldc,
    float* __restrict__ Cf, bf16* __restrict__ Cb,
    const float* __restrict__ bias, const float* __restrict__ pos)
{
    __shared__ short Als[128 * 32];
    __shared__ short Bls[128 * 32];
    int tid = threadIdx.x;
    int lane = tid & 63, wid = tid >> 6;
    int wm = wid >> 1, wn = wid & 1;
    int bm = blockIdx.y * 128, bn = blockIdx.x * 128;

    f32x4 acc[4][4];
    #pragma unroll
    for (int i = 0; i < 4; ++i)
        #pragma unroll
        for (int j = 0; j < 4; ++j)
            acc[i][j] = (f32x4){0.f, 0.f, 0.f, 0.f};

    for (int k0 = 0; k0 < K; k0 += 32) {
        #pragma unroll
        for (int i = 0; i < 2; ++i) {
            int cbase = (i * 4 + wid) * 64;
            int c = cbase + lane;
            int row = c >> 2, kbp = c & 3;
            int kb = kbp ^ ((row >> 1) & 3);
            gload_lds16(A + (size_t)(bm + row) * K + k0 + kb * 8, Als + (size_t)cbase * 8);
            gload_lds16(Wt + (size_t)(bn + row) * K + k0 + kb * 8, Bls + (size_t)cbase * 8);
        }
        __syncthreads();
        bf16x8 af[4], bfr[4];
        #pragma unroll
        for (int mi = 0; mi < 4; ++mi) {
            int row = wm * 64 + mi * 16 + (lane & 15);
            int kbp = (lane >> 4) ^ ((row >> 1) & 3);
            af[mi] = *reinterpret_cast<const bf16x8*>(Als + row * 32 + kbp * 8);
        }
        #pragma unroll
        for (int nj = 0; nj < 4; ++nj) {
            int row = wn * 64 + nj * 16 + (lane & 15);
            int kbp = (lane >> 4) ^ ((row >> 1) & 3);
            bfr[nj] = *reinterpret_cast<const bf16x8*>(Bls + row * 32 + kbp * 8);
        }
        #pragma unroll
        for (int mi = 0; mi < 4; ++mi)
            #pragma unroll
            for (int nj = 0; nj < 4; ++nj)
                acc[mi][nj] = __builtin_amdgcn_mfma_f32_16x16x32_bf16(af[mi], bfr[nj], acc[mi][nj], 0, 0, 0);
        __syncthreads();
    }

    #pragma unroll
    for (int mi = 0; mi < 4; ++mi) {
        #pragma unroll
        for (int nj = 0; nj < 4; ++nj) {
            int r0 = bm + wm * 64 + mi * 16 + ((lane >> 4) << 2);
            int col = bn + wn * 64 + nj * 16 + (lane & 15);
            if (col >= Nstore) continue;
            #pragma unroll
            for (int j = 0; j < 4; ++j) {
                int row = r0 + j;
                if (row >= M) continue;
                float v = acc[mi][nj][j];
                size_t o = (size_t)row * ldc + col;
                if (MODE == 0) Cb[o] = __float2bfloat16(v);
                else if (MODE == 1) Cf[o] = v;
                else if (MODE == 2) Cf[o] = v + bias[col] + pos[(size_t)(row % L_SEQ) * D_MODEL + col];
                else Cf[o] += v;
            }
        }
    }
}

// ---------------------------------------------------------------------------
// f32 tiled GEMM (kept for head M=16).  mode 4: C = acc + bias[col]
__global__ __launch_bounds__(256) void gemm_tiled(
    const float* __restrict__ A, int lda,
    const float* __restrict__ W, int ldw,
    float* __restrict__ C, int ldc,
    int M, int N, int K, int mode,
    const float* __restrict__ bias)
{
    __shared__ float As[16][65];
    __shared__ float Bs[16][64];
    int bm = blockIdx.y * 64, bn = blockIdx.x * 64;
    int tid = threadIdx.x;
    int tx = tid & 15, ty = tid >> 4;
    float acc[4][4] = {};
    for (int k0 = 0; k0 < K; k0 += 16) {
        int ka = k0 + (tid & 15);
        #pragma unroll
        for (int mi = 0; mi < 4; ++mi) {
            int row = bm + mi * 16 + (tid >> 4);
            As[tid & 15][mi * 16 + (tid >> 4)] =
                (row < M && ka < K) ? A[(size_t)row * lda + ka] : 0.f;
        }
        int cb = bn + (tid & 63);
        #pragma unroll
        for (int ki = 0; ki < 4; ++ki) {
            int k = k0 + ki * 4 + (tid >> 6);
            Bs[ki * 4 + (tid >> 6)][tid & 63] =
                (k < K && cb < N) ? W[(size_t)k * ldw + cb] : 0.f;
        }
        __syncthreads();
        #pragma unroll
        for (int kk = 0; kk < 16; ++kk) {
            float a[4], b[4];
            #pragma unroll
            for (int i = 0; i < 4; ++i) a[i] = As[kk][ty + 16 * i];
            #pragma unroll
            for (int j = 0; j < 4; ++j) b[j] = Bs[kk][tx + 16 * j];
            #pragma unroll
            for (int i = 0; i < 4; ++i)
                #pragma unroll
                for (int j = 0; j < 4; ++j)
                    acc[i][j] += a[i] * b[j];
        }
        __syncthreads();
    }
    #pragma unroll
    for (int i = 0; i < 4; ++i) {
        int row = bm + ty + 16 * i;
        if (row >= M) continue;
        #pragma unroll
        for (int j = 0; j < 4; ++j) {
            int col = bn + tx + 16 * j;
            if (col >= N) continue;
            float v = acc[i][j];
            size_t o = (size_t)row * ldc + col;
            if (mode == 3) {
                float z = v + bias[col];
                C[o] = (z > 20.f) ? z : log1pf(__expf(z));
            } else {
                C[o] = v + bias[col];
            }
        }
    }
}

// ---------------------------------------------------------------------------
__global__ __launch_bounds__(256) void rmsnorm_kernel(
    const float* __restrict__ h, const float* __restrict__ w, bf16* __restrict__ o)
{
    int row = blockIdx.x;
    int tid = threadIdx.x;
    const float* hr = h + (size_t)row * D_MODEL;
    float v0 = hr[tid], v1 = hr[tid + 256];
    float ss = v0 * v0 + v1 * v1;
    #pragma unroll
    for (int off = 32; off; off >>= 1) ss += __shfl_down(ss, off);
    __shared__ float ls[4];
    __shared__ float scale_s;
    if ((tid & 63) == 0) ls[tid >> 6] = ss;
    __syncthreads();
    if (tid == 0) {
        float t = ls[0] + ls[1] + ls[2] + ls[3];
        scale_s = rsqrtf(t * (1.f / D_MODEL) + 1e-5f);
    }
    __syncthreads();
    float sc = scale_s;
    o[(size_t)row * D_MODEL + tid]       = __float2bfloat16(v0 * sc * w[tid]);
    o[(size_t)row * D_MODEL + tid + 256] = __float2bfloat16(v1 * sc * w[tid + 256]);
}

// causal depthwise conv (k=4) + SiLU.  xr: [3136,2048] bf16 (xi = first 1024)
__global__ void conv_silu_kernel(const bf16* __restrict__ xr,
                                 const float* __restrict__ cw,
                                 bf16* __restrict__ xs)
{
    int idx = blockIdx.x * 256 + threadIdx.x;
    if (idx >= ROWS * D_INNER) return;
    int d = idx & 1023, row = idx >> 10;
    int l = row % L_SEQ;
    const float* w4 = cw + d * 4;
    float acc = 0.f;
    #pragma unroll
    for (int k = 0; k < 4; ++k) {
        int ls = l - 3 + k;
        if (ls >= 0) acc += __bfloat162float(xr[(size_t)(row - 3 + k) * (2 * D_INNER) + d]) * w4[k];
    }
    float v = acc / (1.f + __expf(-acc));
    xs[idx] = __float2bfloat16(v);
}

// ---------------------------------------------------------------------------
// Fused dt_proj + softplus + selective scan + output gate.
// One block = (batch b, 64-channel group), 64 threads (1 wave), 1 channel each.
// xdbl rows staged in LDS in windows of 8 steps, double-buffered, prefetched
// one window ahead via registers; u/res streams prefetched 2 steps ahead.
__global__ __launch_bounds__(64) void scan_fused_kernel(
    const bf16*  __restrict__ xs,     // u    [rows,1024] bf16
    const float* __restrict__ xdbl,   //      [rows,64]   f32 (dt0:32 | B32:48 | C48:64)
    const float* __restrict__ dtw,    //      [32,1024]   layer slice
    const float* __restrict__ dtb,    //      [1024]
    const float* __restrict__ A_log,  //      [1024,16]
    const float* __restrict__ Dv,     //      [1024]
    const bf16*  __restrict__ xr,     // res  [rows,2048] (cols 1024..2047)
    bf16* __restrict__ y)             //      [rows,1024] bf16
{
    int tid = threadIdx.x;
    int b = blockIdx.x >> 4;
    int d = ((blockIdx.x & 15) << 6) | tid;
    size_t bbase = (size_t)b * L_SEQ;

    float A[16], s[16];
    #pragma unroll
    for (int n = 0; n < 16; ++n) { A[n] = -__expf(A_log[d * 16 + n]); s[n] = 0.f; }
    float Dd = Dv[d];
    float w32[32];
    #pragma unroll
    for (int r = 0; r < 32; ++r) w32[r] = dtw[r * D_INNER + d];
    float bia = dtb[d];

    __shared__ float buf[2][512];
    f32x4 vr0, vr1;
    const int NW = (L_SEQ + 7) / 8;   // 25 windows (xdbl padded to ROWSP rows)

    // window 0 -> regs -> LDS
    {
        const float* src = xdbl + (bbase + 0) * 64;
        vr0 = *reinterpret_cast<const f32x4*>(src + tid * 4);
        vr1 = *reinterpret_cast<const f32x4*>(src + 256 + tid * 4);
        *reinterpret_cast<f32x4*>(&buf[0][tid * 4]) = vr0;
        *reinterpret_cast<f32x4*>(&buf[0][256 + tid * 4]) = vr1;
        __syncthreads();
    }
    // window 1 -> regs (in flight during window 0 compute)
    {
        const float* src = xdbl + (bbase + 8) * 64;
        vr0 = *reinterpret_cast<const f32x4*>(src + tid * 4);
        vr1 = *reinterpret_cast<const f32x4*>(src + 256 + tid * 4);
    }

    float uA = __bfloat162float(xs[(bbase + 0) * D_INNER + d]);
    float rA = __bfloat162float(xr[(bbase + 0) * 2 * D_INNER + D_INNER + d]);
    float uB = __bfloat162float(xs[(bbase + 1) * D_INNER + d]);
    float rB = __bfloat162float(xr[(bbase + 1) * 2 * D_INNER + D_INNER + d]);

    for (int w = 0; w < NW; ++w) {
        const float* wb = buf[w & 1];
        int nst = min(8, L_SEQ - w * 8);
        for (int i = 0; i < nst; ++i) {
            int l = w * 8 + i;
            // prefetch u/res for l+2
            int lp = (l + 2 < L_SEQ) ? l + 2 : L_SEQ - 1;
            float uC = __bfloat162float(xs[(bbase + lp) * D_INNER + d]);
            float rC = __bfloat162float(xr[(bbase + lp) * 2 * D_INNER + D_INNER + d]);

            const float* row = wb + i * 64;
            float dot = bia;
            #pragma unroll
            for (int r = 0; r < 32; ++r) dot += row[r] * w32[r];
            float dl = (dot > 20.f) ? dot : log1pf(__expf(dot));
            float du = dl * uA;
            float acc = 0.f;
            #pragma unroll
            for (int n = 0; n < 16; ++n) {
                s[n] = __expf(dl * A[n]) * s[n] + du * row[32 + n];
                acc += s[n] * row[48 + n];
            }
            float g = rA / (1.f + __expf(-rA));
            y[(bbase + l) * D_INNER + d] = __float2bfloat16((acc + uA * Dd) * g);
            uA = uB; rA = rB; uB = uC; rB = rC;
        }
        if (w + 1 < NW) {
            __syncthreads();
            *reinterpret_cast<f32x4*>(&buf[(w + 1) & 1][tid * 4]) = vr0;
            *reinterpret_cast<f32x4*>(&buf[(w + 1) & 1][256 + tid * 4]) = vr1;
            __syncthreads();
            if (w + 2 < NW) {
                const float* src = xdbl + (bbase + (size_t)(w + 2) * 8) * 64;
                vr0 = *reinterpret_cast<const f32x4*>(src + tid * 4);
                vr1 = *reinterpret_cast<const f32x4*>(src + 256 + tid * 4);
            }
        }
    }
}

// mean over sequence: h[16,196,512] f32 -> hm[16,512] f32
__global__ __launch_bounds__(256) void mean_kernel(const float* __restrict__ h,
                                                   float* __restrict__ hm) {
    int b = blockIdx.x, tid = threadIdx.x;
    for (int c = tid; c < D_MODEL; c += 256) {
        float acc = 0.f;
        for (int l = 0; l < L_SEQ; ++l)
            acc += h[((size_t)b * L_SEQ + l) * D_MODEL + c];
        hm[b * D_MODEL + c] = acc * (1.f / L_SEQ);
    }
}

// ---------------------------------------------------------------------------
extern "C" void kernel_launch(void* const* d_in, const int* in_sizes, int n_in,
                              void* d_out, int out_size, void* d_ws, size_t ws_size,
                              hipStream_t stream) {
    const float* x         = (const float*)d_in[0];
    const float* patch_w   = (const float*)d_in[1];
    const float* patch_b   = (const float*)d_in[2];
    const float* norm_w    = (const float*)d_in[3];
    const float* in_proj_w = (const float*)d_in[4];
    const float* conv_w    = (const float*)d_in[5];
    const float* x_proj_w  = (const float*)d_in[6];
    const float* dt_proj_w = (const float*)d_in[7];
    const float* dt_proj_b = (const float*)d_in[8];
    const float* A_log     = (const float*)d_in[9];
    const float* Dv        = (const float*)d_in[10];
    const float* out_proj_w= (const float*)d_in[11];
    const float* head_w    = (const float*)d_in[12];
    const float* head_b    = (const float*)d_in[13];
    float* out = (float*)d_out;

    char* base = (char*)d_ws;
    size_t off = 0;
    auto alloc = [&](size_t bytes) -> void* {
        void* p = base + off;
        off += (bytes + 255) & ~(size_t)255;
        return p;
    };
    float* pos   = (float*)alloc((size_t)L_SEQ * D_MODEL * 4);
    bf16*  p     = (bf16*) alloc((size_t)ROWSP * PATCH_DIM * 2);
    bf16*  pwT   = (bf16*) alloc((size_t)D_MODEL * PATCH_DIM * 2);
    bf16*  inT   = (bf16*) alloc((size_t)N_LAYERS * 2 * D_INNER * D_MODEL * 2);
    bf16*  xpT   = (bf16*) alloc((size_t)N_LAYERS * 128 * D_INNER * 2);
    bf16*  opT   = (bf16*) alloc((size_t)N_LAYERS * D_MODEL * D_INNER * 2);
    float* h     = (float*)alloc((size_t)ROWS * D_MODEL * 4);
    bf16*  xn    = (bf16*) alloc((size_t)ROWSP * D_MODEL * 2);
    bf16*  xr    = (bf16*) alloc((size_t)ROWSP * 2 * D_INNER * 2);
    bf16*  xs    = (bf16*) alloc((size_t)ROWSP * D_INNER * 2);
    float* xdbl  = (float*)alloc((size_t)ROWSP * 64 * 4);
    bf16*  yb    = (bf16*) alloc((size_t)ROWSP * D_INNER * 2);
    float* hm    = (float*)alloc((size_t)BATCH * D_MODEL * 4);

    posemb_kernel<<<(L_SEQ * D_MODEL + 255) / 256, 256, 0, stream>>>(pos);
    patchify_kernel<<<(ROWS * PATCH_DIM + 255) / 256, 256, 0, stream>>>(x, p);

    // weight prep: f32 [K][N] -> bf16 [Npad][K]
    transpose_bf16_kernel<<<dim3(16, 24, 1), 256, 0, stream>>>(
        patch_w, pwT, PATCH_DIM, D_MODEL, D_MODEL, 0, 0);
    transpose_bf16_kernel<<<dim3(64, 16, N_LAYERS), 256, 0, stream>>>(
        in_proj_w, inT, D_MODEL, 2 * D_INNER, 2 * D_INNER,
        (size_t)D_MODEL * 2 * D_INNER, (size_t)2 * D_INNER * D_MODEL);
    transpose_bf16_kernel<<<dim3(4, 32, N_LAYERS), 256, 0, stream>>>(
        x_proj_w, xpT, D_INNER, 64, 128,
        (size_t)D_INNER * 64, (size_t)128 * D_INNER);
    transpose_bf16_kernel<<<dim3(16, 32, N_LAYERS), 256, 0, stream>>>(
        out_proj_w, opT, D_INNER, D_MODEL, D_MODEL,
        (size_t)D_INNER * D_MODEL, (size_t)D_MODEL * D_INNER);

    // h = p @ patch_w + patch_b + pos
    gemm_mfma<2><<<dim3(D_MODEL / 128, ROWSP / 128), 256, 0, stream>>>(
        p, pwT, PATCH_DIM, D_MODEL, ROWS, D_MODEL, h, nullptr, patch_b, pos);

    for (int layer = 0; layer < N_LAYERS; ++layer) {
        rmsnorm_kernel<<<ROWS, 256, 0, stream>>>(h, norm_w + layer * D_MODEL, xn);

        // xr = xn @ in_proj  [3136,2048] bf16
        gemm_mfma<0><<<dim3(2 * D_INNER / 128, ROWSP / 128), 256, 0, stream>>>(
            xn, inT + (size_t)layer * 2 * D_INNER * D_MODEL,
            D_MODEL, 2 * D_INNER, ROWS, 2 * D_INNER, nullptr, xr, nullptr, nullptr);

        conv_silu_kernel<<<(ROWS * D_INNER) / 256, 256, 0, stream>>>(
            xr, conv_w + (size_t)layer * D_INNER * D_CONV, xs);

        // xdbl = xs @ x_proj  [3136,64] f32 (N padded to 128, stores guarded)
        gemm_mfma<1><<<dim3(1, ROWSP / 128), 256, 0, stream>>>(
            xs, xpT + (size_t)layer * 128 * D_INNER,
            D_INNER, 64, ROWS, 64, xdbl, nullptr, nullptr, nullptr);

        // fused dt_proj + softplus + scan + gate -> yb bf16
        scan_fused_kernel<<<BATCH * (D_INNER / 64), 64, 0, stream>>>(
            xs, xdbl,
            dt_proj_w + (size_t)layer * DT_RANK * D_INNER,
            dt_proj_b + (size_t)layer * D_INNER,
            A_log + (size_t)layer * D_INNER * D_STATE,
            Dv + (size_t)layer * D_INNER, xr, yb);

        // h += yb @ out_proj
        gemm_mfma<3><<<dim3(D_MODEL / 128, ROWSP / 128), 256, 0, stream>>>(
            yb, opT + (size_t)layer * D_MODEL * D_INNER,
            D_INNER, D_MODEL, ROWS, D_MODEL, h, nullptr, nullptr, nullptr);
    }

    mean_kernel<<<BATCH, 256, 0, stream>>>(h, hm);

    // out = hm @ head_w + head_b   [16,1000]
    gemm_tiled<<<dim3((N_CLASSES + 63) / 64, 1), 256, 0, stream>>>(
        hm, D_MODEL, head_w, N_CLASSES, out, N_CLASSES,
        BATCH, N_CLASSES, D_MODEL, 4, head_b);
}

// Round 4
// 1036.189 us; speedup vs baseline: 1.1102x; 1.1102x over previous
//
#include <hip/hip_runtime.h>
#include <hip/hip_bf16.h>
#include <math.h>

#define BATCH 16
#define L_SEQ 196
#define PATCH_DIM 768
#define D_MODEL 512
#define D_INNER 1024
#define D_STATE 16
#define D_CONV 4
#define DT_RANK 32
#define N_LAYERS 4
#define N_CLASSES 1000
#define ROWS (BATCH * L_SEQ)   // 3136
#define ROWSP 3200             // padded to multiple of 128
#define NBIG 1152              // delta(1024) + bc(32), padded to 128

typedef __hip_bfloat16 bf16;
typedef __attribute__((ext_vector_type(8))) __bf16 bf16x8;
typedef __attribute__((ext_vector_type(4))) float f32x4;
typedef __attribute__((ext_vector_type(2))) float f32x2;

__device__ __forceinline__ void gload_lds16(const void* g, void* l) {
    __builtin_amdgcn_global_load_lds((const __attribute__((address_space(1))) void*)g,
                                     (__attribute__((address_space(3))) void*)l, 16, 0, 0);
}

// ---------------------------------------------------------------------------
__global__ void posemb_kernel(float* __restrict__ pos) {
    int idx = blockIdx.x * 256 + threadIdx.x;
    if (idx >= L_SEQ * D_MODEL) return;
    int l = idx >> 9, col = idx & 511;
    int q = col >> 7, wi = col & 127;
    float omega = powf(10000.f, -(float)wi / 127.f);
    float yv = (float)(l / 14), xv = (float)(l % 14);
    float arg = (q < 2 ? xv : yv) * omega;
    pos[idx] = (q & 1) ? cosf(arg) : sinf(arg);
}

// patchify: x[B,224,224,3] -> p[3136,768] bf16
__global__ void patchify_kernel(const float* __restrict__ x, bf16* __restrict__ p) {
    int idx = blockIdx.x * 256 + threadIdx.x;
    if (idx >= ROWS * PATCH_DIM) return;
    int k = idx % PATCH_DIM, row = idx / PATCH_DIM;
    int b = row / L_SEQ, l = row % L_SEQ;
    int i = l / 14, j = l % 14;
    int ph = k / 48, r = k % 48, pw = r / 3, c = r % 3;
    size_t src = (((size_t)b * 224 + i * 16 + ph) * 224 + (j * 16 + pw)) * 3 + c;
    p[idx] = __float2bfloat16(x[src]);
}

// transpose-convert: src[K][N] f32 -> dst[Npad][K] bf16 (zero-fill n>=N)
__global__ __launch_bounds__(256) void transpose_bf16_kernel(
    const float* __restrict__ src, bf16* __restrict__ dst,
    int K, int N, int Npad)
{
    __shared__ float tile[32][33];
    int kb = blockIdx.y * 32, nb = blockIdx.x * 32;
    int tx = threadIdx.x & 31, ty = threadIdx.x >> 5;  // 32 x 8
    #pragma unroll
    for (int i = 0; i < 4; ++i) {
        int k = kb + ty + 8 * i, n = nb + tx;
        tile[ty + 8 * i][tx] = (k < K && n < N) ? src[(size_t)k * N + n] : 0.f;
    }
    __syncthreads();
    #pragma unroll
    for (int i = 0; i < 4; ++i) {
        int n = nb + ty + 8 * i, k = kb + tx;
        if (n < Npad && k < K) dst[(size_t)n * K + k] = __float2bfloat16(tile[tx][ty + 8 * i]);
    }
}

// fill WtBig rows 1024..1055 with interleaved B/C columns of x_proj_w^T:
// row 1024+j, col k = xpw[k][ (j&1) ? 48+(j>>1) : 32+(j>>1) ]
__global__ void bcw_kernel(const float* __restrict__ xpw, bf16* __restrict__ WtBig) {
    int idx = blockIdx.x * 256 + threadIdx.x;
    if (idx >= 32 * 1024) return;
    int j = idx >> 10, k = idx & 1023;
    int src = (j & 1) ? 48 + (j >> 1) : 32 + (j >> 1);
    WtBig[(size_t)(1024 + j) * 1024 + k] = __float2bfloat16(xpw[k * 64 + src]);
}

// ---------------------------------------------------------------------------
// bf16 MFMA GEMM, m97-structure: BM=BN=128, BK=32, 4 waves (2x2), 16x16x32 MFMA.
// MODE 0: Cb = bf16(acc); 1: Cf = acc; 2: Cf = acc+bias+pos; 3: Cf += acc
// MODE 4: col<1024 -> Cf[row*1024+col] = softplus(acc + bias[col])   (delta)
//         1024<=col<1056 -> Cf2[row*32 + col-1024] = acc             (bc)
template<int MODE>
__global__ __launch_bounds__(256) void gemm_mfma(
    const bf16* __restrict__ A, const bf16* __restrict__ Wt,
    int K, int Nstore, int M, int ldc,
    float* __restrict__ Cf, bf16* __restrict__ Cb,
    const float* __restrict__ bias, const float* __restrict__ pos,
    float* __restrict__ Cf2)
{
    __shared__ short Als[128 * 32];
    __shared__ short Bls[128 * 32];
    int tid = threadIdx.x;
    int lane = tid & 63, wid = tid >> 6;
    int wm = wid >> 1, wn = wid & 1;
    int bm = blockIdx.y * 128, bn = blockIdx.x * 128;

    f32x4 acc[4][4];
    #pragma unroll
    for (int i = 0; i < 4; ++i)
        #pragma unroll
        for (int j = 0; j < 4; ++j)
            acc[i][j] = (f32x4){0.f, 0.f, 0.f, 0.f};

    for (int k0 = 0; k0 < K; k0 += 32) {
        #pragma unroll
        for (int i = 0; i < 2; ++i) {
            int cbase = (i * 4 + wid) * 64;
            int c = cbase + lane;
            int row = c >> 2, kbp = c & 3;
            int kb = kbp ^ ((row >> 1) & 3);
            gload_lds16(A + (size_t)(bm + row) * K + k0 + kb * 8, Als + (size_t)cbase * 8);
            gload_lds16(Wt + (size_t)(bn + row) * K + k0 + kb * 8, Bls + (size_t)cbase * 8);
        }
        __syncthreads();
        bf16x8 af[4], bfr[4];
        #pragma unroll
        for (int mi = 0; mi < 4; ++mi) {
            int row = wm * 64 + mi * 16 + (lane & 15);
            int kbp = (lane >> 4) ^ ((row >> 1) & 3);
            af[mi] = *reinterpret_cast<const bf16x8*>(Als + row * 32 + kbp * 8);
        }
        #pragma unroll
        for (int nj = 0; nj < 4; ++nj) {
            int row = wn * 64 + nj * 16 + (lane & 15);
            int kbp = (lane >> 4) ^ ((row >> 1) & 3);
            bfr[nj] = *reinterpret_cast<const bf16x8*>(Bls + row * 32 + kbp * 8);
        }
        #pragma unroll
        for (int mi = 0; mi < 4; ++mi)
            #pragma unroll
            for (int nj = 0; nj < 4; ++nj)
                acc[mi][nj] = __builtin_amdgcn_mfma_f32_16x16x32_bf16(af[mi], bfr[nj], acc[mi][nj], 0, 0, 0);
        __syncthreads();
    }

    #pragma unroll
    for (int mi = 0; mi < 4; ++mi) {
        #pragma unroll
        for (int nj = 0; nj < 4; ++nj) {
            int r0 = bm + wm * 64 + mi * 16 + ((lane >> 4) << 2);
            int col = bn + wn * 64 + nj * 16 + (lane & 15);
            if (col >= Nstore) continue;
            #pragma unroll
            for (int j = 0; j < 4; ++j) {
                int row = r0 + j;
                if (row >= M) continue;
                float v = acc[mi][nj][j];
                if (MODE == 4) {
                    if (col < 1024) {
                        float z = v + bias[col];
                        Cf[(size_t)row * 1024 + col] = (z > 20.f) ? z : log1pf(__expf(z));
                    } else {
                        Cf2[(size_t)row * 32 + (col - 1024)] = v;
                    }
                } else {
                    size_t o = (size_t)row * ldc + col;
                    if (MODE == 0) Cb[o] = __float2bfloat16(v);
                    else if (MODE == 1) Cf[o] = v;
                    else if (MODE == 2) Cf[o] = v + bias[col] + pos[(size_t)(row % L_SEQ) * D_MODEL + col];
                    else Cf[o] += v;
                }
            }
        }
    }
}

// ---------------------------------------------------------------------------
// f32 tiled GEMM.  mode 0: C=acc; mode 4: C = acc + bias[col]
__global__ __launch_bounds__(256) void gemm_tiled(
    const float* __restrict__ A, int lda,
    const float* __restrict__ W, int ldw,
    float* __restrict__ C, int ldc,
    int M, int N, int K, int mode,
    const float* __restrict__ bias)
{
    __shared__ float As[16][65];
    __shared__ float Bs[16][64];
    int bm = blockIdx.y * 64, bn = blockIdx.x * 64;
    int tid = threadIdx.x;
    int tx = tid & 15, ty = tid >> 4;
    float acc[4][4] = {};
    for (int k0 = 0; k0 < K; k0 += 16) {
        int ka = k0 + (tid & 15);
        #pragma unroll
        for (int mi = 0; mi < 4; ++mi) {
            int row = bm + mi * 16 + (tid >> 4);
            As[tid & 15][mi * 16 + (tid >> 4)] =
                (row < M && ka < K) ? A[(size_t)row * lda + ka] : 0.f;
        }
        int cb = bn + (tid & 63);
        #pragma unroll
        for (int ki = 0; ki < 4; ++ki) {
            int k = k0 + ki * 4 + (tid >> 6);
            Bs[ki * 4 + (tid >> 6)][tid & 63] =
                (k < K && cb < N) ? W[(size_t)k * ldw + cb] : 0.f;
        }
        __syncthreads();
        #pragma unroll
        for (int kk = 0; kk < 16; ++kk) {
            float a[4], b[4];
            #pragma unroll
            for (int i = 0; i < 4; ++i) a[i] = As[kk][ty + 16 * i];
            #pragma unroll
            for (int j = 0; j < 4; ++j) b[j] = Bs[kk][tx + 16 * j];
            #pragma unroll
            for (int i = 0; i < 4; ++i)
                #pragma unroll
                for (int j = 0; j < 4; ++j)
                    acc[i][j] += a[i] * b[j];
        }
        __syncthreads();
    }
    #pragma unroll
    for (int i = 0; i < 4; ++i) {
        int row = bm + ty + 16 * i;
        if (row >= M) continue;
        #pragma unroll
        for (int j = 0; j < 4; ++j) {
            int col = bn + tx + 16 * j;
            if (col >= N) continue;
            float v = acc[i][j];
            size_t o = (size_t)row * ldc + col;
            if (mode == 0) C[o] = v;
            else C[o] = v + bias[col];
        }
    }
}

// ---------------------------------------------------------------------------
__global__ __launch_bounds__(256) void rmsnorm_kernel(
    const float* __restrict__ h, const float* __restrict__ w, bf16* __restrict__ o)
{
    int row = blockIdx.x;
    int tid = threadIdx.x;
    const float* hr = h + (size_t)row * D_MODEL;
    float v0 = hr[tid], v1 = hr[tid + 256];
    float ss = v0 * v0 + v1 * v1;
    #pragma unroll
    for (int off = 32; off; off >>= 1) ss += __shfl_down(ss, off);
    __shared__ float ls[4];
    __shared__ float scale_s;
    if ((tid & 63) == 0) ls[tid >> 6] = ss;
    __syncthreads();
    if (tid == 0) {
        float t = ls[0] + ls[1] + ls[2] + ls[3];
        scale_s = rsqrtf(t * (1.f / D_MODEL) + 1e-5f);
    }
    __syncthreads();
    float sc = scale_s;
    o[(size_t)row * D_MODEL + tid]       = __float2bfloat16(v0 * sc * w[tid]);
    o[(size_t)row * D_MODEL + tid + 256] = __float2bfloat16(v1 * sc * w[tid + 256]);
}

// causal depthwise conv (k=4) + SiLU.  xr: [3136,2048] bf16 (xi = first 1024)
__global__ void conv_silu_kernel(const bf16* __restrict__ xr,
                                 const float* __restrict__ cw,
                                 bf16* __restrict__ xs)
{
    int idx = blockIdx.x * 256 + threadIdx.x;
    if (idx >= ROWS * D_INNER) return;
    int d = idx & 1023, row = idx >> 10;
    int l = row % L_SEQ;
    const float* w4 = cw + d * 4;
    float acc = 0.f;
    #pragma unroll
    for (int k = 0; k < 4; ++k) {
        int ls = l - 3 + k;
        if (ls >= 0) acc += __bfloat162float(xr[(size_t)(row - 3 + k) * (2 * D_INNER) + d]) * w4[k];
    }
    float v = acc / (1.f + __expf(-acc));
    xs[idx] = __float2bfloat16(v);
}

// ---------------------------------------------------------------------------
// State-parallel selective scan + output gate.
// Block = 256 threads = 16 channels x 16 lanes (lane owns one SSM state n).
// Grid = BATCH * (D_INNER/16) = 1024 blocks -> 16 waves/CU.
// Recurrence chain per step = 1 FMA; C-dot via 4x shfl_xor dangles off it.
// Depth-4 register pipeline, all statically indexed.
__global__ __launch_bounds__(256) void scan_sp_kernel(
    const bf16*  __restrict__ xs,     // u     [rows,1024] bf16
    const float* __restrict__ delta,  //       [rows,1024] f32
    const float* __restrict__ bc,     //       [rows,32]   f32 interleaved {B[n],C[n]}
    const float* __restrict__ A_log,  //       [1024,16]
    const float* __restrict__ Dv,     //       [1024]
    const bf16*  __restrict__ xr,     // res   [rows,2048] (cols 1024..2047)
    bf16* __restrict__ y)             //       [rows,1024] bf16
{
    int tid = threadIdx.x;
    int n = tid & 15, ch = tid >> 4;
    int b = blockIdx.x >> 6;
    int d = (((int)blockIdx.x & 63) << 4) | ch;
    size_t bbase = (size_t)b * L_SEQ;

    float A = -__expf(A_log[d * 16 + n]);
    float Dd = Dv[d];
    float s = 0.f;

    float dlv[4], uv[4], rv[4];
    f32x2 bcv[4];

#define LOADSLOT(i, l) { size_t _r = bbase + (l); \
    dlv[i] = delta[_r * 1024 + d]; \
    uv[i]  = __bfloat162float(xs[_r * 1024 + d]); \
    rv[i]  = __bfloat162float(xr[_r * 2048 + 1024 + d]); \
    bcv[i] = *reinterpret_cast<const f32x2*>(bc + _r * 32 + 2 * n); }

#define STEP(i, l) { \
    float _a  = __expf(dlv[i] * A); \
    float _du = dlv[i] * uv[i]; \
    s = _a * s + _du * bcv[i].x; \
    float _p = s * bcv[i].y; \
    _p += __shfl_xor(_p, 1); _p += __shfl_xor(_p, 2); \
    _p += __shfl_xor(_p, 4); _p += __shfl_xor(_p, 8); \
    if (n == 0) { \
        float _rr = rv[i]; \
        float _g = _rr / (1.f + __expf(-_rr)); \
        y[(bbase + (l)) * 1024 + d] = __float2bfloat16((_p + uv[i] * Dd) * _g); \
    } }

    LOADSLOT(0, 0) LOADSLOT(1, 1) LOADSLOT(2, 2) LOADSLOT(3, 3)
    for (int g = 0; g < 48; ++g) {
        int l = g * 4;
        STEP(0, l)     LOADSLOT(0, l + 4)
        STEP(1, l + 1) LOADSLOT(1, l + 5)
        STEP(2, l + 2) LOADSLOT(2, l + 6)
        STEP(3, l + 3) LOADSLOT(3, l + 7)
    }
    STEP(0, 192) STEP(1, 193) STEP(2, 194) STEP(3, 195)
#undef LOADSLOT
#undef STEP
}

// mean over sequence: h[16,196,512] f32 -> hm[16,512] f32
__global__ __launch_bounds__(256) void mean_kernel(const float* __restrict__ h,
                                                   float* __restrict__ hm) {
    int b = blockIdx.x, tid = threadIdx.x;
    for (int c = tid; c < D_MODEL; c += 256) {
        float acc = 0.f;
        for (int l = 0; l < L_SEQ; ++l)
            acc += h[((size_t)b * L_SEQ + l) * D_MODEL + c];
        hm[b * D_MODEL + c] = acc * (1.f / L_SEQ);
    }
}

// ---------------------------------------------------------------------------
extern "C" void kernel_launch(void* const* d_in, const int* in_sizes, int n_in,
                              void* d_out, int out_size, void* d_ws, size_t ws_size,
                              hipStream_t stream) {
    const float* x         = (const float*)d_in[0];
    const float* patch_w   = (const float*)d_in[1];
    const float* patch_b   = (const float*)d_in[2];
    const float* norm_w    = (const float*)d_in[3];
    const float* in_proj_w = (const float*)d_in[4];
    const float* conv_w    = (const float*)d_in[5];
    const float* x_proj_w  = (const float*)d_in[6];
    const float* dt_proj_w = (const float*)d_in[7];
    const float* dt_proj_b = (const float*)d_in[8];
    const float* A_log     = (const float*)d_in[9];
    const float* Dv        = (const float*)d_in[10];
    const float* out_proj_w= (const float*)d_in[11];
    const float* head_w    = (const float*)d_in[12];
    const float* head_b    = (const float*)d_in[13];
    float* out = (float*)d_out;

    char* base = (char*)d_ws;
    size_t off = 0;
    auto alloc = [&](size_t bytes) -> void* {
        void* p = base + off;
        off += (bytes + 255) & ~(size_t)255;
        return p;
    };
    float* pos   = (float*)alloc((size_t)L_SEQ * D_MODEL * 4);
    bf16*  pwT   = (bf16*) alloc((size_t)D_MODEL * PATCH_DIM * 2);
    bf16*  inT1  = (bf16*) alloc((size_t)2 * D_INNER * D_MODEL * 2);     // per-layer
    bf16*  WtBig = (bf16*) alloc((size_t)NBIG * D_INNER * 2);            // per-layer
    bf16*  opT1  = (bf16*) alloc((size_t)D_MODEL * D_INNER * 2);         // per-layer
    float* h     = (float*)alloc((size_t)ROWS * D_MODEL * 4);
    bf16*  xn    = (bf16*) alloc((size_t)ROWSP * D_MODEL * 2);
    // region shared by patch matrix p (prologue) and xr (layer loop)
    char*  reg0  = (char*) alloc((size_t)ROWSP * 2 * D_INNER * 2);
    bf16*  p     = (bf16*)reg0;
    bf16*  xr    = (bf16*)reg0;
    bf16*  xs    = (bf16*) alloc((size_t)ROWSP * D_INNER * 2);
    float* delta = (float*)alloc((size_t)ROWS * D_INNER * 4);
    float* bcb   = (float*)alloc((size_t)ROWS * 32 * 4);
    // yb region also hosts WcombS f32 scratch (prep phase of each layer,
    // consumed by transpose before scan writes yb)
    char*  reg1  = (char*) alloc((size_t)ROWSP * D_INNER * 2);
    bf16*  yb    = (bf16*)reg1;
    float* WcombS= (float*)reg1;
    float* hm    = (float*)alloc((size_t)BATCH * D_MODEL * 4);

    posemb_kernel<<<(L_SEQ * D_MODEL + 255) / 256, 256, 0, stream>>>(pos);
    patchify_kernel<<<(ROWS * PATCH_DIM + 255) / 256, 256, 0, stream>>>(x, p);
    transpose_bf16_kernel<<<dim3(16, 24), 256, 0, stream>>>(patch_w, pwT, PATCH_DIM, D_MODEL, D_MODEL);

    // h = p @ patch_w + patch_b + pos
    gemm_mfma<2><<<dim3(D_MODEL / 128, ROWSP / 128), 256, 0, stream>>>(
        p, pwT, PATCH_DIM, D_MODEL, ROWS, D_MODEL, h, nullptr, patch_b, pos, nullptr);

    for (int layer = 0; layer < N_LAYERS; ++layer) {
        const float* xpw = x_proj_w + (size_t)layer * D_INNER * 64;
        const float* dtw = dt_proj_w + (size_t)layer * DT_RANK * D_INNER;

        // ---- per-layer weight prep ----
        transpose_bf16_kernel<<<dim3(64, 16), 256, 0, stream>>>(
            in_proj_w + (size_t)layer * D_MODEL * 2 * D_INNER, inT1, D_MODEL, 2 * D_INNER, 2 * D_INNER);
        // W_comb = xpw[:, :32] @ dtw   [1024,1024] f32
        gemm_tiled<<<dim3(16, 16), 256, 0, stream>>>(
            xpw, 64, dtw, D_INNER, WcombS, D_INNER, D_INNER, D_INNER, DT_RANK, 0, nullptr);
        transpose_bf16_kernel<<<dim3(32, 32), 256, 0, stream>>>(
            WcombS, WtBig, D_INNER, D_INNER, D_INNER);
        bcw_kernel<<<128, 256, 0, stream>>>(xpw, WtBig);
        transpose_bf16_kernel<<<dim3(16, 32), 256, 0, stream>>>(
            out_proj_w + (size_t)layer * D_INNER * D_MODEL, opT1, D_INNER, D_MODEL, D_MODEL);

        // ---- compute ----
        rmsnorm_kernel<<<ROWS, 256, 0, stream>>>(h, norm_w + layer * D_MODEL, xn);

        // xr = xn @ in_proj  [3136,2048] bf16
        gemm_mfma<0><<<dim3(2 * D_INNER / 128, ROWSP / 128), 256, 0, stream>>>(
            xn, inT1, D_MODEL, 2 * D_INNER, ROWS, 2 * D_INNER, nullptr, xr, nullptr, nullptr, nullptr);

        conv_silu_kernel<<<(ROWS * D_INNER) / 256, 256, 0, stream>>>(
            xr, conv_w + (size_t)layer * D_INNER * D_CONV, xs);

        // delta = softplus(xs @ W_comb + dtb); bc = xs @ xpw[:,32:64] interleaved
        gemm_mfma<4><<<dim3(NBIG / 128, ROWSP / 128), 256, 0, stream>>>(
            xs, WtBig, D_INNER, 1056, ROWS, 0, delta, nullptr,
            dt_proj_b + (size_t)layer * D_INNER, nullptr, bcb);

        // state-parallel scan + gate -> yb bf16
        scan_sp_kernel<<<BATCH * (D_INNER / 16), 256, 0, stream>>>(
            xs, delta, bcb,
            A_log + (size_t)layer * D_INNER * D_STATE,
            Dv + (size_t)layer * D_INNER, xr, yb);

        // h += yb @ out_proj
        gemm_mfma<3><<<dim3(D_MODEL / 128, ROWSP / 128), 256, 0, stream>>>(
            yb, opT1, D_INNER, D_MODEL, ROWS, D_MODEL, h, nullptr, nullptr, nullptr, nullptr);
    }

    mean_kernel<<<BATCH, 256, 0, stream>>>(h, hm);

    // out = hm @ head_w + head_b   [16,1000]
    gemm_tiled<<<dim3((N_CLASSES + 63) / 64, 1), 256, 0, stream>>>(
        hm, D_MODEL, head_w, N_CLASSES, out, N_CLASSES,
        BATCH, N_CLASSES, D_MODEL, 4, head_b);
}

// Round 5
// 924.677 us; speedup vs baseline: 1.2441x; 1.1206x over previous
//
#include <hip/hip_runtime.h>
#include <hip/hip_bf16.h>
#include <math.h>

#define BATCH 16
#define L_SEQ 196
#define PATCH_DIM 768
#define D_MODEL 512
#define D_INNER 1024
#define D_STATE 16
#define D_CONV 4
#define DT_RANK 32
#define N_LAYERS 4
#define N_CLASSES 1000
#define ROWS (BATCH * L_SEQ)   // 3136
#define ROWSP 3200             // padded to multiple of 128
#define NBIG 1152              // delta(1024) + bc(32), padded to 128

typedef __hip_bfloat16 bf16;
typedef __attribute__((ext_vector_type(8))) __bf16 bf16x8;
typedef __attribute__((ext_vector_type(4))) float f32x4;
typedef __attribute__((ext_vector_type(2))) float f32x2;

__device__ __forceinline__ void gload_lds16(const void* g, void* l) {
    __builtin_amdgcn_global_load_lds((const __attribute__((address_space(1))) void*)g,
                                     (__attribute__((address_space(3))) void*)l, 16, 0, 0);
}

// ---------------------------------------------------------------------------
__global__ void posemb_kernel(float* __restrict__ pos) {
    int idx = blockIdx.x * 256 + threadIdx.x;
    if (idx >= L_SEQ * D_MODEL) return;
    int l = idx >> 9, col = idx & 511;
    int q = col >> 7, wi = col & 127;
    float omega = powf(10000.f, -(float)wi / 127.f);
    float yv = (float)(l / 14), xv = (float)(l % 14);
    float arg = (q < 2 ? xv : yv) * omega;
    pos[idx] = (q & 1) ? cosf(arg) : sinf(arg);
}

// patchify: x[B,224,224,3] -> p[3136,768] bf16
__global__ void patchify_kernel(const float* __restrict__ x, bf16* __restrict__ p) {
    int idx = blockIdx.x * 256 + threadIdx.x;
    if (idx >= ROWS * PATCH_DIM) return;
    int k = idx % PATCH_DIM, row = idx / PATCH_DIM;
    int b = row / L_SEQ, l = row % L_SEQ;
    int i = l / 14, j = l % 14;
    int ph = k / 48, r = k % 48, pw = r / 3, c = r % 3;
    size_t src = (((size_t)b * 224 + i * 16 + ph) * 224 + (j * 16 + pw)) * 3 + c;
    p[idx] = __float2bfloat16(x[src]);
}

// transpose-convert: src[K][N] f32 -> dst[Npad][K] bf16 (zero-fill), z = layer
__global__ __launch_bounds__(256) void transpose_bf16_kernel(
    const float* __restrict__ src, bf16* __restrict__ dst,
    int K, int N, int Npad, size_t src_lstride, size_t dst_lstride)
{
    src += (size_t)blockIdx.z * src_lstride;
    dst += (size_t)blockIdx.z * dst_lstride;
    __shared__ float tile[32][33];
    int kb = blockIdx.y * 32, nb = blockIdx.x * 32;
    int tx = threadIdx.x & 31, ty = threadIdx.x >> 5;  // 32 x 8
    #pragma unroll
    for (int i = 0; i < 4; ++i) {
        int k = kb + ty + 8 * i, n = nb + tx;
        tile[ty + 8 * i][tx] = (k < K && n < N) ? src[(size_t)k * N + n] : 0.f;
    }
    __syncthreads();
    #pragma unroll
    for (int i = 0; i < 4; ++i) {
        int n = nb + ty + 8 * i, k = kb + tx;
        if (n < Npad && k < K) dst[(size_t)n * K + k] = __float2bfloat16(tile[tx][ty + 8 * i]);
    }
}

// W_comb^T directly in bf16: Wt[z][n][k] = sum_{r<32} dtw_z[r][n] * xpw_z[k][r]
// 16x16 output tile per block, LDS-staged operands.
__global__ __launch_bounds__(256) void wcomb_kernel(
    const float* __restrict__ xpw_all,   // [z][1024][64]
    const float* __restrict__ dtw_all,   // [z][32][1024]
    bf16* __restrict__ WtBig_all)        // [z][NBIG][1024]
{
    int z = blockIdx.z;
    const float* xpw = xpw_all + (size_t)z * D_INNER * 64;
    const float* dtw = dtw_all + (size_t)z * DT_RANK * D_INNER;
    bf16* Wt = WtBig_all + (size_t)z * NBIG * D_INNER;
    __shared__ float sd[32][17];  // [r][n]
    __shared__ float sx[16][33];  // [k][r]
    int n0 = blockIdx.x * 16, k0 = blockIdx.y * 16;
    int tid = threadIdx.x;
    {   // 512 elements of dtw tile, 2 per thread
        int e = tid;        sd[e >> 4][e & 15] = dtw[(e >> 4) * D_INNER + n0 + (e & 15)];
        e = tid + 256;      sd[e >> 4][e & 15] = dtw[(e >> 4) * D_INNER + n0 + (e & 15)];
    }
    {   // 512 elements of xpw tile, 2 per thread
        int e = tid;        sx[e >> 5][e & 31] = xpw[(size_t)(k0 + (e >> 5)) * 64 + (e & 31)];
        e = tid + 256;      sx[e >> 5][e & 31] = xpw[(size_t)(k0 + (e >> 5)) * 64 + (e & 31)];
    }
    __syncthreads();
    int nn = tid >> 4, kk = tid & 15;
    float acc = 0.f;
    #pragma unroll
    for (int r = 0; r < 32; ++r) acc += sd[r][nn] * sx[kk][r];
    Wt[(size_t)(n0 + nn) * D_INNER + k0 + kk] = __float2bfloat16(acc);
}

// fill WtBig rows 1024..1055: row 1024+j, col k = xpw[k][(j&1)?48+(j>>1):32+(j>>1)]
__global__ void bcw_kernel(const float* __restrict__ xpw_all, bf16* __restrict__ WtBig_all) {
    int z = blockIdx.y;
    const float* xpw = xpw_all + (size_t)z * D_INNER * 64;
    bf16* WtBig = WtBig_all + (size_t)z * NBIG * D_INNER;
    int idx = blockIdx.x * 256 + threadIdx.x;
    if (idx >= 32 * 1024) return;
    int j = idx >> 10, k = idx & 1023;
    int src = (j & 1) ? 48 + (j >> 1) : 32 + (j >> 1);
    WtBig[(size_t)(1024 + j) * 1024 + k] = __float2bfloat16(xpw[k * 64 + src]);
}

// ---------------------------------------------------------------------------
// bf16 MFMA GEMM, m97-structure: BM=BN=128, BK=32, 4 waves (2x2), 16x16x32 MFMA.
// MODE 0: Cb = bf16(acc); 1: Cf = acc; 2: Cf = acc+bias+pos; 3: Cf += acc
// MODE 4: col<1024 -> Cf[row*1024+col] = softplus(acc + bias[col])   (delta)
//         1024<=col<1056 -> Cf2[row*32 + col-1024] = acc             (bc)
template<int MODE>
__global__ __launch_bounds__(256) void gemm_mfma(
    const bf16* __restrict__ A, const bf16* __restrict__ Wt,
    int K, int Nstore, int M, int ldc,
    float* __restrict__ Cf, bf16* __restrict__ Cb,
    const float* __restrict__ bias, const float* __restrict__ pos,
    float* __restrict__ Cf2)
{
    __shared__ short Als[128 * 32];
    __shared__ short Bls[128 * 32];
    int tid = threadIdx.x;
    int lane = tid & 63, wid = tid >> 6;
    int wm = wid >> 1, wn = wid & 1;
    int bm = blockIdx.y * 128, bn = blockIdx.x * 128;

    f32x4 acc[4][4];
    #pragma unroll
    for (int i = 0; i < 4; ++i)
        #pragma unroll
        for (int j = 0; j < 4; ++j)
            acc[i][j] = (f32x4){0.f, 0.f, 0.f, 0.f};

    for (int k0 = 0; k0 < K; k0 += 32) {
        #pragma unroll
        for (int i = 0; i < 2; ++i) {
            int cbase = (i * 4 + wid) * 64;
            int c = cbase + lane;
            int row = c >> 2, kbp = c & 3;
            int kb = kbp ^ ((row >> 1) & 3);
            gload_lds16(A + (size_t)(bm + row) * K + k0 + kb * 8, Als + (size_t)cbase * 8);
            gload_lds16(Wt + (size_t)(bn + row) * K + k0 + kb * 8, Bls + (size_t)cbase * 8);
        }
        __syncthreads();
        bf16x8 af[4], bfr[4];
        #pragma unroll
        for (int mi = 0; mi < 4; ++mi) {
            int row = wm * 64 + mi * 16 + (lane & 15);
            int kbp = (lane >> 4) ^ ((row >> 1) & 3);
            af[mi] = *reinterpret_cast<const bf16x8*>(Als + row * 32 + kbp * 8);
        }
        #pragma unroll
        for (int nj = 0; nj < 4; ++nj) {
            int row = wn * 64 + nj * 16 + (lane & 15);
            int kbp = (lane >> 4) ^ ((row >> 1) & 3);
            bfr[nj] = *reinterpret_cast<const bf16x8*>(Bls + row * 32 + kbp * 8);
        }
        #pragma unroll
        for (int mi = 0; mi < 4; ++mi)
            #pragma unroll
            for (int nj = 0; nj < 4; ++nj)
                acc[mi][nj] = __builtin_amdgcn_mfma_f32_16x16x32_bf16(af[mi], bfr[nj], acc[mi][nj], 0, 0, 0);
        __syncthreads();
    }

    #pragma unroll
    for (int mi = 0; mi < 4; ++mi) {
        #pragma unroll
        for (int nj = 0; nj < 4; ++nj) {
            int r0 = bm + wm * 64 + mi * 16 + ((lane >> 4) << 2);
            int col = bn + wn * 64 + nj * 16 + (lane & 15);
            if (col >= Nstore) continue;
            #pragma unroll
            for (int j = 0; j < 4; ++j) {
                int row = r0 + j;
                if (row >= M) continue;
                float v = acc[mi][nj][j];
                if (MODE == 4) {
                    if (col < 1024) {
                        float z = v + bias[col];
                        Cf[(size_t)row * 1024 + col] = (z > 20.f) ? z : log1pf(__expf(z));
                    } else {
                        Cf2[(size_t)row * 32 + (col - 1024)] = v;
                    }
                } else {
                    size_t o = (size_t)row * ldc + col;
                    if (MODE == 0) Cb[o] = __float2bfloat16(v);
                    else if (MODE == 1) Cf[o] = v;
                    else if (MODE == 2) Cf[o] = v + bias[col] + pos[(size_t)(row % L_SEQ) * D_MODEL + col];
                    else Cf[o] += v;
                }
            }
        }
    }
}

// ---------------------------------------------------------------------------
__global__ __launch_bounds__(256) void rmsnorm_kernel(
    const float* __restrict__ h, const float* __restrict__ w, bf16* __restrict__ o)
{
    int row = blockIdx.x;
    int tid = threadIdx.x;
    const float* hr = h + (size_t)row * D_MODEL;
    float v0 = hr[tid], v1 = hr[tid + 256];
    float ss = v0 * v0 + v1 * v1;
    #pragma unroll
    for (int off = 32; off; off >>= 1) ss += __shfl_down(ss, off);
    __shared__ float ls[4];
    __shared__ float scale_s;
    if ((tid & 63) == 0) ls[tid >> 6] = ss;
    __syncthreads();
    if (tid == 0) {
        float t = ls[0] + ls[1] + ls[2] + ls[3];
        scale_s = rsqrtf(t * (1.f / D_MODEL) + 1e-5f);
    }
    __syncthreads();
    float sc = scale_s;
    o[(size_t)row * D_MODEL + tid]       = __float2bfloat16(v0 * sc * w[tid]);
    o[(size_t)row * D_MODEL + tid + 256] = __float2bfloat16(v1 * sc * w[tid + 256]);
}

// causal depthwise conv (k=4) + SiLU.  xr: [3136,2048] bf16 (xi = first 1024)
__global__ void conv_silu_kernel(const bf16* __restrict__ xr,
                                 const float* __restrict__ cw,
                                 bf16* __restrict__ xs)
{
    int idx = blockIdx.x * 256 + threadIdx.x;
    if (idx >= ROWS * D_INNER) return;
    int d = idx & 1023, row = idx >> 10;
    int l = row % L_SEQ;
    const float* w4 = cw + d * 4;
    float acc = 0.f;
    #pragma unroll
    for (int k = 0; k < 4; ++k) {
        int ls = l - 3 + k;
        if (ls >= 0) acc += __bfloat162float(xr[(size_t)(row - 3 + k) * (2 * D_INNER) + d]) * w4[k];
    }
    float v = acc / (1.f + __expf(-acc));
    xs[idx] = __float2bfloat16(v);
}

// ---------------------------------------------------------------------------
// State-parallel selective scan + output gate (16 lanes per channel).
__global__ __launch_bounds__(256) void scan_sp_kernel(
    const bf16*  __restrict__ xs,     // u     [rows,1024] bf16
    const float* __restrict__ delta,  //       [rows,1024] f32
    const float* __restrict__ bc,     //       [rows,32]   f32 interleaved {B[n],C[n]}
    const float* __restrict__ A_log,  //       [1024,16]
    const float* __restrict__ Dv,     //       [1024]
    const bf16*  __restrict__ xr,     // res   [rows,2048] (cols 1024..2047)
    bf16* __restrict__ y)             //       [rows,1024] bf16
{
    int tid = threadIdx.x;
    int n = tid & 15, ch = tid >> 4;
    int b = blockIdx.x >> 6;
    int d = (((int)blockIdx.x & 63) << 4) | ch;
    size_t bbase = (size_t)b * L_SEQ;

    float A = -__expf(A_log[d * 16 + n]);
    float Dd = Dv[d];
    float s = 0.f;

    float dlv[4], uv[4], rv[4];
    f32x2 bcv[4];

#define LOADSLOT(i, l) { size_t _r = bbase + (l); \
    dlv[i] = delta[_r * 1024 + d]; \
    uv[i]  = __bfloat162float(xs[_r * 1024 + d]); \
    rv[i]  = __bfloat162float(xr[_r * 2048 + 1024 + d]); \
    bcv[i] = *reinterpret_cast<const f32x2*>(bc + _r * 32 + 2 * n); }

#define STEP(i, l) { \
    float _a  = __expf(dlv[i] * A); \
    float _du = dlv[i] * uv[i]; \
    s = _a * s + _du * bcv[i].x; \
    float _p = s * bcv[i].y; \
    _p += __shfl_xor(_p, 1); _p += __shfl_xor(_p, 2); \
    _p += __shfl_xor(_p, 4); _p += __shfl_xor(_p, 8); \
    if (n == 0) { \
        float _rr = rv[i]; \
        float _g = _rr / (1.f + __expf(-_rr)); \
        y[(bbase + (l)) * 1024 + d] = __float2bfloat16((_p + uv[i] * Dd) * _g); \
    } }

    LOADSLOT(0, 0) LOADSLOT(1, 1) LOADSLOT(2, 2) LOADSLOT(3, 3)
    for (int g = 0; g < 48; ++g) {
        int l = g * 4;
        STEP(0, l)     LOADSLOT(0, l + 4)
        STEP(1, l + 1) LOADSLOT(1, l + 5)
        STEP(2, l + 2) LOADSLOT(2, l + 6)
        STEP(3, l + 3) LOADSLOT(3, l + 7)
    }
    STEP(0, 192) STEP(1, 193) STEP(2, 194) STEP(3, 195)
#undef LOADSLOT
#undef STEP
}

// mean over sequence: h[16,196,512] f32 -> hm[16,512] f32.  grid (2,16)
__global__ __launch_bounds__(256) void mean_kernel(const float* __restrict__ h,
                                                   float* __restrict__ hm) {
    int c = blockIdx.x * 256 + threadIdx.x;
    int b = blockIdx.y;
    const float* hb = h + (size_t)b * L_SEQ * D_MODEL + c;
    float acc = 0.f;
    #pragma unroll 4
    for (int l = 0; l < L_SEQ; ++l) acc += hb[(size_t)l * D_MODEL];
    hm[b * D_MODEL + c] = acc * (1.f / L_SEQ);
}

// head: out[b][c] = hm[b,:] . head_w[:,c] + head_b[c].  grid (4,16)
__global__ __launch_bounds__(256) void head_kernel(
    const float* __restrict__ hm, const float* __restrict__ head_w,
    const float* __restrict__ head_b, float* __restrict__ out)
{
    __shared__ float hmr[D_MODEL];
    int tid = threadIdx.x;
    int b = blockIdx.y;
    hmr[tid]       = hm[b * D_MODEL + tid];
    hmr[tid + 256] = hm[b * D_MODEL + tid + 256];
    __syncthreads();
    int c = blockIdx.x * 256 + tid;
    if (c >= N_CLASSES) return;
    float acc = head_b[c];
    #pragma unroll 8
    for (int k = 0; k < D_MODEL; ++k)
        acc += hmr[k] * head_w[(size_t)k * N_CLASSES + c];
    out[(size_t)b * N_CLASSES + c] = acc;
}

// ---------------------------------------------------------------------------
extern "C" void kernel_launch(void* const* d_in, const int* in_sizes, int n_in,
                              void* d_out, int out_size, void* d_ws, size_t ws_size,
                              hipStream_t stream) {
    const float* x         = (const float*)d_in[0];
    const float* patch_w   = (const float*)d_in[1];
    const float* patch_b   = (const float*)d_in[2];
    const float* norm_w    = (const float*)d_in[3];
    const float* in_proj_w = (const float*)d_in[4];
    const float* conv_w    = (const float*)d_in[5];
    const float* x_proj_w  = (const float*)d_in[6];
    const float* dt_proj_w = (const float*)d_in[7];
    const float* dt_proj_b = (const float*)d_in[8];
    const float* A_log     = (const float*)d_in[9];
    const float* Dv        = (const float*)d_in[10];
    const float* out_proj_w= (const float*)d_in[11];
    const float* head_w    = (const float*)d_in[12];
    const float* head_b    = (const float*)d_in[13];
    float* out = (float*)d_out;

    char* base = (char*)d_ws;
    size_t off = 0;
    auto alloc = [&](size_t bytes) -> void* {
        void* p = base + off;
        off += (bytes + 255) & ~(size_t)255;
        return p;
    };
    float* pos   = (float*)alloc((size_t)L_SEQ * D_MODEL * 4);
    bf16*  pwT   = (bf16*) alloc((size_t)D_MODEL * PATCH_DIM * 2);
    bf16*  inT   = (bf16*) alloc((size_t)N_LAYERS * 2 * D_INNER * D_MODEL * 2);
    bf16*  WtBig = (bf16*) alloc((size_t)N_LAYERS * NBIG * D_INNER * 2);
    bf16*  opT   = (bf16*) alloc((size_t)N_LAYERS * D_MODEL * D_INNER * 2);
    float* h     = (float*)alloc((size_t)ROWS * D_MODEL * 4);
    bf16*  xn    = (bf16*) alloc((size_t)ROWSP * D_MODEL * 2);
    // region shared by patch matrix p (prologue) and xr (layer loop)
    char*  reg0  = (char*) alloc((size_t)ROWSP * 2 * D_INNER * 2);
    bf16*  p     = (bf16*)reg0;
    bf16*  xr    = (bf16*)reg0;
    bf16*  xs    = (bf16*) alloc((size_t)ROWSP * D_INNER * 2);
    float* delta = (float*)alloc((size_t)ROWS * D_INNER * 4);
    float* bcb   = (float*)alloc((size_t)ROWS * 32 * 4);
    bf16*  yb    = (bf16*) alloc((size_t)ROWSP * D_INNER * 2);
    float* hm    = (float*)alloc((size_t)BATCH * D_MODEL * 4);

    // ---- prologue + batched weight prep ----
    posemb_kernel<<<(L_SEQ * D_MODEL + 255) / 256, 256, 0, stream>>>(pos);
    patchify_kernel<<<(ROWS * PATCH_DIM + 255) / 256, 256, 0, stream>>>(x, p);
    transpose_bf16_kernel<<<dim3(16, 24), 256, 0, stream>>>(
        patch_w, pwT, PATCH_DIM, D_MODEL, D_MODEL, 0, 0);
    transpose_bf16_kernel<<<dim3(64, 16, N_LAYERS), 256, 0, stream>>>(
        in_proj_w, inT, D_MODEL, 2 * D_INNER, 2 * D_INNER,
        (size_t)D_MODEL * 2 * D_INNER, (size_t)2 * D_INNER * D_MODEL);
    transpose_bf16_kernel<<<dim3(16, 32, N_LAYERS), 256, 0, stream>>>(
        out_proj_w, opT, D_INNER, D_MODEL, D_MODEL,
        (size_t)D_INNER * D_MODEL, (size_t)D_MODEL * D_INNER);
    wcomb_kernel<<<dim3(64, 64, N_LAYERS), 256, 0, stream>>>(
        x_proj_w, dt_proj_w, WtBig);
    bcw_kernel<<<dim3(128, N_LAYERS), 256, 0, stream>>>(x_proj_w, WtBig);

    // h = p @ patch_w + patch_b + pos
    gemm_mfma<2><<<dim3(D_MODEL / 128, ROWSP / 128), 256, 0, stream>>>(
        p, pwT, PATCH_DIM, D_MODEL, ROWS, D_MODEL, h, nullptr, patch_b, pos, nullptr);

    for (int layer = 0; layer < N_LAYERS; ++layer) {
        rmsnorm_kernel<<<ROWS, 256, 0, stream>>>(h, norm_w + layer * D_MODEL, xn);

        // xr = xn @ in_proj  [3136,2048] bf16
        gemm_mfma<0><<<dim3(2 * D_INNER / 128, ROWSP / 128), 256, 0, stream>>>(
            xn, inT + (size_t)layer * 2 * D_INNER * D_MODEL,
            D_MODEL, 2 * D_INNER, ROWS, 2 * D_INNER, nullptr, xr, nullptr, nullptr, nullptr);

        conv_silu_kernel<<<(ROWS * D_INNER) / 256, 256, 0, stream>>>(
            xr, conv_w + (size_t)layer * D_INNER * D_CONV, xs);

        // delta = softplus(xs @ W_comb + dtb); bc = xs @ xpw[:,32:64] interleaved
        gemm_mfma<4><<<dim3(NBIG / 128, ROWSP / 128), 256, 0, stream>>>(
            xs, WtBig + (size_t)layer * NBIG * D_INNER, D_INNER, 1056, ROWS, 0,
            delta, nullptr, dt_proj_b + (size_t)layer * D_INNER, nullptr, bcb);

        // state-parallel scan + gate -> yb bf16
        scan_sp_kernel<<<BATCH * (D_INNER / 16), 256, 0, stream>>>(
            xs, delta, bcb,
            A_log + (size_t)layer * D_INNER * D_STATE,
            Dv + (size_t)layer * D_INNER, xr, yb);

        // h += yb @ out_proj
        gemm_mfma<3><<<dim3(D_MODEL / 128, ROWSP / 128), 256, 0, stream>>>(
            yb, opT + (size_t)layer * D_MODEL * D_INNER,
            D_INNER, D_MODEL, ROWS, D_MODEL, h, nullptr, nullptr, nullptr, nullptr);
    }

    mean_kernel<<<dim3(2, BATCH), 256, 0, stream>>>(h, hm);
    head_kernel<<<dim3(4, BATCH), 256, 0, stream>>>(hm, head_w, head_b, out);
}

// Round 6
// 884.997 us; speedup vs baseline: 1.2999x; 1.0448x over previous
//
#include <hip/hip_runtime.h>
#include <hip/hip_bf16.h>
#include <math.h>

#define BATCH 16
#define L_SEQ 196
#define PATCH_DIM 768
#define D_MODEL 512
#define D_INNER 1024
#define D_STATE 16
#define D_CONV 4
#define DT_RANK 32
#define N_LAYERS 4
#define N_CLASSES 1000
#define ROWS (BATCH * L_SEQ)   // 3136
#define ROWSP 3200             // padded to multiple of 128
#define NBIG 1152              // delta(1024) + bc(32), padded to 128

typedef __hip_bfloat16 bf16;
typedef __attribute__((ext_vector_type(8))) __bf16 bf16x8;
typedef __attribute__((ext_vector_type(4))) float f32x4;
typedef __attribute__((ext_vector_type(2))) float f32x2;

__device__ __forceinline__ void gload_lds16(const void* g, void* l) {
    __builtin_amdgcn_global_load_lds((const __attribute__((address_space(1))) void*)g,
                                     (__attribute__((address_space(3))) void*)l, 16, 0, 0);
}

// sum across 16 consecutive lanes via DPP (quad_perm x2, half_mirror, mirror)
__device__ __forceinline__ float dpp_sum16(float x) {
    x += __int_as_float(__builtin_amdgcn_mov_dpp(__float_as_int(x), 0xB1, 0xF, 0xF, true));  // ^1
    x += __int_as_float(__builtin_amdgcn_mov_dpp(__float_as_int(x), 0x4E, 0xF, 0xF, true));  // ^2
    x += __int_as_float(__builtin_amdgcn_mov_dpp(__float_as_int(x), 0x141, 0xF, 0xF, true)); // ^7 half_mirror
    x += __int_as_float(__builtin_amdgcn_mov_dpp(__float_as_int(x), 0x140, 0xF, 0xF, true)); // ^15 mirror
    return x;
}

// ---------------------------------------------------------------------------
__global__ void posemb_kernel(float* __restrict__ pos) {
    int idx = blockIdx.x * 256 + threadIdx.x;
    if (idx >= L_SEQ * D_MODEL) return;
    int l = idx >> 9, col = idx & 511;
    int q = col >> 7, wi = col & 127;
    float omega = powf(10000.f, -(float)wi / 127.f);
    float yv = (float)(l / 14), xv = (float)(l % 14);
    float arg = (q < 2 ? xv : yv) * omega;
    pos[idx] = (q & 1) ? cosf(arg) : sinf(arg);
}

// patchify: x[B,224,224,3] -> p[3136,768] bf16
__global__ void patchify_kernel(const float* __restrict__ x, bf16* __restrict__ p) {
    int idx = blockIdx.x * 256 + threadIdx.x;
    if (idx >= ROWS * PATCH_DIM) return;
    int k = idx % PATCH_DIM, row = idx / PATCH_DIM;
    int b = row / L_SEQ, l = row % L_SEQ;
    int i = l / 14, j = l % 14;
    int ph = k / 48, r = k % 48, pw = r / 3, c = r % 3;
    size_t src = (((size_t)b * 224 + i * 16 + ph) * 224 + (j * 16 + pw)) * 3 + c;
    p[idx] = __float2bfloat16(x[src]);
}

// transpose-convert: src[K][N] f32 -> dst[Npad][K] bf16 (zero-fill), z = layer
__global__ __launch_bounds__(256) void transpose_bf16_kernel(
    const float* __restrict__ src, bf16* __restrict__ dst,
    int K, int N, int Npad, size_t src_lstride, size_t dst_lstride)
{
    src += (size_t)blockIdx.z * src_lstride;
    dst += (size_t)blockIdx.z * dst_lstride;
    __shared__ float tile[32][33];
    int kb = blockIdx.y * 32, nb = blockIdx.x * 32;
    int tx = threadIdx.x & 31, ty = threadIdx.x >> 5;  // 32 x 8
    #pragma unroll
    for (int i = 0; i < 4; ++i) {
        int k = kb + ty + 8 * i, n = nb + tx;
        tile[ty + 8 * i][tx] = (k < K && n < N) ? src[(size_t)k * N + n] : 0.f;
    }
    __syncthreads();
    #pragma unroll
    for (int i = 0; i < 4; ++i) {
        int n = nb + ty + 8 * i, k = kb + tx;
        if (n < Npad && k < K) dst[(size_t)n * K + k] = __float2bfloat16(tile[tx][ty + 8 * i]);
    }
}

// W_comb^T directly in bf16: Wt[z][n][k] = sum_{r<32} dtw_z[r][n] * xpw_z[k][r]
__global__ __launch_bounds__(256) void wcomb_kernel(
    const float* __restrict__ xpw_all,   // [z][1024][64]
    const float* __restrict__ dtw_all,   // [z][32][1024]
    bf16* __restrict__ WtBig_all)        // [z][NBIG][1024]
{
    int z = blockIdx.z;
    const float* xpw = xpw_all + (size_t)z * D_INNER * 64;
    const float* dtw = dtw_all + (size_t)z * DT_RANK * D_INNER;
    bf16* Wt = WtBig_all + (size_t)z * NBIG * D_INNER;
    __shared__ float sd[32][17];  // [r][n]
    __shared__ float sx[16][33];  // [k][r]
    int n0 = blockIdx.x * 16, k0 = blockIdx.y * 16;
    int tid = threadIdx.x;
    {
        int e = tid;        sd[e >> 4][e & 15] = dtw[(e >> 4) * D_INNER + n0 + (e & 15)];
        e = tid + 256;      sd[e >> 4][e & 15] = dtw[(e >> 4) * D_INNER + n0 + (e & 15)];
    }
    {
        int e = tid;        sx[e >> 5][e & 31] = xpw[(size_t)(k0 + (e >> 5)) * 64 + (e & 31)];
        e = tid + 256;      sx[e >> 5][e & 31] = xpw[(size_t)(k0 + (e >> 5)) * 64 + (e & 31)];
    }
    __syncthreads();
    int nn = tid >> 4, kk = tid & 15;
    float acc = 0.f;
    #pragma unroll
    for (int r = 0; r < 32; ++r) acc += sd[r][nn] * sx[kk][r];
    Wt[(size_t)(n0 + nn) * D_INNER + k0 + kk] = __float2bfloat16(acc);
}

// fill WtBig rows 1024..1055: row 1024+j, col k = xpw[k][(j&1)?48+(j>>1):32+(j>>1)]
__global__ void bcw_kernel(const float* __restrict__ xpw_all, bf16* __restrict__ WtBig_all) {
    int z = blockIdx.y;
    const float* xpw = xpw_all + (size_t)z * D_INNER * 64;
    bf16* WtBig = WtBig_all + (size_t)z * NBIG * D_INNER;
    int idx = blockIdx.x * 256 + threadIdx.x;
    if (idx >= 32 * 1024) return;
    int j = idx >> 10, k = idx & 1023;
    int src = (j & 1) ? 48 + (j >> 1) : 32 + (j >> 1);
    WtBig[(size_t)(1024 + j) * 1024 + k] = __float2bfloat16(xpw[k * 64 + src]);
}

// ---------------------------------------------------------------------------
// bf16 MFMA GEMM, m97-structure: BM=BN=128, BK=32, 4 waves (2x2), 16x16x32 MFMA.
// MODE 0: Cb = bf16(acc); 1: Cf = acc; 2: Cf = acc+bias+pos; 3: Cf += acc
// MODE 4: col<1024 -> Cf[row*1024+col] = softplus(acc + bias[col])   (delta)
//         1024<=col<1056 -> Cf2[row*32 + col-1024] = acc             (bc)
template<int MODE>
__global__ __launch_bounds__(256) void gemm_mfma(
    const bf16* __restrict__ A, const bf16* __restrict__ Wt,
    int K, int Nstore, int M, int ldc,
    float* __restrict__ Cf, bf16* __restrict__ Cb,
    const float* __restrict__ bias, const float* __restrict__ pos,
    float* __restrict__ Cf2)
{
    __shared__ short Als[128 * 32];
    __shared__ short Bls[128 * 32];
    int tid = threadIdx.x;
    int lane = tid & 63, wid = tid >> 6;
    int wm = wid >> 1, wn = wid & 1;
    int bm = blockIdx.y * 128, bn = blockIdx.x * 128;

    f32x4 acc[4][4];
    #pragma unroll
    for (int i = 0; i < 4; ++i)
        #pragma unroll
        for (int j = 0; j < 4; ++j)
            acc[i][j] = (f32x4){0.f, 0.f, 0.f, 0.f};

    for (int k0 = 0; k0 < K; k0 += 32) {
        #pragma unroll
        for (int i = 0; i < 2; ++i) {
            int cbase = (i * 4 + wid) * 64;
            int c = cbase + lane;
            int row = c >> 2, kbp = c & 3;
            int kb = kbp ^ ((row >> 1) & 3);
            gload_lds16(A + (size_t)(bm + row) * K + k0 + kb * 8, Als + (size_t)cbase * 8);
            gload_lds16(Wt + (size_t)(bn + row) * K + k0 + kb * 8, Bls + (size_t)cbase * 8);
        }
        __syncthreads();
        bf16x8 af[4], bfr[4];
        #pragma unroll
        for (int mi = 0; mi < 4; ++mi) {
            int row = wm * 64 + mi * 16 + (lane & 15);
            int kbp = (lane >> 4) ^ ((row >> 1) & 3);
            af[mi] = *reinterpret_cast<const bf16x8*>(Als + row * 32 + kbp * 8);
        }
        #pragma unroll
        for (int nj = 0; nj < 4; ++nj) {
            int row = wn * 64 + nj * 16 + (lane & 15);
            int kbp = (lane >> 4) ^ ((row >> 1) & 3);
            bfr[nj] = *reinterpret_cast<const bf16x8*>(Bls + row * 32 + kbp * 8);
        }
        #pragma unroll
        for (int mi = 0; mi < 4; ++mi)
            #pragma unroll
            for (int nj = 0; nj < 4; ++nj)
                acc[mi][nj] = __builtin_amdgcn_mfma_f32_16x16x32_bf16(af[mi], bfr[nj], acc[mi][nj], 0, 0, 0);
        __syncthreads();
    }

    #pragma unroll
    for (int mi = 0; mi < 4; ++mi) {
        #pragma unroll
        for (int nj = 0; nj < 4; ++nj) {
            int r0 = bm + wm * 64 + mi * 16 + ((lane >> 4) << 2);
            int col = bn + wn * 64 + nj * 16 + (lane & 15);
            if (col >= Nstore) continue;
            #pragma unroll
            for (int j = 0; j < 4; ++j) {
                int row = r0 + j;
                if (row >= M) continue;
                float v = acc[mi][nj][j];
                if (MODE == 4) {
                    if (col < 1024) {
                        float z = v + bias[col];
                        Cf[(size_t)row * 1024 + col] = (z > 20.f) ? z : log1pf(__expf(z));
                    } else {
                        Cf2[(size_t)row * 32 + (col - 1024)] = v;
                    }
                } else {
                    size_t o = (size_t)row * ldc + col;
                    if (MODE == 0) Cb[o] = __float2bfloat16(v);
                    else if (MODE == 1) Cf[o] = v;
                    else if (MODE == 2) Cf[o] = v + bias[col] + pos[(size_t)(row % L_SEQ) * D_MODEL + col];
                    else Cf[o] += v;
                }
            }
        }
    }
}

// ---------------------------------------------------------------------------
__global__ __launch_bounds__(256) void rmsnorm_kernel(
    const float* __restrict__ h, const float* __restrict__ w, bf16* __restrict__ o)
{
    int row = blockIdx.x;
    int tid = threadIdx.x;
    const float* hr = h + (size_t)row * D_MODEL;
    float v0 = hr[tid], v1 = hr[tid + 256];
    float ss = v0 * v0 + v1 * v1;
    #pragma unroll
    for (int off = 32; off; off >>= 1) ss += __shfl_down(ss, off);
    __shared__ float ls[4];
    __shared__ float scale_s;
    if ((tid & 63) == 0) ls[tid >> 6] = ss;
    __syncthreads();
    if (tid == 0) {
        float t = ls[0] + ls[1] + ls[2] + ls[3];
        scale_s = rsqrtf(t * (1.f / D_MODEL) + 1e-5f);
    }
    __syncthreads();
    float sc = scale_s;
    o[(size_t)row * D_MODEL + tid]       = __float2bfloat16(v0 * sc * w[tid]);
    o[(size_t)row * D_MODEL + tid + 256] = __float2bfloat16(v1 * sc * w[tid + 256]);
}

// causal depthwise conv (k=4) + SiLU.  xr: [3136,2048] bf16 (xi = first 1024)
// writes xs[row][d] (GEMM A-matrix) and ur[row][d] = {u, res} packed bf16x2
__global__ void conv_silu_kernel(const bf16* __restrict__ xr,
                                 const float* __restrict__ cw,
                                 bf16* __restrict__ xs,
                                 __hip_bfloat162* __restrict__ ur)
{
    int idx = blockIdx.x * 256 + threadIdx.x;
    if (idx >= ROWS * D_INNER) return;
    int d = idx & 1023, row = idx >> 10;
    int l = row % L_SEQ;
    const float* w4 = cw + d * 4;
    float acc = 0.f;
    #pragma unroll
    for (int k = 0; k < 4; ++k) {
        int ls = l - 3 + k;
        if (ls >= 0) acc += __bfloat162float(xr[(size_t)(row - 3 + k) * (2 * D_INNER) + d]) * w4[k];
    }
    float v = acc / (1.f + __expf(-acc));
    bf16 ub = __float2bfloat16(v);
    xs[idx] = ub;
    __hip_bfloat162 pr;
    pr.x = ub;
    pr.y = xr[(size_t)row * (2 * D_INNER) + D_INNER + d];   // res, raw bf16 copy
    ur[idx] = pr;
}

// ---------------------------------------------------------------------------
// State-parallel selective scan + output gate (16 lanes per channel).
// 8-deep register pipeline; DPP lane reduction; 3 loads/step (delta, ur, bc).
__global__ __launch_bounds__(256) void scan_sp_kernel(
    const __hip_bfloat162* __restrict__ ur, // {u,res} [rows,1024]
    const float* __restrict__ delta,        //         [rows,1024] f32
    const float* __restrict__ bc,           //         [rows,32]   f32 {B[n],C[n]}
    const float* __restrict__ A_log,        //         [1024,16]
    const float* __restrict__ Dv,           //         [1024]
    bf16* __restrict__ y)                   //         [rows,1024] bf16
{
    int tid = threadIdx.x;
    int n = tid & 15, ch = tid >> 4;
    int b = blockIdx.x >> 6;
    int d = (((int)blockIdx.x & 63) << 4) | ch;
    size_t bbase = (size_t)b * L_SEQ;

    float A = -__expf(A_log[d * 16 + n]);
    float Dd = Dv[d];
    float s = 0.f;

    float dlv[8];
    __hip_bfloat162 uv[8];
    f32x2 bcv[8];

#define LOADSLOT(i, l) { int _l = (l) < L_SEQ ? (l) : L_SEQ - 1; size_t _r = bbase + _l; \
    dlv[i] = delta[_r * 1024 + d]; \
    uv[i]  = ur[_r * 1024 + d]; \
    bcv[i] = *reinterpret_cast<const f32x2*>(bc + _r * 32 + 2 * n); }

#define STEP(i, l) { \
    float _a  = __expf(dlv[i] * A); \
    float _u  = __bfloat162float(uv[i].x); \
    s = _a * s + (dlv[i] * _u) * bcv[i].x; \
    float _p = dpp_sum16(s * bcv[i].y); \
    if (n == 0) { \
        float _rr = __bfloat162float(uv[i].y); \
        float _g = _rr / (1.f + __expf(-_rr)); \
        y[(bbase + (l)) * 1024 + d] = __float2bfloat16((_p + _u * Dd) * _g); \
    } }

    LOADSLOT(0, 0) LOADSLOT(1, 1) LOADSLOT(2, 2) LOADSLOT(3, 3)
    LOADSLOT(4, 4) LOADSLOT(5, 5) LOADSLOT(6, 6) LOADSLOT(7, 7)
    for (int g = 0; g < 24; ++g) {
        int l = g * 8;
        STEP(0, l)     LOADSLOT(0, l + 8)
        STEP(1, l + 1) LOADSLOT(1, l + 9)
        STEP(2, l + 2) LOADSLOT(2, l + 10)
        STEP(3, l + 3) LOADSLOT(3, l + 11)
        STEP(4, l + 4) LOADSLOT(4, l + 12)
        STEP(5, l + 5) LOADSLOT(5, l + 13)
        STEP(6, l + 6) LOADSLOT(6, l + 14)
        STEP(7, l + 7) LOADSLOT(7, l + 15)
    }
    STEP(0, 192) STEP(1, 193) STEP(2, 194) STEP(3, 195)
#undef LOADSLOT
#undef STEP
}

// mean over sequence: h[16,196,512] f32 -> hm[16,512] f32.  grid (2,16)
__global__ __launch_bounds__(256) void mean_kernel(const float* __restrict__ h,
                                                   float* __restrict__ hm) {
    int c = blockIdx.x * 256 + threadIdx.x;
    int b = blockIdx.y;
    const float* hb = h + (size_t)b * L_SEQ * D_MODEL + c;
    float acc = 0.f;
    #pragma unroll 4
    for (int l = 0; l < L_SEQ; ++l) acc += hb[(size_t)l * D_MODEL];
    hm[b * D_MODEL + c] = acc * (1.f / L_SEQ);
}

// head: out[b][c] = hm[b,:] . head_w[:,c] + head_b[c].  grid (4,16)
__global__ __launch_bounds__(256) void head_kernel(
    const float* __restrict__ hm, const float* __restrict__ head_w,
    const float* __restrict__ head_b, float* __restrict__ out)
{
    __shared__ float hmr[D_MODEL];
    int tid = threadIdx.x;
    int b = blockIdx.y;
    hmr[tid]       = hm[b * D_MODEL + tid];
    hmr[tid + 256] = hm[b * D_MODEL + tid + 256];
    __syncthreads();
    int c = blockIdx.x * 256 + tid;
    if (c >= N_CLASSES) return;
    float acc = head_b[c];
    #pragma unroll 8
    for (int k = 0; k < D_MODEL; ++k)
        acc += hmr[k] * head_w[(size_t)k * N_CLASSES + c];
    out[(size_t)b * N_CLASSES + c] = acc;
}

// ---------------------------------------------------------------------------
extern "C" void kernel_launch(void* const* d_in, const int* in_sizes, int n_in,
                              void* d_out, int out_size, void* d_ws, size_t ws_size,
                              hipStream_t stream) {
    const float* x         = (const float*)d_in[0];
    const float* patch_w   = (const float*)d_in[1];
    const float* patch_b   = (const float*)d_in[2];
    const float* norm_w    = (const float*)d_in[3];
    const float* in_proj_w = (const float*)d_in[4];
    const float* conv_w    = (const float*)d_in[5];
    const float* x_proj_w  = (const float*)d_in[6];
    const float* dt_proj_w = (const float*)d_in[7];
    const float* dt_proj_b = (const float*)d_in[8];
    const float* A_log     = (const float*)d_in[9];
    const float* Dv        = (const float*)d_in[10];
    const float* out_proj_w= (const float*)d_in[11];
    const float* head_w    = (const float*)d_in[12];
    const float* head_b    = (const float*)d_in[13];
    float* out = (float*)d_out;

    char* base = (char*)d_ws;
    size_t off = 0;
    auto alloc = [&](size_t bytes) -> void* {
        void* p = base + off;
        off += (bytes + 255) & ~(size_t)255;
        return p;
    };
    float* pos   = (float*)alloc((size_t)L_SEQ * D_MODEL * 4);
    bf16*  pwT   = (bf16*) alloc((size_t)D_MODEL * PATCH_DIM * 2);
    bf16*  inT   = (bf16*) alloc((size_t)N_LAYERS * 2 * D_INNER * D_MODEL * 2);
    bf16*  WtBig = (bf16*) alloc((size_t)N_LAYERS * NBIG * D_INNER * 2);
    bf16*  opT   = (bf16*) alloc((size_t)N_LAYERS * D_MODEL * D_INNER * 2);
    float* h     = (float*)alloc((size_t)ROWS * D_MODEL * 4);
    bf16*  xn    = (bf16*) alloc((size_t)ROWSP * D_MODEL * 2);
    // region shared by patch matrix p (prologue) and xr (layer loop)
    char*  reg0  = (char*) alloc((size_t)ROWSP * 2 * D_INNER * 2);
    bf16*  p     = (bf16*)reg0;
    bf16*  xr    = (bf16*)reg0;
    bf16*  xs    = (bf16*) alloc((size_t)ROWSP * D_INNER * 2);
    __hip_bfloat162* ur = (__hip_bfloat162*)alloc((size_t)ROWSP * D_INNER * 4);
    float* delta = (float*)alloc((size_t)ROWS * D_INNER * 4);
    float* bcb   = (float*)alloc((size_t)ROWS * 32 * 4);
    bf16*  yb    = (bf16*) alloc((size_t)ROWSP * D_INNER * 2);
    float* hm    = (float*)alloc((size_t)BATCH * D_MODEL * 4);

    // ---- prologue + batched weight prep ----
    posemb_kernel<<<(L_SEQ * D_MODEL + 255) / 256, 256, 0, stream>>>(pos);
    patchify_kernel<<<(ROWS * PATCH_DIM + 255) / 256, 256, 0, stream>>>(x, p);
    transpose_bf16_kernel<<<dim3(16, 24), 256, 0, stream>>>(
        patch_w, pwT, PATCH_DIM, D_MODEL, D_MODEL, 0, 0);
    transpose_bf16_kernel<<<dim3(64, 16, N_LAYERS), 256, 0, stream>>>(
        in_proj_w, inT, D_MODEL, 2 * D_INNER, 2 * D_INNER,
        (size_t)D_MODEL * 2 * D_INNER, (size_t)2 * D_INNER * D_MODEL);
    transpose_bf16_kernel<<<dim3(16, 32, N_LAYERS), 256, 0, stream>>>(
        out_proj_w, opT, D_INNER, D_MODEL, D_MODEL,
        (size_t)D_INNER * D_MODEL, (size_t)D_MODEL * D_INNER);
    wcomb_kernel<<<dim3(64, 64, N_LAYERS), 256, 0, stream>>>(
        x_proj_w, dt_proj_w, WtBig);
    bcw_kernel<<<dim3(128, N_LAYERS), 256, 0, stream>>>(x_proj_w, WtBig);

    // h = p @ patch_w + patch_b + pos
    gemm_mfma<2><<<dim3(D_MODEL / 128, ROWSP / 128), 256, 0, stream>>>(
        p, pwT, PATCH_DIM, D_MODEL, ROWS, D_MODEL, h, nullptr, patch_b, pos, nullptr);

    for (int layer = 0; layer < N_LAYERS; ++layer) {
        rmsnorm_kernel<<<ROWS, 256, 0, stream>>>(h, norm_w + layer * D_MODEL, xn);

        // xr = xn @ in_proj  [3136,2048] bf16
        gemm_mfma<0><<<dim3(2 * D_INNER / 128, ROWSP / 128), 256, 0, stream>>>(
            xn, inT + (size_t)layer * 2 * D_INNER * D_MODEL,
            D_MODEL, 2 * D_INNER, ROWS, 2 * D_INNER, nullptr, xr, nullptr, nullptr, nullptr);

        conv_silu_kernel<<<(ROWS * D_INNER) / 256, 256, 0, stream>>>(
            xr, conv_w + (size_t)layer * D_INNER * D_CONV, xs, ur);

        // delta = softplus(xs @ W_comb + dtb); bc = xs @ xpw[:,32:64] interleaved
        gemm_mfma<4><<<dim3(NBIG / 128, ROWSP / 128), 256, 0, stream>>>(
            xs, WtBig + (size_t)layer * NBIG * D_INNER, D_INNER, 1056, ROWS, 0,
            delta, nullptr, dt_proj_b + (size_t)layer * D_INNER, nullptr, bcb);

        // state-parallel scan + gate -> yb bf16
        scan_sp_kernel<<<BATCH * (D_INNER / 16), 256, 0, stream>>>(
            ur, delta, bcb,
            A_log + (size_t)layer * D_INNER * D_STATE,
            Dv + (size_t)layer * D_INNER, yb);

        // h += yb @ out_proj
        gemm_mfma<3><<<dim3(D_MODEL / 128, ROWSP / 128), 256, 0, stream>>>(
            yb, opT + (size_t)layer * D_MODEL * D_INNER,
            D_INNER, D_MODEL, ROWS, D_MODEL, h, nullptr, nullptr, nullptr, nullptr);
    }

    mean_kernel<<<dim3(2, BATCH), 256, 0, stream>>>(h, hm);
    head_kernel<<<dim3(4, BATCH), 256, 0, stream>>>(hm, head_w, head_b, out);
}

// Round 7
// 721.572 us; speedup vs baseline: 1.5943x; 1.2265x over previous
//
#include <hip/hip_runtime.h>
#include <hip/hip_bf16.h>
#include <math.h>

#define BATCH 16
#define L_SEQ 196
#define PATCH_DIM 768
#define D_MODEL 512
#define D_INNER 1024
#define D_STATE 16
#define D_CONV 4
#define DT_RANK 32
#define N_LAYERS 4
#define N_CLASSES 1000
#define ROWS (BATCH * L_SEQ)   // 3136
#define ROWSP 3200             // padded to multiple of 128
#define NBIG 1152              // delta(1024) + bc(32), padded to 128

typedef __hip_bfloat16 bf16;
typedef __attribute__((ext_vector_type(8))) __bf16 bf16x8;
typedef __attribute__((ext_vector_type(4))) float f32x4;
typedef __attribute__((ext_vector_type(2))) float f32x2;

__device__ __forceinline__ void gload_lds16(const void* g, void* l) {
    __builtin_amdgcn_global_load_lds((const __attribute__((address_space(1))) void*)g,
                                     (__attribute__((address_space(3))) void*)l, 16, 0, 0);
}

// ---------------------------------------------------------------------------
__global__ void posemb_kernel(float* __restrict__ pos) {
    int idx = blockIdx.x * 256 + threadIdx.x;
    if (idx >= L_SEQ * D_MODEL) return;
    int l = idx >> 9, col = idx & 511;
    int q = col >> 7, wi = col & 127;
    float omega = powf(10000.f, -(float)wi / 127.f);
    float yv = (float)(l / 14), xv = (float)(l % 14);
    float arg = (q < 2 ? xv : yv) * omega;
    pos[idx] = (q & 1) ? cosf(arg) : sinf(arg);
}

// patchify: x[B,224,224,3] -> p[3136,768] bf16
__global__ void patchify_kernel(const float* __restrict__ x, bf16* __restrict__ p) {
    int idx = blockIdx.x * 256 + threadIdx.x;
    if (idx >= ROWS * PATCH_DIM) return;
    int k = idx % PATCH_DIM, row = idx / PATCH_DIM;
    int b = row / L_SEQ, l = row % L_SEQ;
    int i = l / 14, j = l % 14;
    int ph = k / 48, r = k % 48, pw = r / 3, c = r % 3;
    size_t src = (((size_t)b * 224 + i * 16 + ph) * 224 + (j * 16 + pw)) * 3 + c;
    p[idx] = __float2bfloat16(x[src]);
}

// transpose-convert: src[K][N] f32 -> dst[Npad][K] bf16 (zero-fill), z = layer
__global__ __launch_bounds__(256) void transpose_bf16_kernel(
    const float* __restrict__ src, bf16* __restrict__ dst,
    int K, int N, int Npad, size_t src_lstride, size_t dst_lstride)
{
    src += (size_t)blockIdx.z * src_lstride;
    dst += (size_t)blockIdx.z * dst_lstride;
    __shared__ float tile[32][33];
    int kb = blockIdx.y * 32, nb = blockIdx.x * 32;
    int tx = threadIdx.x & 31, ty = threadIdx.x >> 5;  // 32 x 8
    #pragma unroll
    for (int i = 0; i < 4; ++i) {
        int k = kb + ty + 8 * i, n = nb + tx;
        tile[ty + 8 * i][tx] = (k < K && n < N) ? src[(size_t)k * N + n] : 0.f;
    }
    __syncthreads();
    #pragma unroll
    for (int i = 0; i < 4; ++i) {
        int n = nb + ty + 8 * i, k = kb + tx;
        if (n < Npad && k < K) dst[(size_t)n * K + k] = __float2bfloat16(tile[tx][ty + 8 * i]);
    }
}

// W_comb^T directly in bf16: Wt[z][n][k] = sum_{r<32} dtw_z[r][n] * xpw_z[k][r]
__global__ __launch_bounds__(256) void wcomb_kernel(
    const float* __restrict__ xpw_all,   // [z][1024][64]
    const float* __restrict__ dtw_all,   // [z][32][1024]
    bf16* __restrict__ WtBig_all)        // [z][NBIG][1024]
{
    int z = blockIdx.z;
    const float* xpw = xpw_all + (size_t)z * D_INNER * 64;
    const float* dtw = dtw_all + (size_t)z * DT_RANK * D_INNER;
    bf16* Wt = WtBig_all + (size_t)z * NBIG * D_INNER;
    __shared__ float sd[32][17];  // [r][n]
    __shared__ float sx[16][33];  // [k][r]
    int n0 = blockIdx.x * 16, k0 = blockIdx.y * 16;
    int tid = threadIdx.x;
    {
        int e = tid;        sd[e >> 4][e & 15] = dtw[(e >> 4) * D_INNER + n0 + (e & 15)];
        e = tid + 256;      sd[e >> 4][e & 15] = dtw[(e >> 4) * D_INNER + n0 + (e & 15)];
    }
    {
        int e = tid;        sx[e >> 5][e & 31] = xpw[(size_t)(k0 + (e >> 5)) * 64 + (e & 31)];
        e = tid + 256;      sx[e >> 5][e & 31] = xpw[(size_t)(k0 + (e >> 5)) * 64 + (e & 31)];
    }
    __syncthreads();
    int nn = tid >> 4, kk = tid & 15;
    float acc = 0.f;
    #pragma unroll
    for (int r = 0; r < 32; ++r) acc += sd[r][nn] * sx[kk][r];
    Wt[(size_t)(n0 + nn) * D_INNER + k0 + kk] = __float2bfloat16(acc);
}

// fill WtBig rows 1024..1055: row 1024+j, col k = xpw[k][(j&1)?48+(j>>1):32+(j>>1)]
__global__ void bcw_kernel(const float* __restrict__ xpw_all, bf16* __restrict__ WtBig_all) {
    int z = blockIdx.y;
    const float* xpw = xpw_all + (size_t)z * D_INNER * 64;
    bf16* WtBig = WtBig_all + (size_t)z * NBIG * D_INNER;
    int idx = blockIdx.x * 256 + threadIdx.x;
    if (idx >= 32 * 1024) return;
    int j = idx >> 10, k = idx & 1023;
    int src = (j & 1) ? 48 + (j >> 1) : 32 + (j >> 1);
    WtBig[(size_t)(1024 + j) * 1024 + k] = __float2bfloat16(xpw[k * 64 + src]);
}

// ---------------------------------------------------------------------------
// bf16 MFMA GEMM, BM=BN=128, BK=32, 4 waves (2x2), 16x16x32 MFMA.
// MODE 0: Cb = bf16(acc)
// MODE 4: col<1024 -> Cf[(row*1024+col)*2+1] = softplus(acc+bias[col])  (delta in udg.y)
//         1024<=col<1056 -> Cf2[row*32 + col-1024] = acc                (bc)
template<int MODE>
__global__ __launch_bounds__(256) void gemm_mfma(
    const bf16* __restrict__ A, const bf16* __restrict__ Wt,
    int K, int Nstore, int M, int ldc,
    float* __restrict__ Cf, bf16* __restrict__ Cb,
    const float* __restrict__ bias, const float* __restrict__ pos,
    float* __restrict__ Cf2)
{
    __shared__ short Als[128 * 32];
    __shared__ short Bls[128 * 32];
    int tid = threadIdx.x;
    int lane = tid & 63, wid = tid >> 6;
    int wm = wid >> 1, wn = wid & 1;
    int bm = blockIdx.y * 128, bn = blockIdx.x * 128;

    f32x4 acc[4][4];
    #pragma unroll
    for (int i = 0; i < 4; ++i)
        #pragma unroll
        for (int j = 0; j < 4; ++j)
            acc[i][j] = (f32x4){0.f, 0.f, 0.f, 0.f};

    for (int k0 = 0; k0 < K; k0 += 32) {
        #pragma unroll
        for (int i = 0; i < 2; ++i) {
            int cbase = (i * 4 + wid) * 64;
            int c = cbase + lane;
            int row = c >> 2, kbp = c & 3;
            int kb = kbp ^ ((row >> 1) & 3);
            gload_lds16(A + (size_t)(bm + row) * K + k0 + kb * 8, Als + (size_t)cbase * 8);
            gload_lds16(Wt + (size_t)(bn + row) * K + k0 + kb * 8, Bls + (size_t)cbase * 8);
        }
        __syncthreads();
        bf16x8 af[4], bfr[4];
        #pragma unroll
        for (int mi = 0; mi < 4; ++mi) {
            int row = wm * 64 + mi * 16 + (lane & 15);
            int kbp = (lane >> 4) ^ ((row >> 1) & 3);
            af[mi] = *reinterpret_cast<const bf16x8*>(Als + row * 32 + kbp * 8);
        }
        #pragma unroll
        for (int nj = 0; nj < 4; ++nj) {
            int row = wn * 64 + nj * 16 + (lane & 15);
            int kbp = (lane >> 4) ^ ((row >> 1) & 3);
            bfr[nj] = *reinterpret_cast<const bf16x8*>(Bls + row * 32 + kbp * 8);
        }
        #pragma unroll
        for (int mi = 0; mi < 4; ++mi)
            #pragma unroll
            for (int nj = 0; nj < 4; ++nj)
                acc[mi][nj] = __builtin_amdgcn_mfma_f32_16x16x32_bf16(af[mi], bfr[nj], acc[mi][nj], 0, 0, 0);
        __syncthreads();
    }

    #pragma unroll
    for (int mi = 0; mi < 4; ++mi) {
        #pragma unroll
        for (int nj = 0; nj < 4; ++nj) {
            int r0 = bm + wm * 64 + mi * 16 + ((lane >> 4) << 2);
            int col = bn + wn * 64 + nj * 16 + (lane & 15);
            if (col >= Nstore) continue;
            #pragma unroll
            for (int j = 0; j < 4; ++j) {
                int row = r0 + j;
                if (row >= M) continue;
                float v = acc[mi][nj][j];
                if (MODE == 4) {
                    if (col < 1024) {
                        float z = v + bias[col];
                        Cf[((size_t)row * 1024 + col) * 2 + 1] = (z > 20.f) ? z : log1pf(__expf(z));
                    } else {
                        Cf2[(size_t)row * 32 + (col - 1024)] = v;
                    }
                } else {
                    size_t o = (size_t)row * ldc + col;
                    if (MODE == 0) Cb[o] = __float2bfloat16(v);
                }
            }
        }
    }
}

// BM=64, BN=128 variant for narrow GEMMs (more blocks -> better CU coverage).
// MODE 2: Cf = acc + bias[col] + pos[(row%196)*512+col];  MODE 3: Cf += acc
template<int MODE>
__global__ __launch_bounds__(256) void gemm_mfma64(
    const bf16* __restrict__ A, const bf16* __restrict__ Wt,
    int K, int Nstore, int M, int ldc,
    float* __restrict__ Cf,
    const float* __restrict__ bias, const float* __restrict__ pos)
{
    __shared__ short Als[64 * 32];
    __shared__ short Bls[128 * 32];
    int tid = threadIdx.x;
    int lane = tid & 63, wid = tid >> 6;
    int wm = wid >> 1, wn = wid & 1;   // 2x2 waves; wm covers 32 rows, wn 64 cols
    int bm = blockIdx.y * 64, bn = blockIdx.x * 128;

    f32x4 acc[2][4];
    #pragma unroll
    for (int i = 0; i < 2; ++i)
        #pragma unroll
        for (int j = 0; j < 4; ++j)
            acc[i][j] = (f32x4){0.f, 0.f, 0.f, 0.f};

    for (int k0 = 0; k0 < K; k0 += 32) {
        // A: 256 chunks (64 rows x 4 kb);  B: 512 chunks
        {
            int c = tid;               // A chunk
            int row = c >> 2, kbp = c & 3;
            int kb = kbp ^ ((row >> 1) & 3);
            gload_lds16(A + (size_t)(bm + row) * K + k0 + kb * 8, Als + (size_t)(wid * 64) * 8);
        }
        #pragma unroll
        for (int i = 0; i < 2; ++i) {
            int cbase = (i * 4 + wid) * 64;
            int c = cbase + lane;
            int row = c >> 2, kbp = c & 3;
            int kb = kbp ^ ((row >> 1) & 3);
            gload_lds16(Wt + (size_t)(bn + row) * K + k0 + kb * 8, Bls + (size_t)cbase * 8);
        }
        __syncthreads();
        bf16x8 af[2], bfr[4];
        #pragma unroll
        for (int mi = 0; mi < 2; ++mi) {
            int row = wm * 32 + mi * 16 + (lane & 15);
            int kbp = (lane >> 4) ^ ((row >> 1) & 3);
            af[mi] = *reinterpret_cast<const bf16x8*>(Als + row * 32 + kbp * 8);
        }
        #pragma unroll
        for (int nj = 0; nj < 4; ++nj) {
            int row = wn * 64 + nj * 16 + (lane & 15);
            int kbp = (lane >> 4) ^ ((row >> 1) & 3);
            bfr[nj] = *reinterpret_cast<const bf16x8*>(Bls + row * 32 + kbp * 8);
        }
        #pragma unroll
        for (int mi = 0; mi < 2; ++mi)
            #pragma unroll
            for (int nj = 0; nj < 4; ++nj)
                acc[mi][nj] = __builtin_amdgcn_mfma_f32_16x16x32_bf16(af[mi], bfr[nj], acc[mi][nj], 0, 0, 0);
        __syncthreads();
    }

    #pragma unroll
    for (int mi = 0; mi < 2; ++mi) {
        #pragma unroll
        for (int nj = 0; nj < 4; ++nj) {
            int r0 = bm + wm * 32 + mi * 16 + ((lane >> 4) << 2);
            int col = bn + wn * 64 + nj * 16 + (lane & 15);
            if (col >= Nstore) continue;
            #pragma unroll
            for (int j = 0; j < 4; ++j) {
                int row = r0 + j;
                if (row >= M) continue;
                float v = acc[mi][nj][j];
                size_t o = (size_t)row * ldc + col;
                if (MODE == 2) Cf[o] = v + bias[col] + pos[(size_t)(row % L_SEQ) * D_MODEL + col];
                else Cf[o] += v;
            }
        }
    }
}

// ---------------------------------------------------------------------------
__global__ __launch_bounds__(256) void rmsnorm_kernel(
    const float* __restrict__ h, const float* __restrict__ w, bf16* __restrict__ o)
{
    int row = blockIdx.x;
    int tid = threadIdx.x;
    const float* hr = h + (size_t)row * D_MODEL;
    float v0 = hr[tid], v1 = hr[tid + 256];
    float ss = v0 * v0 + v1 * v1;
    #pragma unroll
    for (int off = 32; off; off >>= 1) ss += __shfl_down(ss, off);
    __shared__ float ls[4];
    __shared__ float scale_s;
    if ((tid & 63) == 0) ls[tid >> 6] = ss;
    __syncthreads();
    if (tid == 0) {
        float t = ls[0] + ls[1] + ls[2] + ls[3];
        scale_s = rsqrtf(t * (1.f / D_MODEL) + 1e-5f);
    }
    __syncthreads();
    float sc = scale_s;
    o[(size_t)row * D_MODEL + tid]       = __float2bfloat16(v0 * sc * w[tid]);
    o[(size_t)row * D_MODEL + tid + 256] = __float2bfloat16(v1 * sc * w[tid + 256]);
}

// causal depthwise conv (k=4) + SiLU; also precompute gate g = silu(res).
// writes xs[row][d] bf16 (GEMM A) and udg[row][d].x = pack(u_bf16, g_bf16)
__global__ void conv_silu_kernel(const bf16* __restrict__ xr,
                                 const float* __restrict__ cw,
                                 bf16* __restrict__ xs,
                                 unsigned int* __restrict__ udgx) // stride-2 uints
{
    int idx = blockIdx.x * 256 + threadIdx.x;
    if (idx >= ROWS * D_INNER) return;
    int d = idx & 1023, row = idx >> 10;
    int l = row % L_SEQ;
    const float* w4 = cw + d * 4;
    float acc = 0.f;
    #pragma unroll
    for (int k = 0; k < 4; ++k) {
        int ls = l - 3 + k;
        if (ls >= 0) acc += __bfloat162float(xr[(size_t)(row - 3 + k) * (2 * D_INNER) + d]) * w4[k];
    }
    float v = acc / (1.f + __expf(-acc));
    bf16 ub = __float2bfloat16(v);
    xs[idx] = ub;
    float res = __bfloat162float(xr[(size_t)row * (2 * D_INNER) + D_INNER + d]);
    float g = res / (1.f + __expf(-res));
    __hip_bfloat162 pr;
    pr.x = ub;
    pr.y = __float2bfloat16(g);
    udgx[(size_t)idx * 2] = *reinterpret_cast<unsigned int*>(&pr);
}

// ---------------------------------------------------------------------------
// State-parallel selective scan + gate. 2 states/lane, 8 lanes/channel,
// 32 channels/block (256 thr), grid = 16 x 32 = 512 blocks.
// Per step: one 8B udg load ({u,g} bf16x2 + delta f32) + one 16B bc load.
__global__ __launch_bounds__(256) void scan_sp_kernel(
    const uint2* __restrict__ udg,   // [rows,1024]  {.x = u|g bf16x2, .y = delta f32}
    const float* __restrict__ bc,    // [rows,32]  {B0,C0,B1,C1,...}
    const float* __restrict__ A_log, // [1024,16]
    const float* __restrict__ Dv,    // [1024]
    bf16* __restrict__ y)            // [rows,1024] bf16
{
    int tid = threadIdx.x;
    int n2 = tid & 7, ch = tid >> 3;
    int b = blockIdx.x >> 5;
    int d = (((int)blockIdx.x & 31) << 5) | ch;
    size_t bbase = (size_t)b * L_SEQ;

    float A0 = -__expf(A_log[d * 16 + 2 * n2]);
    float A1 = -__expf(A_log[d * 16 + 2 * n2 + 1]);
    float Dd = Dv[d];
    float s0 = 0.f, s1 = 0.f;

    uint2 uv[8];
    f32x4 bcv[8];

#define LOADSLOT(i, l) { int _l = (l) < L_SEQ ? (l) : L_SEQ - 1; size_t _r = bbase + _l; \
    uv[i]  = udg[_r * 1024 + d]; \
    bcv[i] = *reinterpret_cast<const f32x4*>(bc + _r * 32 + 4 * n2); }

#define STEP(i, l) { \
    float _dl = __uint_as_float(uv[i].y); \
    __hip_bfloat162 _p2 = *reinterpret_cast<__hip_bfloat162*>(&uv[i].x); \
    float _u = __bfloat162float(_p2.x); \
    float _a0 = __expf(_dl * A0), _a1 = __expf(_dl * A1); \
    float _du = _dl * _u; \
    s0 = _a0 * s0 + _du * bcv[i].x; \
    s1 = _a1 * s1 + _du * bcv[i].z; \
    float _p = s0 * bcv[i].y + s1 * bcv[i].w; \
    _p += __int_as_float(__builtin_amdgcn_mov_dpp(__float_as_int(_p), 0xB1, 0xF, 0xF, true)); \
    _p += __int_as_float(__builtin_amdgcn_mov_dpp(__float_as_int(_p), 0x4E, 0xF, 0xF, true)); \
    _p += __int_as_float(__builtin_amdgcn_mov_dpp(__float_as_int(_p), 0x141, 0xF, 0xF, true)); \
    if (n2 == 0) { \
        float _g = __bfloat162float(_p2.y); \
        y[(bbase + (l)) * 1024 + d] = __float2bfloat16((_p + _u * Dd) * _g); \
    } }

    LOADSLOT(0, 0) LOADSLOT(1, 1) LOADSLOT(2, 2) LOADSLOT(3, 3)
    LOADSLOT(4, 4) LOADSLOT(5, 5) LOADSLOT(6, 6) LOADSLOT(7, 7)
    for (int g = 0; g < 24; ++g) {
        int l = g * 8;
        STEP(0, l)     LOADSLOT(0, l + 8)
        STEP(1, l + 1) LOADSLOT(1, l + 9)
        STEP(2, l + 2) LOADSLOT(2, l + 10)
        STEP(3, l + 3) LOADSLOT(3, l + 11)
        STEP(4, l + 4) LOADSLOT(4, l + 12)
        STEP(5, l + 5) LOADSLOT(5, l + 13)
        STEP(6, l + 6) LOADSLOT(6, l + 14)
        STEP(7, l + 7) LOADSLOT(7, l + 15)
    }
    STEP(0, 192) STEP(1, 193) STEP(2, 194) STEP(3, 195)
#undef LOADSLOT
#undef STEP
}

// mean over sequence: h[16,196,512] f32 -> hm[16,512] f32.  grid (2,16)
__global__ __launch_bounds__(256) void mean_kernel(const float* __restrict__ h,
                                                   float* __restrict__ hm) {
    int c = blockIdx.x * 256 + threadIdx.x;
    int b = blockIdx.y;
    const float* hb = h + (size_t)b * L_SEQ * D_MODEL + c;
    float acc = 0.f;
    #pragma unroll 4
    for (int l = 0; l < L_SEQ; ++l) acc += hb[(size_t)l * D_MODEL];
    hm[b * D_MODEL + c] = acc * (1.f / L_SEQ);
}

// head: out[b][c] = hm[b,:] . head_w[:,c] + head_b[c].  grid (4,16)
__global__ __launch_bounds__(256) void head_kernel(
    const float* __restrict__ hm, const float* __restrict__ head_w,
    const float* __restrict__ head_b, float* __restrict__ out)
{
    __shared__ float hmr[D_MODEL];
    int tid = threadIdx.x;
    int b = blockIdx.y;
    hmr[tid]       = hm[b * D_MODEL + tid];
    hmr[tid + 256] = hm[b * D_MODEL + tid + 256];
    __syncthreads();
    int c = blockIdx.x * 256 + tid;
    if (c >= N_CLASSES) return;
    float acc = head_b[c];
    #pragma unroll 8
    for (int k = 0; k < D_MODEL; ++k)
        acc += hmr[k] * head_w[(size_t)k * N_CLASSES + c];
    out[(size_t)b * N_CLASSES + c] = acc;
}

// ---------------------------------------------------------------------------
extern "C" void kernel_launch(void* const* d_in, const int* in_sizes, int n_in,
                              void* d_out, int out_size, void* d_ws, size_t ws_size,
                              hipStream_t stream) {
    const float* x         = (const float*)d_in[0];
    const float* patch_w   = (const float*)d_in[1];
    const float* patch_b   = (const float*)d_in[2];
    const float* norm_w    = (const float*)d_in[3];
    const float* in_proj_w = (const float*)d_in[4];
    const float* conv_w    = (const float*)d_in[5];
    const float* x_proj_w  = (const float*)d_in[6];
    const float* dt_proj_w = (const float*)d_in[7];
    const float* dt_proj_b = (const float*)d_in[8];
    const float* A_log     = (const float*)d_in[9];
    const float* Dv        = (const float*)d_in[10];
    const float* out_proj_w= (const float*)d_in[11];
    const float* head_w    = (const float*)d_in[12];
    const float* head_b    = (const float*)d_in[13];
    float* out = (float*)d_out;

    char* base = (char*)d_ws;
    size_t off = 0;
    auto alloc = [&](size_t bytes) -> void* {
        void* p = base + off;
        off += (bytes + 255) & ~(size_t)255;
        return p;
    };
    float* pos   = (float*)alloc((size_t)L_SEQ * D_MODEL * 4);
    bf16*  pwT   = (bf16*) alloc((size_t)D_MODEL * PATCH_DIM * 2);
    bf16*  inT   = (bf16*) alloc((size_t)N_LAYERS * 2 * D_INNER * D_MODEL * 2);
    bf16*  WtBig = (bf16*) alloc((size_t)N_LAYERS * NBIG * D_INNER * 2);
    bf16*  opT   = (bf16*) alloc((size_t)N_LAYERS * D_MODEL * D_INNER * 2);
    float* h     = (float*)alloc((size_t)ROWS * D_MODEL * 4);
    bf16*  xn    = (bf16*) alloc((size_t)ROWSP * D_MODEL * 2);
    // region shared by patch matrix p (prologue) and xr (layer loop)
    char*  reg0  = (char*) alloc((size_t)ROWSP * 2 * D_INNER * 2);
    bf16*  p     = (bf16*)reg0;
    bf16*  xr    = (bf16*)reg0;
    bf16*  xs    = (bf16*) alloc((size_t)ROWSP * D_INNER * 2);
    uint2* udg   = (uint2*)alloc((size_t)ROWSP * D_INNER * 8);
    float* bcb   = (float*)alloc((size_t)ROWS * 32 * 4);
    bf16*  yb    = (bf16*) alloc((size_t)ROWSP * D_INNER * 2);
    float* hm    = (float*)alloc((size_t)BATCH * D_MODEL * 4);

    // ---- prologue + batched weight prep ----
    posemb_kernel<<<(L_SEQ * D_MODEL + 255) / 256, 256, 0, stream>>>(pos);
    patchify_kernel<<<(ROWS * PATCH_DIM + 255) / 256, 256, 0, stream>>>(x, p);
    transpose_bf16_kernel<<<dim3(16, 24), 256, 0, stream>>>(
        patch_w, pwT, PATCH_DIM, D_MODEL, D_MODEL, 0, 0);
    transpose_bf16_kernel<<<dim3(64, 16, N_LAYERS), 256, 0, stream>>>(
        in_proj_w, inT, D_MODEL, 2 * D_INNER, 2 * D_INNER,
        (size_t)D_MODEL * 2 * D_INNER, (size_t)2 * D_INNER * D_MODEL);
    transpose_bf16_kernel<<<dim3(16, 32, N_LAYERS), 256, 0, stream>>>(
        out_proj_w, opT, D_INNER, D_MODEL, D_MODEL,
        (size_t)D_INNER * D_MODEL, (size_t)D_MODEL * D_INNER);
    wcomb_kernel<<<dim3(64, 64, N_LAYERS), 256, 0, stream>>>(
        x_proj_w, dt_proj_w, WtBig);
    bcw_kernel<<<dim3(128, N_LAYERS), 256, 0, stream>>>(x_proj_w, WtBig);

    // h = p @ patch_w + patch_b + pos   (BM=64 variant, grid (4,50))
    gemm_mfma64<2><<<dim3(D_MODEL / 128, ROWSP / 64), 256, 0, stream>>>(
        p, pwT, PATCH_DIM, D_MODEL, ROWS, D_MODEL, h, patch_b, pos);

    for (int layer = 0; layer < N_LAYERS; ++layer) {
        rmsnorm_kernel<<<ROWS, 256, 0, stream>>>(h, norm_w + layer * D_MODEL, xn);

        // xr = xn @ in_proj  [3136,2048] bf16
        gemm_mfma<0><<<dim3(2 * D_INNER / 128, ROWSP / 128), 256, 0, stream>>>(
            xn, inT + (size_t)layer * 2 * D_INNER * D_MODEL,
            D_MODEL, 2 * D_INNER, ROWS, 2 * D_INNER, nullptr, xr, nullptr, nullptr, nullptr);

        conv_silu_kernel<<<(ROWS * D_INNER) / 256, 256, 0, stream>>>(
            xr, conv_w + (size_t)layer * D_INNER * D_CONV, xs, (unsigned int*)udg);

        // udg.y = softplus(xs @ W_comb + dtb); bc = xs @ xpw[:,32:64] interleaved
        gemm_mfma<4><<<dim3(NBIG / 128, ROWSP / 128), 256, 0, stream>>>(
            xs, WtBig + (size_t)layer * NBIG * D_INNER, D_INNER, 1056, ROWS, 0,
            (float*)udg, nullptr, dt_proj_b + (size_t)layer * D_INNER, nullptr, bcb);

        // state-parallel scan + gate -> yb bf16
        scan_sp_kernel<<<BATCH * (D_INNER / 32), 256, 0, stream>>>(
            udg, bcb,
            A_log + (size_t)layer * D_INNER * D_STATE,
            Dv + (size_t)layer * D_INNER, yb);

        // h += yb @ out_proj   (BM=64 variant, grid (4,50))
        gemm_mfma64<3><<<dim3(D_MODEL / 128, ROWSP / 64), 256, 0, stream>>>(
            yb, opT + (size_t)layer * D_MODEL * D_INNER,
            D_INNER, D_MODEL, ROWS, D_MODEL, h, nullptr, nullptr);
    }

    mean_kernel<<<dim3(2, BATCH), 256, 0, stream>>>(h, hm);
    head_kernel<<<dim3(4, BATCH), 256, 0, stream>>>(hm, head_w, head_b, out);
}

// Round 8
// 627.408 us; speedup vs baseline: 1.8336x; 1.1501x over previous
//
#include <hip/hip_runtime.h>
#include <hip/hip_bf16.h>
#include <math.h>

#define BATCH 16
#define L_SEQ 196
#define PATCH_DIM 768
#define D_MODEL 512
#define D_INNER 1024
#define D_STATE 16
#define D_CONV 4
#define DT_RANK 32
#define N_LAYERS 4
#define N_CLASSES 1000
#define ROWS (BATCH * L_SEQ)   // 3136
#define ROWSP 3200             // padded to multiple of 64
#define NBIG 1152              // delta(1024) + bc(32), padded to 128

typedef __hip_bfloat16 bf16;
typedef __attribute__((ext_vector_type(8))) __bf16 bf16x8;
typedef __attribute__((ext_vector_type(4))) float f32x4;
typedef __attribute__((ext_vector_type(2))) float f32x2;

__device__ __forceinline__ void gload_lds16(const void* g, void* l) {
    __builtin_amdgcn_global_load_lds((const __attribute__((address_space(1))) void*)g,
                                     (__attribute__((address_space(3))) void*)l, 16, 0, 0);
}

// ---------------------------------------------------------------------------
__global__ void posemb_kernel(float* __restrict__ pos) {
    int idx = blockIdx.x * 256 + threadIdx.x;
    if (idx >= L_SEQ * D_MODEL) return;
    int l = idx >> 9, col = idx & 511;
    int q = col >> 7, wi = col & 127;
    float omega = powf(10000.f, -(float)wi / 127.f);
    float yv = (float)(l / 14), xv = (float)(l % 14);
    float arg = (q < 2 ? xv : yv) * omega;
    pos[idx] = (q & 1) ? cosf(arg) : sinf(arg);
}

// patchify: x[B,224,224,3] -> p[3136,768] bf16
__global__ void patchify_kernel(const float* __restrict__ x, bf16* __restrict__ p) {
    int idx = blockIdx.x * 256 + threadIdx.x;
    if (idx >= ROWS * PATCH_DIM) return;
    int k = idx % PATCH_DIM, row = idx / PATCH_DIM;
    int b = row / L_SEQ, l = row % L_SEQ;
    int i = l / 14, j = l % 14;
    int ph = k / 48, r = k % 48, pw = r / 3, c = r % 3;
    size_t src = (((size_t)b * 224 + i * 16 + ph) * 224 + (j * 16 + pw)) * 3 + c;
    p[idx] = __float2bfloat16(x[src]);
}

// transpose-convert: src[K][N] f32 -> dst[Npad][K] bf16 (zero-fill), z = layer
__global__ __launch_bounds__(256) void transpose_bf16_kernel(
    const float* __restrict__ src, bf16* __restrict__ dst,
    int K, int N, int Npad, size_t src_lstride, size_t dst_lstride)
{
    src += (size_t)blockIdx.z * src_lstride;
    dst += (size_t)blockIdx.z * dst_lstride;
    __shared__ float tile[32][33];
    int kb = blockIdx.y * 32, nb = blockIdx.x * 32;
    int tx = threadIdx.x & 31, ty = threadIdx.x >> 5;  // 32 x 8
    #pragma unroll
    for (int i = 0; i < 4; ++i) {
        int k = kb + ty + 8 * i, n = nb + tx;
        tile[ty + 8 * i][tx] = (k < K && n < N) ? src[(size_t)k * N + n] : 0.f;
    }
    __syncthreads();
    #pragma unroll
    for (int i = 0; i < 4; ++i) {
        int n = nb + ty + 8 * i, k = kb + tx;
        if (n < Npad && k < K) dst[(size_t)n * K + k] = __float2bfloat16(tile[tx][ty + 8 * i]);
    }
}

// W_comb^T directly in bf16: Wt[z][n][k] = sum_{r<32} dtw_z[r][n] * xpw_z[k][r]
__global__ __launch_bounds__(256) void wcomb_kernel(
    const float* __restrict__ xpw_all,   // [z][1024][64]
    const float* __restrict__ dtw_all,   // [z][32][1024]
    bf16* __restrict__ WtBig_all)        // [z][NBIG][1024]
{
    int z = blockIdx.z;
    const float* xpw = xpw_all + (size_t)z * D_INNER * 64;
    const float* dtw = dtw_all + (size_t)z * DT_RANK * D_INNER;
    bf16* Wt = WtBig_all + (size_t)z * NBIG * D_INNER;
    __shared__ float sd[32][17];  // [r][n]
    __shared__ float sx[16][33];  // [k][r]
    int n0 = blockIdx.x * 16, k0 = blockIdx.y * 16;
    int tid = threadIdx.x;
    {
        int e = tid;        sd[e >> 4][e & 15] = dtw[(e >> 4) * D_INNER + n0 + (e & 15)];
        e = tid + 256;      sd[e >> 4][e & 15] = dtw[(e >> 4) * D_INNER + n0 + (e & 15)];
    }
    {
        int e = tid;        sx[e >> 5][e & 31] = xpw[(size_t)(k0 + (e >> 5)) * 64 + (e & 31)];
        e = tid + 256;      sx[e >> 5][e & 31] = xpw[(size_t)(k0 + (e >> 5)) * 64 + (e & 31)];
    }
    __syncthreads();
    int nn = tid >> 4, kk = tid & 15;
    float acc = 0.f;
    #pragma unroll
    for (int r = 0; r < 32; ++r) acc += sd[r][nn] * sx[kk][r];
    Wt[(size_t)(n0 + nn) * D_INNER + k0 + kk] = __float2bfloat16(acc);
}

// fill WtBig rows 1024..1055: row 1024+j, col k = xpw[k][(j&1)?48+(j>>1):32+(j>>1)]
__global__ void bcw_kernel(const float* __restrict__ xpw_all, bf16* __restrict__ WtBig_all) {
    int z = blockIdx.y;
    const float* xpw = xpw_all + (size_t)z * D_INNER * 64;
    bf16* WtBig = WtBig_all + (size_t)z * NBIG * D_INNER;
    int idx = blockIdx.x * 256 + threadIdx.x;
    if (idx >= 32 * 1024) return;
    int j = idx >> 10, k = idx & 1023;
    int src = (j & 1) ? 48 + (j >> 1) : 32 + (j >> 1);
    WtBig[(size_t)(1024 + j) * 1024 + k] = __float2bfloat16(xpw[k * 64 + src]);
}

// ---------------------------------------------------------------------------
// Unified bf16 MFMA GEMM: BM=64, BN=128, BK=32, 4 waves (2Mx2N), 16x16x32 MFMA.
// 1D grid with bijective XCD-chunked remap (each XCD gets contiguous row-tiles
// so its private L2 keeps the A-panel + full W resident).
// MODE 0: Cb = bf16(acc)
// MODE 2: Cf = acc + bias[col] + pos[(row%196)*512+col]
// MODE 3: Cf += acc
// MODE 4: col<1024 -> Cf[row*1024+col] = softplus(acc+bias[col])  (delta, contiguous)
//         1024<=col<1056 -> Cf2[row*32 + col-1024] = acc          (bc)
template<int MODE>
__global__ __launch_bounds__(256) void gemm64(
    const bf16* __restrict__ A, const bf16* __restrict__ Wt,
    int K, int gx, int Nstore, int M, int ldc,
    float* __restrict__ Cf, bf16* __restrict__ Cb,
    const float* __restrict__ bias, const float* __restrict__ pos,
    float* __restrict__ Cf2)
{
    // bijective XCD chunk remap (m204): consecutive hw blocks -> same XCD gets
    // a contiguous range of logical wgids.
    int nwg = gridDim.x, bid = blockIdx.x;
    int q = nwg >> 3, r = nwg & 7;
    int xcd = bid & 7, sub = bid >> 3;
    int wgid = (xcd < r ? xcd * (q + 1) : r * (q + 1) + (xcd - r) * q) + sub;
    int bx = wgid % gx, by = wgid / gx;
    int bm = by * 64, bn = bx * 128;

    __shared__ short Als[64 * 32];
    __shared__ short Bls[128 * 32];
    int tid = threadIdx.x;
    int lane = tid & 63, wid = tid >> 6;
    int wm = wid >> 1, wn = wid & 1;   // wm covers 32 rows, wn 64 cols

    f32x4 acc[2][4];
    #pragma unroll
    for (int i = 0; i < 2; ++i)
        #pragma unroll
        for (int j = 0; j < 4; ++j)
            acc[i][j] = (f32x4){0.f, 0.f, 0.f, 0.f};

    for (int k0 = 0; k0 < K; k0 += 32) {
        {   // A tile: 256 chunks of 16B
            int c = tid;
            int row = c >> 2, kbp = c & 3;
            int kb = kbp ^ ((row >> 1) & 3);
            gload_lds16(A + (size_t)(bm + row) * K + k0 + kb * 8, Als + (size_t)(wid * 64) * 8);
        }
        #pragma unroll
        for (int i = 0; i < 2; ++i) {   // B tile: 512 chunks
            int cbase = (i * 4 + wid) * 64;
            int c = cbase + lane;
            int row = c >> 2, kbp = c & 3;
            int kb = kbp ^ ((row >> 1) & 3);
            gload_lds16(Wt + (size_t)(bn + row) * K + k0 + kb * 8, Bls + (size_t)cbase * 8);
        }
        __syncthreads();
        bf16x8 af[2], bfr[4];
        #pragma unroll
        for (int mi = 0; mi < 2; ++mi) {
            int row = wm * 32 + mi * 16 + (lane & 15);
            int kbp = (lane >> 4) ^ ((row >> 1) & 3);
            af[mi] = *reinterpret_cast<const bf16x8*>(Als + row * 32 + kbp * 8);
        }
        #pragma unroll
        for (int nj = 0; nj < 4; ++nj) {
            int row = wn * 64 + nj * 16 + (lane & 15);
            int kbp = (lane >> 4) ^ ((row >> 1) & 3);
            bfr[nj] = *reinterpret_cast<const bf16x8*>(Bls + row * 32 + kbp * 8);
        }
        #pragma unroll
        for (int mi = 0; mi < 2; ++mi)
            #pragma unroll
            for (int nj = 0; nj < 4; ++nj)
                acc[mi][nj] = __builtin_amdgcn_mfma_f32_16x16x32_bf16(af[mi], bfr[nj], acc[mi][nj], 0, 0, 0);
        __syncthreads();
    }

    #pragma unroll
    for (int mi = 0; mi < 2; ++mi) {
        #pragma unroll
        for (int nj = 0; nj < 4; ++nj) {
            int r0 = bm + wm * 32 + mi * 16 + ((lane >> 4) << 2);
            int col = bn + wn * 64 + nj * 16 + (lane & 15);
            if (col >= Nstore) continue;
            #pragma unroll
            for (int j = 0; j < 4; ++j) {
                int row = r0 + j;
                if (row >= M) continue;
                float v = acc[mi][nj][j];
                if (MODE == 4) {
                    if (col < 1024) {
                        float z = v + bias[col];
                        Cf[(size_t)row * 1024 + col] = (z > 20.f) ? z : log1pf(__expf(z));
                    } else {
                        Cf2[(size_t)row * 32 + (col - 1024)] = v;
                    }
                } else {
                    size_t o = (size_t)row * ldc + col;
                    if (MODE == 0) Cb[o] = __float2bfloat16(v);
                    else if (MODE == 2) Cf[o] = v + bias[col] + pos[(size_t)(row % L_SEQ) * D_MODEL + col];
                    else if (MODE == 3) Cf[o] += v;
                }
            }
        }
    }
}

// ---------------------------------------------------------------------------
__global__ __launch_bounds__(256) void rmsnorm_kernel(
    const float* __restrict__ h, const float* __restrict__ w, bf16* __restrict__ o)
{
    int row = blockIdx.x;
    int tid = threadIdx.x;
    const float* hr = h + (size_t)row * D_MODEL;
    float v0 = hr[tid], v1 = hr[tid + 256];
    float ss = v0 * v0 + v1 * v1;
    #pragma unroll
    for (int off = 32; off; off >>= 1) ss += __shfl_down(ss, off);
    __shared__ float ls[4];
    __shared__ float scale_s;
    if ((tid & 63) == 0) ls[tid >> 6] = ss;
    __syncthreads();
    if (tid == 0) {
        float t = ls[0] + ls[1] + ls[2] + ls[3];
        scale_s = rsqrtf(t * (1.f / D_MODEL) + 1e-5f);
    }
    __syncthreads();
    float sc = scale_s;
    o[(size_t)row * D_MODEL + tid]       = __float2bfloat16(v0 * sc * w[tid]);
    o[(size_t)row * D_MODEL + tid + 256] = __float2bfloat16(v1 * sc * w[tid + 256]);
}

// causal depthwise conv (k=4) + SiLU; also precompute gate g = silu(res).
// writes xs[row][d] bf16 (GEMM A) and ug[row][d] = pack(u_bf16, g_bf16) (4B, coalesced)
__global__ void conv_silu_kernel(const bf16* __restrict__ xr,
                                 const float* __restrict__ cw,
                                 bf16* __restrict__ xs,
                                 unsigned int* __restrict__ ug)
{
    int idx = blockIdx.x * 256 + threadIdx.x;
    if (idx >= ROWS * D_INNER) return;
    int d = idx & 1023, row = idx >> 10;
    int l = row % L_SEQ;
    const float* w4 = cw + d * 4;
    float acc = 0.f;
    #pragma unroll
    for (int k = 0; k < 4; ++k) {
        int ls = l - 3 + k;
        if (ls >= 0) acc += __bfloat162float(xr[(size_t)(row - 3 + k) * (2 * D_INNER) + d]) * w4[k];
    }
    float v = acc / (1.f + __expf(-acc));
    bf16 ub = __float2bfloat16(v);
    xs[idx] = ub;
    float res = __bfloat162float(xr[(size_t)row * (2 * D_INNER) + D_INNER + d]);
    float g = res / (1.f + __expf(-res));
    __hip_bfloat162 pr;
    pr.x = ub;
    pr.y = __float2bfloat16(g);
    ug[idx] = *reinterpret_cast<unsigned int*>(&pr);
}

// ---------------------------------------------------------------------------
// State-parallel selective scan + gate. 2 states/lane, 8 lanes/channel,
// 32 channels/block (256 thr), grid = 16 x 32 = 512 blocks.
// Per step: ug 4B + delta 4B + bc 16B loads.
__global__ __launch_bounds__(256) void scan_sp_kernel(
    const unsigned int* __restrict__ ug, // {u,g} bf16x2  [rows,1024]
    const float* __restrict__ delta,     //               [rows,1024] f32
    const float* __restrict__ bc,        // [rows,32]  {B0,C0,B1,C1,...}
    const float* __restrict__ A_log,     // [1024,16]
    const float* __restrict__ Dv,        // [1024]
    bf16* __restrict__ y)                // [rows,1024] bf16
{
    int tid = threadIdx.x;
    int n2 = tid & 7, ch = tid >> 3;
    int b = blockIdx.x >> 5;
    int d = (((int)blockIdx.x & 31) << 5) | ch;
    size_t bbase = (size_t)b * L_SEQ;

    float A0 = -__expf(A_log[d * 16 + 2 * n2]);
    float A1 = -__expf(A_log[d * 16 + 2 * n2 + 1]);
    float Dd = Dv[d];
    float s0 = 0.f, s1 = 0.f;

    unsigned int uv[8];
    float dlv[8];
    f32x4 bcv[8];

#define LOADSLOT(i, l) { int _l = (l) < L_SEQ ? (l) : L_SEQ - 1; size_t _r = bbase + _l; \
    uv[i]  = ug[_r * 1024 + d]; \
    dlv[i] = delta[_r * 1024 + d]; \
    bcv[i] = *reinterpret_cast<const f32x4*>(bc + _r * 32 + 4 * n2); }

#define STEP(i, l) { \
    float _dl = dlv[i]; \
    __hip_bfloat162 _p2 = *reinterpret_cast<__hip_bfloat162*>(&uv[i]); \
    float _u = __bfloat162float(_p2.x); \
    float _a0 = __expf(_dl * A0), _a1 = __expf(_dl * A1); \
    float _du = _dl * _u; \
    s0 = _a0 * s0 + _du * bcv[i].x; \
    s1 = _a1 * s1 + _du * bcv[i].z; \
    float _p = s0 * bcv[i].y + s1 * bcv[i].w; \
    _p += __int_as_float(__builtin_amdgcn_mov_dpp(__float_as_int(_p), 0xB1, 0xF, 0xF, true)); \
    _p += __int_as_float(__builtin_amdgcn_mov_dpp(__float_as_int(_p), 0x4E, 0xF, 0xF, true)); \
    _p += __int_as_float(__builtin_amdgcn_mov_dpp(__float_as_int(_p), 0x141, 0xF, 0xF, true)); \
    if (n2 == 0) { \
        float _g = __bfloat162float(_p2.y); \
        y[(bbase + (l)) * 1024 + d] = __float2bfloat16((_p + _u * Dd) * _g); \
    } }

    LOADSLOT(0, 0) LOADSLOT(1, 1) LOADSLOT(2, 2) LOADSLOT(3, 3)
    LOADSLOT(4, 4) LOADSLOT(5, 5) LOADSLOT(6, 6) LOADSLOT(7, 7)
    for (int g = 0; g < 24; ++g) {
        int l = g * 8;
        STEP(0, l)     LOADSLOT(0, l + 8)
        STEP(1, l + 1) LOADSLOT(1, l + 9)
        STEP(2, l + 2) LOADSLOT(2, l + 10)
        STEP(3, l + 3) LOADSLOT(3, l + 11)
        STEP(4, l + 4) LOADSLOT(4, l + 12)
        STEP(5, l + 5) LOADSLOT(5, l + 13)
        STEP(6, l + 6) LOADSLOT(6, l + 14)
        STEP(7, l + 7) LOADSLOT(7, l + 15)
    }
    STEP(0, 192) STEP(1, 193) STEP(2, 194) STEP(3, 195)
#undef LOADSLOT
#undef STEP
}

// mean over sequence: h[16,196,512] f32 -> hm[16,512] f32.  grid (2,16)
__global__ __launch_bounds__(256) void mean_kernel(const float* __restrict__ h,
                                                   float* __restrict__ hm) {
    int c = blockIdx.x * 256 + threadIdx.x;
    int b = blockIdx.y;
    const float* hb = h + (size_t)b * L_SEQ * D_MODEL + c;
    float acc = 0.f;
    #pragma unroll 4
    for (int l = 0; l < L_SEQ; ++l) acc += hb[(size_t)l * D_MODEL];
    hm[b * D_MODEL + c] = acc * (1.f / L_SEQ);
}

// head: out[b][c] = hm[b,:] . head_w[:,c] + head_b[c].  grid (4,16)
__global__ __launch_bounds__(256) void head_kernel(
    const float* __restrict__ hm, const float* __restrict__ head_w,
    const float* __restrict__ head_b, float* __restrict__ out)
{
    __shared__ float hmr[D_MODEL];
    int tid = threadIdx.x;
    int b = blockIdx.y;
    hmr[tid]       = hm[b * D_MODEL + tid];
    hmr[tid + 256] = hm[b * D_MODEL + tid + 256];
    __syncthreads();
    int c = blockIdx.x * 256 + tid;
    if (c >= N_CLASSES) return;
    float acc = head_b[c];
    #pragma unroll 8
    for (int k = 0; k < D_MODEL; ++k)
        acc += hmr[k] * head_w[(size_t)k * N_CLASSES + c];
    out[(size_t)b * N_CLASSES + c] = acc;
}

// ---------------------------------------------------------------------------
extern "C" void kernel_launch(void* const* d_in, const int* in_sizes, int n_in,
                              void* d_out, int out_size, void* d_ws, size_t ws_size,
                              hipStream_t stream) {
    const float* x         = (const float*)d_in[0];
    const float* patch_w   = (const float*)d_in[1];
    const float* patch_b   = (const float*)d_in[2];
    const float* norm_w    = (const float*)d_in[3];
    const float* in_proj_w = (const float*)d_in[4];
    const float* conv_w    = (const float*)d_in[5];
    const float* x_proj_w  = (const float*)d_in[6];
    const float* dt_proj_w = (const float*)d_in[7];
    const float* dt_proj_b = (const float*)d_in[8];
    const float* A_log     = (const float*)d_in[9];
    const float* Dv        = (const float*)d_in[10];
    const float* out_proj_w= (const float*)d_in[11];
    const float* head_w    = (const float*)d_in[12];
    const float* head_b    = (const float*)d_in[13];
    float* out = (float*)d_out;

    char* base = (char*)d_ws;
    size_t off = 0;
    auto alloc = [&](size_t bytes) -> void* {
        void* p = base + off;
        off += (bytes + 255) & ~(size_t)255;
        return p;
    };
    float* pos   = (float*)alloc((size_t)L_SEQ * D_MODEL * 4);
    bf16*  pwT   = (bf16*) alloc((size_t)D_MODEL * PATCH_DIM * 2);
    bf16*  inT   = (bf16*) alloc((size_t)N_LAYERS * 2 * D_INNER * D_MODEL * 2);
    bf16*  WtBig = (bf16*) alloc((size_t)N_LAYERS * NBIG * D_INNER * 2);
    bf16*  opT   = (bf16*) alloc((size_t)N_LAYERS * D_MODEL * D_INNER * 2);
    float* h     = (float*)alloc((size_t)ROWS * D_MODEL * 4);
    bf16*  xn    = (bf16*) alloc((size_t)ROWSP * D_MODEL * 2);
    // region shared by patch matrix p (prologue) and xr (layer loop)
    char*  reg0  = (char*) alloc((size_t)ROWSP * 2 * D_INNER * 2);
    bf16*  p     = (bf16*)reg0;
    bf16*  xr    = (bf16*)reg0;
    bf16*  xs    = (bf16*) alloc((size_t)ROWSP * D_INNER * 2);
    unsigned int* ug = (unsigned int*)alloc((size_t)ROWSP * D_INNER * 4);
    float* delta = (float*)alloc((size_t)ROWSP * D_INNER * 4);
    float* bcb   = (float*)alloc((size_t)ROWS * 32 * 4);
    bf16*  yb    = (bf16*) alloc((size_t)ROWSP * D_INNER * 2);
    float* hm    = (float*)alloc((size_t)BATCH * D_MODEL * 4);

    // ---- prologue + batched weight prep ----
    posemb_kernel<<<(L_SEQ * D_MODEL + 255) / 256, 256, 0, stream>>>(pos);
    patchify_kernel<<<(ROWS * PATCH_DIM + 255) / 256, 256, 0, stream>>>(x, p);
    transpose_bf16_kernel<<<dim3(16, 24), 256, 0, stream>>>(
        patch_w, pwT, PATCH_DIM, D_MODEL, D_MODEL, 0, 0);
    transpose_bf16_kernel<<<dim3(64, 16, N_LAYERS), 256, 0, stream>>>(
        in_proj_w, inT, D_MODEL, 2 * D_INNER, 2 * D_INNER,
        (size_t)D_MODEL * 2 * D_INNER, (size_t)2 * D_INNER * D_MODEL);
    transpose_bf16_kernel<<<dim3(16, 32, N_LAYERS), 256, 0, stream>>>(
        out_proj_w, opT, D_INNER, D_MODEL, D_MODEL,
        (size_t)D_INNER * D_MODEL, (size_t)D_MODEL * D_INNER);
    wcomb_kernel<<<dim3(64, 64, N_LAYERS), 256, 0, stream>>>(
        x_proj_w, dt_proj_w, WtBig);
    bcw_kernel<<<dim3(128, N_LAYERS), 256, 0, stream>>>(x_proj_w, WtBig);

    // h = p @ patch_w + patch_b + pos   grid 4*50=200
    gemm64<2><<<(D_MODEL / 128) * (ROWSP / 64), 256, 0, stream>>>(
        p, pwT, PATCH_DIM, D_MODEL / 128, D_MODEL, ROWS, D_MODEL,
        h, nullptr, patch_b, pos, nullptr);

    for (int layer = 0; layer < N_LAYERS; ++layer) {
        rmsnorm_kernel<<<ROWS, 256, 0, stream>>>(h, norm_w + layer * D_MODEL, xn);

        // xr = xn @ in_proj  [3136,2048] bf16   grid 16*50=800
        gemm64<0><<<(2 * D_INNER / 128) * (ROWSP / 64), 256, 0, stream>>>(
            xn, inT + (size_t)layer * 2 * D_INNER * D_MODEL,
            D_MODEL, 2 * D_INNER / 128, 2 * D_INNER, ROWS, 2 * D_INNER,
            nullptr, xr, nullptr, nullptr, nullptr);

        conv_silu_kernel<<<(ROWS * D_INNER) / 256, 256, 0, stream>>>(
            xr, conv_w + (size_t)layer * D_INNER * D_CONV, xs, ug);

        // delta = softplus(xs @ W_comb + dtb) (contiguous f32); bc interleaved
        // grid 9*50=450
        gemm64<4><<<(NBIG / 128) * (ROWSP / 64), 256, 0, stream>>>(
            xs, WtBig + (size_t)layer * NBIG * D_INNER,
            D_INNER, NBIG / 128, 1056, ROWS, 0,
            delta, nullptr, dt_proj_b + (size_t)layer * D_INNER, nullptr, bcb);

        // state-parallel scan + gate -> yb bf16
        scan_sp_kernel<<<BATCH * (D_INNER / 32), 256, 0, stream>>>(
            ug, delta, bcb,
            A_log + (size_t)layer * D_INNER * D_STATE,
            Dv + (size_t)layer * D_INNER, yb);

        // h += yb @ out_proj    grid 4*50=200
        gemm64<3><<<(D_MODEL / 128) * (ROWSP / 64), 256, 0, stream>>>(
            yb, opT + (size_t)layer * D_MODEL * D_INNER,
            D_INNER, D_MODEL / 128, D_MODEL, ROWS, D_MODEL,
            h, nullptr, nullptr, nullptr, nullptr);
    }

    mean_kernel<<<dim3(2, BATCH), 256, 0, stream>>>(h, hm);
    head_kernel<<<dim3(4, BATCH), 256, 0, stream>>>(hm, head_w, head_b, out);
}

// Round 9
// 617.749 us; speedup vs baseline: 1.8622x; 1.0156x over previous
//
#include <hip/hip_runtime.h>
#include <hip/hip_bf16.h>
#include <math.h>

#define BATCH 16
#define L_SEQ 196
#define PATCH_DIM 768
#define D_MODEL 512
#define D_INNER 1024
#define D_STATE 16
#define D_CONV 4
#define DT_RANK 32
#define N_LAYERS 4
#define N_CLASSES 1000
#define ROWS (BATCH * L_SEQ)   // 3136
#define ROWSP 3200             // padded to multiple of 64
#define NBIG 1152              // delta(1024) + bc(32), padded to 128

typedef __hip_bfloat16 bf16;
typedef __attribute__((ext_vector_type(8))) __bf16 bf16x8;
typedef __attribute__((ext_vector_type(4))) float f32x4;
typedef __attribute__((ext_vector_type(2))) float f32x2;

__device__ __forceinline__ void gload_lds16(const void* g, void* l) {
    __builtin_amdgcn_global_load_lds((const __attribute__((address_space(1))) void*)g,
                                     (__attribute__((address_space(3))) void*)l, 16, 0, 0);
}

// ---------------------------------------------------------------------------
__global__ void posemb_kernel(float* __restrict__ pos) {
    int idx = blockIdx.x * 256 + threadIdx.x;
    if (idx >= L_SEQ * D_MODEL) return;
    int l = idx >> 9, col = idx & 511;
    int q = col >> 7, wi = col & 127;
    float omega = powf(10000.f, -(float)wi / 127.f);
    float yv = (float)(l / 14), xv = (float)(l % 14);
    float arg = (q < 2 ? xv : yv) * omega;
    pos[idx] = (q & 1) ? cosf(arg) : sinf(arg);
}

// patchify: x[B,224,224,3] -> p[3136,768] bf16
__global__ void patchify_kernel(const float* __restrict__ x, bf16* __restrict__ p) {
    int idx = blockIdx.x * 256 + threadIdx.x;
    if (idx >= ROWS * PATCH_DIM) return;
    int k = idx % PATCH_DIM, row = idx / PATCH_DIM;
    int b = row / L_SEQ, l = row % L_SEQ;
    int i = l / 14, j = l % 14;
    int ph = k / 48, r = k % 48, pw = r / 3, c = r % 3;
    size_t src = (((size_t)b * 224 + i * 16 + ph) * 224 + (j * 16 + pw)) * 3 + c;
    p[idx] = __float2bfloat16(x[src]);
}

// transpose-convert: src[K][N] f32 -> dst[Npad][K] bf16 (zero-fill), z = layer
__global__ __launch_bounds__(256) void transpose_bf16_kernel(
    const float* __restrict__ src, bf16* __restrict__ dst,
    int K, int N, int Npad, size_t src_lstride, size_t dst_lstride)
{
    src += (size_t)blockIdx.z * src_lstride;
    dst += (size_t)blockIdx.z * dst_lstride;
    __shared__ float tile[32][33];
    int kb = blockIdx.y * 32, nb = blockIdx.x * 32;
    int tx = threadIdx.x & 31, ty = threadIdx.x >> 5;  // 32 x 8
    #pragma unroll
    for (int i = 0; i < 4; ++i) {
        int k = kb + ty + 8 * i, n = nb + tx;
        tile[ty + 8 * i][tx] = (k < K && n < N) ? src[(size_t)k * N + n] : 0.f;
    }
    __syncthreads();
    #pragma unroll
    for (int i = 0; i < 4; ++i) {
        int n = nb + ty + 8 * i, k = kb + tx;
        if (n < Npad && k < K) dst[(size_t)n * K + k] = __float2bfloat16(tile[tx][ty + 8 * i]);
    }
}

// W_comb^T directly in bf16: Wt[z][n][k] = sum_{r<32} dtw_z[r][n] * xpw_z[k][r]
__global__ __launch_bounds__(256) void wcomb_kernel(
    const float* __restrict__ xpw_all,   // [z][1024][64]
    const float* __restrict__ dtw_all,   // [z][32][1024]
    bf16* __restrict__ WtBig_all)        // [z][NBIG][1024]
{
    int z = blockIdx.z;
    const float* xpw = xpw_all + (size_t)z * D_INNER * 64;
    const float* dtw = dtw_all + (size_t)z * DT_RANK * D_INNER;
    bf16* Wt = WtBig_all + (size_t)z * NBIG * D_INNER;
    __shared__ float sd[32][17];  // [r][n]
    __shared__ float sx[16][33];  // [k][r]
    int n0 = blockIdx.x * 16, k0 = blockIdx.y * 16;
    int tid = threadIdx.x;
    {
        int e = tid;        sd[e >> 4][e & 15] = dtw[(e >> 4) * D_INNER + n0 + (e & 15)];
        e = tid + 256;      sd[e >> 4][e & 15] = dtw[(e >> 4) * D_INNER + n0 + (e & 15)];
    }
    {
        int e = tid;        sx[e >> 5][e & 31] = xpw[(size_t)(k0 + (e >> 5)) * 64 + (e & 31)];
        e = tid + 256;      sx[e >> 5][e & 31] = xpw[(size_t)(k0 + (e >> 5)) * 64 + (e & 31)];
    }
    __syncthreads();
    int nn = tid >> 4, kk = tid & 15;
    float acc = 0.f;
    #pragma unroll
    for (int r = 0; r < 32; ++r) acc += sd[r][nn] * sx[kk][r];
    Wt[(size_t)(n0 + nn) * D_INNER + k0 + kk] = __float2bfloat16(acc);
}

// fill WtBig rows 1024..1055: row 1024+j, col k = xpw[k][(j&1)?48+(j>>1):32+(j>>1)]
__global__ void bcw_kernel(const float* __restrict__ xpw_all, bf16* __restrict__ WtBig_all) {
    int z = blockIdx.y;
    const float* xpw = xpw_all + (size_t)z * D_INNER * 64;
    bf16* WtBig = WtBig_all + (size_t)z * NBIG * D_INNER;
    int idx = blockIdx.x * 256 + threadIdx.x;
    if (idx >= 32 * 1024) return;
    int j = idx >> 10, k = idx & 1023;
    int src = (j & 1) ? 48 + (j >> 1) : 32 + (j >> 1);
    WtBig[(size_t)(1024 + j) * 1024 + k] = __float2bfloat16(xpw[k * 64 + src]);
}

// ---------------------------------------------------------------------------
// Unified bf16 MFMA GEMM: BM=64, BN=128, BK=32, 4 waves (2Mx2N), 16x16x32 MFMA.
// Double-buffered LDS, prefetch-ahead (T3 2-phase): issue next K-tile's
// global_load_lds BEFORE computing the current tile; one barrier per K-step.
// 1D grid with bijective XCD-chunked remap.
// MODE 0: Cb = bf16(acc)
// MODE 2: Cf = acc + bias[col] + pos[(row%196)*512+col]
// MODE 3: Cf += acc
// MODE 4: col<1024 -> Cf[row*1024+col] = softplus(acc+bias[col])  (delta)
//         1024<=col<1056 -> Cf2[row*32 + col-1024] = acc          (bc)
template<int MODE>
__global__ __launch_bounds__(256) void gemm64(
    const bf16* __restrict__ A, const bf16* __restrict__ Wt,
    int K, int gx, int Nstore, int M, int ldc,
    float* __restrict__ Cf, bf16* __restrict__ Cb,
    const float* __restrict__ bias, const float* __restrict__ pos,
    float* __restrict__ Cf2)
{
    int nwg = gridDim.x, bid = blockIdx.x;
    int q = nwg >> 3, r = nwg & 7;
    int xcd = bid & 7, sub = bid >> 3;
    int wgid = (xcd < r ? xcd * (q + 1) : r * (q + 1) + (xcd - r) * q) + sub;
    int bx = wgid % gx, by = wgid / gx;
    int bm = by * 64, bn = bx * 128;

    __shared__ short Als[2][64 * 32];
    __shared__ short Bls[2][128 * 32];
    int tid = threadIdx.x;
    int lane = tid & 63, wid = tid >> 6;
    int wm = wid >> 1, wn = wid & 1;   // wm covers 32 rows, wn 64 cols

    // hoisted per-thread staging addresses (advance by k0 elements per tile)
    int ra = tid >> 2, kpa = tid & 3;
    int ka = kpa ^ ((ra >> 1) & 3);
    const bf16* gA = A + (size_t)(bm + ra) * K + ka * 8;
    const int adst = wid * 64 * 8;
    int cb0 = wid * 64 + lane;              // chunks 0..255
    int rb0 = cb0 >> 2, kpb0 = cb0 & 3;
    int kb0 = kpb0 ^ ((rb0 >> 1) & 3);
    const bf16* gB0 = Wt + (size_t)(bn + rb0) * K + kb0 * 8;
    int cb1 = (4 + wid) * 64 + lane;        // chunks 256..511
    int rb1 = cb1 >> 2, kpb1 = cb1 & 3;
    int kb1 = kpb1 ^ ((rb1 >> 1) & 3);
    const bf16* gB1 = Wt + (size_t)(bn + rb1) * K + kb1 * 8;
    const int b0dst = wid * 64 * 8, b1dst = (4 + wid) * 64 * 8;

#define STAGE(buf, k0) { \
    gload_lds16(gA + (k0), &Als[buf][adst]); \
    gload_lds16(gB0 + (k0), &Bls[buf][b0dst]); \
    gload_lds16(gB1 + (k0), &Bls[buf][b1dst]); }

    f32x4 acc[2][4];
    #pragma unroll
    for (int i = 0; i < 2; ++i)
        #pragma unroll
        for (int j = 0; j < 4; ++j)
            acc[i][j] = (f32x4){0.f, 0.f, 0.f, 0.f};

    STAGE(0, 0)
    __syncthreads();
    int cur = 0;
    for (int k0 = 0; k0 < K; k0 += 32) {
        if (k0 + 32 < K) STAGE(cur ^ 1, k0 + 32)
        bf16x8 af[2], bfr[4];
        #pragma unroll
        for (int mi = 0; mi < 2; ++mi) {
            int row = wm * 32 + mi * 16 + (lane & 15);
            int kbp = (lane >> 4) ^ ((row >> 1) & 3);
            af[mi] = *reinterpret_cast<const bf16x8*>(&Als[cur][row * 32 + kbp * 8]);
        }
        #pragma unroll
        for (int nj = 0; nj < 4; ++nj) {
            int row = wn * 64 + nj * 16 + (lane & 15);
            int kbp = (lane >> 4) ^ ((row >> 1) & 3);
            bfr[nj] = *reinterpret_cast<const bf16x8*>(&Bls[cur][row * 32 + kbp * 8]);
        }
        #pragma unroll
        for (int mi = 0; mi < 2; ++mi)
            #pragma unroll
            for (int nj = 0; nj < 4; ++nj)
                acc[mi][nj] = __builtin_amdgcn_mfma_f32_16x16x32_bf16(af[mi], bfr[nj], acc[mi][nj], 0, 0, 0);
        __syncthreads();
        cur ^= 1;
    }
#undef STAGE

    #pragma unroll
    for (int mi = 0; mi < 2; ++mi) {
        #pragma unroll
        for (int nj = 0; nj < 4; ++nj) {
            int r0 = bm + wm * 32 + mi * 16 + ((lane >> 4) << 2);
            int col = bn + wn * 64 + nj * 16 + (lane & 15);
            if (col >= Nstore) continue;
            #pragma unroll
            for (int j = 0; j < 4; ++j) {
                int row = r0 + j;
                if (row >= M) continue;
                float v = acc[mi][nj][j];
                if (MODE == 4) {
                    if (col < 1024) {
                        float z = v + bias[col];
                        Cf[(size_t)row * 1024 + col] = (z > 20.f) ? z : log1pf(__expf(z));
                    } else {
                        Cf2[(size_t)row * 32 + (col - 1024)] = v;
                    }
                } else {
                    size_t o = (size_t)row * ldc + col;
                    if (MODE == 0) Cb[o] = __float2bfloat16(v);
                    else if (MODE == 2) Cf[o] = v + bias[col] + pos[(size_t)(row % L_SEQ) * D_MODEL + col];
                    else if (MODE == 3) Cf[o] += v;
                }
            }
        }
    }
}

// ---------------------------------------------------------------------------
__global__ __launch_bounds__(256) void rmsnorm_kernel(
    const float* __restrict__ h, const float* __restrict__ w, bf16* __restrict__ o)
{
    int row = blockIdx.x;
    int tid = threadIdx.x;
    const float* hr = h + (size_t)row * D_MODEL;
    float v0 = hr[tid], v1 = hr[tid + 256];
    float ss = v0 * v0 + v1 * v1;
    #pragma unroll
    for (int off = 32; off; off >>= 1) ss += __shfl_down(ss, off);
    __shared__ float ls[4];
    __shared__ float scale_s;
    if ((tid & 63) == 0) ls[tid >> 6] = ss;
    __syncthreads();
    if (tid == 0) {
        float t = ls[0] + ls[1] + ls[2] + ls[3];
        scale_s = rsqrtf(t * (1.f / D_MODEL) + 1e-5f);
    }
    __syncthreads();
    float sc = scale_s;
    o[(size_t)row * D_MODEL + tid]       = __float2bfloat16(v0 * sc * w[tid]);
    o[(size_t)row * D_MODEL + tid + 256] = __float2bfloat16(v1 * sc * w[tid + 256]);
}

// causal depthwise conv (k=4) + SiLU; also precompute gate g = silu(res).
__global__ void conv_silu_kernel(const bf16* __restrict__ xr,
                                 const float* __restrict__ cw,
                                 bf16* __restrict__ xs,
                                 unsigned int* __restrict__ ug)
{
    int idx = blockIdx.x * 256 + threadIdx.x;
    if (idx >= ROWS * D_INNER) return;
    int d = idx & 1023, row = idx >> 10;
    int l = row % L_SEQ;
    const float* w4 = cw + d * 4;
    float acc = 0.f;
    #pragma unroll
    for (int k = 0; k < 4; ++k) {
        int ls = l - 3 + k;
        if (ls >= 0) acc += __bfloat162float(xr[(size_t)(row - 3 + k) * (2 * D_INNER) + d]) * w4[k];
    }
    float v = acc / (1.f + __expf(-acc));
    bf16 ub = __float2bfloat16(v);
    xs[idx] = ub;
    float res = __bfloat162float(xr[(size_t)row * (2 * D_INNER) + D_INNER + d]);
    float g = res / (1.f + __expf(-res));
    __hip_bfloat162 pr;
    pr.x = ub;
    pr.y = __float2bfloat16(g);
    ug[idx] = *reinterpret_cast<unsigned int*>(&pr);
}

// ---------------------------------------------------------------------------
// State-parallel selective scan + gate. 2 states/lane, 8 lanes/channel,
// 32 channels/block (256 thr), grid = 16 x 32 = 512 blocks.
__global__ __launch_bounds__(256) void scan_sp_kernel(
    const unsigned int* __restrict__ ug, // {u,g} bf16x2  [rows,1024]
    const float* __restrict__ delta,     //               [rows,1024] f32
    const float* __restrict__ bc,        // [rows,32]  {B0,C0,B1,C1,...}
    const float* __restrict__ A_log,     // [1024,16]
    const float* __restrict__ Dv,        // [1024]
    bf16* __restrict__ y)                // [rows,1024] bf16
{
    int tid = threadIdx.x;
    int n2 = tid & 7, ch = tid >> 3;
    int b = blockIdx.x >> 5;
    int d = (((int)blockIdx.x & 31) << 5) | ch;
    size_t bbase = (size_t)b * L_SEQ;

    float A0 = -__expf(A_log[d * 16 + 2 * n2]);
    float A1 = -__expf(A_log[d * 16 + 2 * n2 + 1]);
    float Dd = Dv[d];
    float s0 = 0.f, s1 = 0.f;

    unsigned int uv[8];
    float dlv[8];
    f32x4 bcv[8];

#define LOADSLOT(i, l) { int _l = (l) < L_SEQ ? (l) : L_SEQ - 1; size_t _r = bbase + _l; \
    uv[i]  = ug[_r * 1024 + d]; \
    dlv[i] = delta[_r * 1024 + d]; \
    bcv[i] = *reinterpret_cast<const f32x4*>(bc + _r * 32 + 4 * n2); }

#define STEP(i, l) { \
    float _dl = dlv[i]; \
    __hip_bfloat162 _p2 = *reinterpret_cast<__hip_bfloat162*>(&uv[i]); \
    float _u = __bfloat162float(_p2.x); \
    float _a0 = __expf(_dl * A0), _a1 = __expf(_dl * A1); \
    float _du = _dl * _u; \
    s0 = _a0 * s0 + _du * bcv[i].x; \
    s1 = _a1 * s1 + _du * bcv[i].z; \
    float _p = s0 * bcv[i].y + s1 * bcv[i].w; \
    _p += __int_as_float(__builtin_amdgcn_mov_dpp(__float_as_int(_p), 0xB1, 0xF, 0xF, true)); \
    _p += __int_as_float(__builtin_amdgcn_mov_dpp(__float_as_int(_p), 0x4E, 0xF, 0xF, true)); \
    _p += __int_as_float(__builtin_amdgcn_mov_dpp(__float_as_int(_p), 0x141, 0xF, 0xF, true)); \
    if (n2 == 0) { \
        float _g = __bfloat162float(_p2.y); \
        y[(bbase + (l)) * 1024 + d] = __float2bfloat16((_p + _u * Dd) * _g); \
    } }

    LOADSLOT(0, 0) LOADSLOT(1, 1) LOADSLOT(2, 2) LOADSLOT(3, 3)
    LOADSLOT(4, 4) LOADSLOT(5, 5) LOADSLOT(6, 6) LOADSLOT(7, 7)
    for (int g = 0; g < 24; ++g) {
        int l = g * 8;
        STEP(0, l)     LOADSLOT(0, l + 8)
        STEP(1, l + 1) LOADSLOT(1, l + 9)
        STEP(2, l + 2) LOADSLOT(2, l + 10)
        STEP(3, l + 3) LOADSLOT(3, l + 11)
        STEP(4, l + 4) LOADSLOT(4, l + 12)
        STEP(5, l + 5) LOADSLOT(5, l + 13)
        STEP(6, l + 6) LOADSLOT(6, l + 14)
        STEP(7, l + 7) LOADSLOT(7, l + 15)
    }
    STEP(0, 192) STEP(1, 193) STEP(2, 194) STEP(3, 195)
#undef LOADSLOT
#undef STEP
}

// mean over sequence: h[16,196,512] f32 -> hm[16,512] f32.  grid (2,16)
__global__ __launch_bounds__(256) void mean_kernel(const float* __restrict__ h,
                                                   float* __restrict__ hm) {
    int c = blockIdx.x * 256 + threadIdx.x;
    int b = blockIdx.y;
    const float* hb = h + (size_t)b * L_SEQ * D_MODEL + c;
    float acc = 0.f;
    #pragma unroll 4
    for (int l = 0; l < L_SEQ; ++l) acc += hb[(size_t)l * D_MODEL];
    hm[b * D_MODEL + c] = acc * (1.f / L_SEQ);
}

// head: out[b][c] = hm[b,:] . head_w[:,c] + head_b[c].  grid (4,16)
__global__ __launch_bounds__(256) void head_kernel(
    const float* __restrict__ hm, const float* __restrict__ head_w,
    const float* __restrict__ head_b, float* __restrict__ out)
{
    __shared__ float hmr[D_MODEL];
    int tid = threadIdx.x;
    int b = blockIdx.y;
    hmr[tid]       = hm[b * D_MODEL + tid];
    hmr[tid + 256] = hm[b * D_MODEL + tid + 256];
    __syncthreads();
    int c = blockIdx.x * 256 + tid;
    if (c >= N_CLASSES) return;
    float acc = head_b[c];
    #pragma unroll 8
    for (int k = 0; k < D_MODEL; ++k)
        acc += hmr[k] * head_w[(size_t)k * N_CLASSES + c];
    out[(size_t)b * N_CLASSES + c] = acc;
}

// ---------------------------------------------------------------------------
extern "C" void kernel_launch(void* const* d_in, const int* in_sizes, int n_in,
                              void* d_out, int out_size, void* d_ws, size_t ws_size,
                              hipStream_t stream) {
    const float* x         = (const float*)d_in[0];
    const float* patch_w   = (const float*)d_in[1];
    const float* patch_b   = (const float*)d_in[2];
    const float* norm_w    = (const float*)d_in[3];
    const float* in_proj_w = (const float*)d_in[4];
    const float* conv_w    = (const float*)d_in[5];
    const float* x_proj_w  = (const float*)d_in[6];
    const float* dt_proj_w = (const float*)d_in[7];
    const float* dt_proj_b = (const float*)d_in[8];
    const float* A_log     = (const float*)d_in[9];
    const float* Dv        = (const float*)d_in[10];
    const float* out_proj_w= (const float*)d_in[11];
    const float* head_w    = (const float*)d_in[12];
    const float* head_b    = (const float*)d_in[13];
    float* out = (float*)d_out;

    char* base = (char*)d_ws;
    size_t off = 0;
    auto alloc = [&](size_t bytes) -> void* {
        void* p = base + off;
        off += (bytes + 255) & ~(size_t)255;
        return p;
    };
    float* pos   = (float*)alloc((size_t)L_SEQ * D_MODEL * 4);
    bf16*  pwT   = (bf16*) alloc((size_t)D_MODEL * PATCH_DIM * 2);
    bf16*  inT   = (bf16*) alloc((size_t)N_LAYERS * 2 * D_INNER * D_MODEL * 2);
    bf16*  WtBig = (bf16*) alloc((size_t)N_LAYERS * NBIG * D_INNER * 2);
    bf16*  opT   = (bf16*) alloc((size_t)N_LAYERS * D_MODEL * D_INNER * 2);
    float* h     = (float*)alloc((size_t)ROWS * D_MODEL * 4);
    bf16*  xn    = (bf16*) alloc((size_t)ROWSP * D_MODEL * 2);
    char*  reg0  = (char*) alloc((size_t)ROWSP * 2 * D_INNER * 2);
    bf16*  p     = (bf16*)reg0;
    bf16*  xr    = (bf16*)reg0;
    bf16*  xs    = (bf16*) alloc((size_t)ROWSP * D_INNER * 2);
    unsigned int* ug = (unsigned int*)alloc((size_t)ROWSP * D_INNER * 4);
    float* delta = (float*)alloc((size_t)ROWSP * D_INNER * 4);
    float* bcb   = (float*)alloc((size_t)ROWS * 32 * 4);
    bf16*  yb    = (bf16*) alloc((size_t)ROWSP * D_INNER * 2);
    float* hm    = (float*)alloc((size_t)BATCH * D_MODEL * 4);

    // ---- prologue + batched weight prep ----
    posemb_kernel<<<(L_SEQ * D_MODEL + 255) / 256, 256, 0, stream>>>(pos);
    patchify_kernel<<<(ROWS * PATCH_DIM + 255) / 256, 256, 0, stream>>>(x, p);
    transpose_bf16_kernel<<<dim3(16, 24), 256, 0, stream>>>(
        patch_w, pwT, PATCH_DIM, D_MODEL, D_MODEL, 0, 0);
    transpose_bf16_kernel<<<dim3(64, 16, N_LAYERS), 256, 0, stream>>>(
        in_proj_w, inT, D_MODEL, 2 * D_INNER, 2 * D_INNER,
        (size_t)D_MODEL * 2 * D_INNER, (size_t)2 * D_INNER * D_MODEL);
    transpose_bf16_kernel<<<dim3(16, 32, N_LAYERS), 256, 0, stream>>>(
        out_proj_w, opT, D_INNER, D_MODEL, D_MODEL,
        (size_t)D_INNER * D_MODEL, (size_t)D_MODEL * D_INNER);
    wcomb_kernel<<<dim3(64, 64, N_LAYERS), 256, 0, stream>>>(
        x_proj_w, dt_proj_w, WtBig);
    bcw_kernel<<<dim3(128, N_LAYERS), 256, 0, stream>>>(x_proj_w, WtBig);

    // h = p @ patch_w + patch_b + pos   grid 4*50=200
    gemm64<2><<<(D_MODEL / 128) * (ROWSP / 64), 256, 0, stream>>>(
        p, pwT, PATCH_DIM, D_MODEL / 128, D_MODEL, ROWS, D_MODEL,
        h, nullptr, patch_b, pos, nullptr);

    for (int layer = 0; layer < N_LAYERS; ++layer) {
        rmsnorm_kernel<<<ROWS, 256, 0, stream>>>(h, norm_w + layer * D_MODEL, xn);

        // xr = xn @ in_proj  [3136,2048] bf16   grid 16*50=800
        gemm64<0><<<(2 * D_INNER / 128) * (ROWSP / 64), 256, 0, stream>>>(
            xn, inT + (size_t)layer * 2 * D_INNER * D_MODEL,
            D_MODEL, 2 * D_INNER / 128, 2 * D_INNER, ROWS, 2 * D_INNER,
            nullptr, xr, nullptr, nullptr, nullptr);

        conv_silu_kernel<<<(ROWS * D_INNER) / 256, 256, 0, stream>>>(
            xr, conv_w + (size_t)layer * D_INNER * D_CONV, xs, ug);

        // delta = softplus(xs @ W_comb + dtb); bc interleaved   grid 9*50=450
        gemm64<4><<<(NBIG / 128) * (ROWSP / 64), 256, 0, stream>>>(
            xs, WtBig + (size_t)layer * NBIG * D_INNER,
            D_INNER, NBIG / 128, 1056, ROWS, 0,
            delta, nullptr, dt_proj_b + (size_t)layer * D_INNER, nullptr, bcb);

        // state-parallel scan + gate -> yb bf16
        scan_sp_kernel<<<BATCH * (D_INNER / 32), 256, 0, stream>>>(
            ug, delta, bcb,
            A_log + (size_t)layer * D_INNER * D_STATE,
            Dv + (size_t)layer * D_INNER, yb);

        // h += yb @ out_proj    grid 4*50=200
        gemm64<3><<<(D_MODEL / 128) * (ROWSP / 64), 256, 0, stream>>>(
            yb, opT + (size_t)layer * D_MODEL * D_INNER,
            D_INNER, D_MODEL / 128, D_MODEL, ROWS, D_MODEL,
            h, nullptr, nullptr, nullptr, nullptr);
    }

    mean_kernel<<<dim3(2, BATCH), 256, 0, stream>>>(h, hm);
    head_kernel<<<dim3(4, BATCH), 256, 0, stream>>>(hm, head_w, head_b, out);
}

// Round 10
// 581.344 us; speedup vs baseline: 1.9789x; 1.0626x over previous
//
#include <hip/hip_runtime.h>
#include <hip/hip_bf16.h>
#include <math.h>

#define BATCH 16
#define L_SEQ 196
#define PATCH_DIM 768
#define D_MODEL 512
#define D_INNER 1024
#define D_STATE 16
#define D_CONV 4
#define DT_RANK 32
#define N_LAYERS 4
#define N_CLASSES 1000
#define ROWS (BATCH * L_SEQ)   // 3136
#define ROWSP 3200             // padded to multiple of 64
#define NBIG 1152              // delta(1024) + bc(32), padded to 128

typedef __hip_bfloat16 bf16;
typedef __attribute__((ext_vector_type(8))) __bf16 bf16x8;
typedef __attribute__((ext_vector_type(8))) short short8;
typedef __attribute__((ext_vector_type(4))) float f32x4;

__device__ __forceinline__ void gload_lds16(const void* g, void* l) {
    __builtin_amdgcn_global_load_lds((const __attribute__((address_space(1))) void*)g,
                                     (__attribute__((address_space(3))) void*)l, 16, 0, 0);
}
__device__ __forceinline__ float bfbits2f(int b) {
    return __int_as_float(((unsigned)b & 0xFFFFu) << 16);
}
__device__ __forceinline__ unsigned short f2bfbits(float f) {
    __hip_bfloat16 h = __float2bfloat16(f);
    return *reinterpret_cast<unsigned short*>(&h);
}

// ---------------------------------------------------------------------------
__global__ void posemb_kernel(float* __restrict__ pos) {
    int idx = blockIdx.x * 256 + threadIdx.x;
    if (idx >= L_SEQ * D_MODEL) return;
    int l = idx >> 9, col = idx & 511;
    int q = col >> 7, wi = col & 127;
    float omega = powf(10000.f, -(float)wi / 127.f);
    float yv = (float)(l / 14), xv = (float)(l % 14);
    float arg = (q < 2 ? xv : yv) * omega;
    pos[idx] = (q & 1) ? cosf(arg) : sinf(arg);
}

// patchify: x[B,224,224,3] -> p[3136,768] bf16
__global__ void patchify_kernel(const float* __restrict__ x, bf16* __restrict__ p) {
    int idx = blockIdx.x * 256 + threadIdx.x;
    if (idx >= ROWS * PATCH_DIM) return;
    int k = idx % PATCH_DIM, row = idx / PATCH_DIM;
    int b = row / L_SEQ, l = row % L_SEQ;
    int i = l / 14, j = l % 14;
    int ph = k / 48, r = k % 48, pw = r / 3, c = r % 3;
    size_t src = (((size_t)b * 224 + i * 16 + ph) * 224 + (j * 16 + pw)) * 3 + c;
    p[idx] = __float2bfloat16(x[src]);
}

// transpose-convert: src[K][N] f32 -> dst[Npad][K] bf16 (zero-fill), z = layer
__global__ __launch_bounds__(256) void transpose_bf16_kernel(
    const float* __restrict__ src, bf16* __restrict__ dst,
    int K, int N, int Npad, size_t src_lstride, size_t dst_lstride)
{
    src += (size_t)blockIdx.z * src_lstride;
    dst += (size_t)blockIdx.z * dst_lstride;
    __shared__ float tile[32][33];
    int kb = blockIdx.y * 32, nb = blockIdx.x * 32;
    int tx = threadIdx.x & 31, ty = threadIdx.x >> 5;  // 32 x 8
    #pragma unroll
    for (int i = 0; i < 4; ++i) {
        int k = kb + ty + 8 * i, n = nb + tx;
        tile[ty + 8 * i][tx] = (k < K && n < N) ? src[(size_t)k * N + n] : 0.f;
    }
    __syncthreads();
    #pragma unroll
    for (int i = 0; i < 4; ++i) {
        int n = nb + ty + 8 * i, k = kb + tx;
        if (n < Npad && k < K) dst[(size_t)n * K + k] = __float2bfloat16(tile[tx][ty + 8 * i]);
    }
}

// W_comb^T directly in bf16: Wt[z][n][k] = sum_{r<32} dtw_z[r][n] * xpw_z[k][r]
__global__ __launch_bounds__(256) void wcomb_kernel(
    const float* __restrict__ xpw_all,   // [z][1024][64]
    const float* __restrict__ dtw_all,   // [z][32][1024]
    bf16* __restrict__ WtBig_all)        // [z][NBIG][1024]
{
    int z = blockIdx.z;
    const float* xpw = xpw_all + (size_t)z * D_INNER * 64;
    const float* dtw = dtw_all + (size_t)z * DT_RANK * D_INNER;
    bf16* Wt = WtBig_all + (size_t)z * NBIG * D_INNER;
    __shared__ float sd[32][17];  // [r][n]
    __shared__ float sx[16][33];  // [k][r]
    int n0 = blockIdx.x * 16, k0 = blockIdx.y * 16;
    int tid = threadIdx.x;
    {
        int e = tid;        sd[e >> 4][e & 15] = dtw[(e >> 4) * D_INNER + n0 + (e & 15)];
        e = tid + 256;      sd[e >> 4][e & 15] = dtw[(e >> 4) * D_INNER + n0 + (e & 15)];
    }
    {
        int e = tid;        sx[e >> 5][e & 31] = xpw[(size_t)(k0 + (e >> 5)) * 64 + (e & 31)];
        e = tid + 256;      sx[e >> 5][e & 31] = xpw[(size_t)(k0 + (e >> 5)) * 64 + (e & 31)];
    }
    __syncthreads();
    int nn = tid >> 4, kk = tid & 15;
    float acc = 0.f;
    #pragma unroll
    for (int r = 0; r < 32; ++r) acc += sd[r][nn] * sx[kk][r];
    Wt[(size_t)(n0 + nn) * D_INNER + k0 + kk] = __float2bfloat16(acc);
}

// fill WtBig rows 1024..1055: row 1024+j, col k = xpw[k][(j&1)?48+(j>>1):32+(j>>1)]
__global__ void bcw_kernel(const float* __restrict__ xpw_all, bf16* __restrict__ WtBig_all) {
    int z = blockIdx.y;
    const float* xpw = xpw_all + (size_t)z * D_INNER * 64;
    bf16* WtBig = WtBig_all + (size_t)z * NBIG * D_INNER;
    int idx = blockIdx.x * 256 + threadIdx.x;
    if (idx >= 32 * 1024) return;
    int j = idx >> 10, k = idx & 1023;
    int src = (j & 1) ? 48 + (j >> 1) : 32 + (j >> 1);
    WtBig[(size_t)(1024 + j) * 1024 + k] = __float2bfloat16(xpw[k * 64 + src]);
}

// conv weight transpose: cw[z][1024][4] -> cwT[z][4][1024]
__global__ void cwt_kernel(const float* __restrict__ cw, float* __restrict__ cwT) {
    int z = blockIdx.y;
    int idx = blockIdx.x * 256 + threadIdx.x;
    if (idx >= 4096) return;
    int d = idx >> 2, k = idx & 3;
    cwT[(size_t)z * 4096 + k * 1024 + d] = cw[(size_t)z * 4096 + d * 4 + k];
}

// ---------------------------------------------------------------------------
// Unified bf16 MFMA GEMM: BM=64, BN=128, BK=64, 4 waves (2Mx2N), 16x16x32 MFMA.
// Double-buffered LDS (48KB), prefetch-ahead; one barrier per 64-K step.
// 8-chunk XOR swizzle: LDS chunk (row,kbp) holds global chunk kb = kbp ^ (row&7).
// MODE 0: Cb = bf16(acc); 2: +bias+pos; 3: +=; 4: delta/bc split epilogue.
template<int MODE>
__global__ __launch_bounds__(256) void gemm64(
    const bf16* __restrict__ A, const bf16* __restrict__ Wt,
    int K, int gx, int Nstore, int M, int ldc,
    float* __restrict__ Cf, bf16* __restrict__ Cb,
    const float* __restrict__ bias, const float* __restrict__ pos,
    float* __restrict__ Cf2)
{
    int nwg = gridDim.x, bid = blockIdx.x;
    int q = nwg >> 3, r = nwg & 7;
    int xcd = bid & 7, sub = bid >> 3;
    int wgid = (xcd < r ? xcd * (q + 1) : r * (q + 1) + (xcd - r) * q) + sub;
    int bx = wgid % gx, by = wgid / gx;
    int bm = by * 64, bn = bx * 128;

    __shared__ short Als[2][64 * 64];
    __shared__ short Bls[2][128 * 64];
    int tid = threadIdx.x;
    int lane = tid & 63, wid = tid >> 6;
    int wm = wid >> 1, wn = wid & 1;

    // staging source pointers (per lane) + LDS bases (wave-uniform)
    int t3 = tid >> 3, t7 = tid & 7;
    int rA0 = t3,        kA0 = t7 ^ (rA0 & 7);
    int rA1 = 32 + t3,   kA1 = t7 ^ (rA1 & 7);
    const bf16* gA0 = A + (size_t)(bm + rA0) * K + kA0 * 8;
    const bf16* gA1 = A + (size_t)(bm + rA1) * K + kA1 * 8;
    const int aB0 = (wid * 64) * 8, aB1 = (256 + wid * 64) * 8;
    int rB0 = t3,        kB0 = t7 ^ (rB0 & 7);
    int rB1 = 32 + t3,   kB1 = t7 ^ (rB1 & 7);
    int rB2 = 64 + t3,   kB2 = t7 ^ (rB2 & 7);
    int rB3 = 96 + t3,   kB3 = t7 ^ (rB3 & 7);
    const bf16* gB0 = Wt + (size_t)(bn + rB0) * K + kB0 * 8;
    const bf16* gB1 = Wt + (size_t)(bn + rB1) * K + kB1 * 8;
    const bf16* gB2 = Wt + (size_t)(bn + rB2) * K + kB2 * 8;
    const bf16* gB3 = Wt + (size_t)(bn + rB3) * K + kB3 * 8;
    const int bB0 = (wid * 64) * 8,       bB1 = (256 + wid * 64) * 8;
    const int bB2 = (512 + wid * 64) * 8, bB3 = (768 + wid * 64) * 8;

#define STAGE(buf, k0) { \
    gload_lds16(gA0 + (k0), &Als[buf][aB0]); \
    gload_lds16(gA1 + (k0), &Als[buf][aB1]); \
    gload_lds16(gB0 + (k0), &Bls[buf][bB0]); \
    gload_lds16(gB1 + (k0), &Bls[buf][bB1]); \
    gload_lds16(gB2 + (k0), &Bls[buf][bB2]); \
    gload_lds16(gB3 + (k0), &Bls[buf][bB3]); }

    f32x4 acc[2][4];
    #pragma unroll
    for (int i = 0; i < 2; ++i)
        #pragma unroll
        for (int j = 0; j < 4; ++j)
            acc[i][j] = (f32x4){0.f, 0.f, 0.f, 0.f};

    STAGE(0, 0)
    __syncthreads();
    int cur = 0;
    for (int k0 = 0; k0 < K; k0 += 64) {
        if (k0 + 64 < K) STAGE(cur ^ 1, k0 + 64)
        bf16x8 af[2][2], bfr[2][4];
        #pragma unroll
        for (int kw = 0; kw < 2; ++kw) {
            int kc = kw * 4 + (lane >> 4);
            #pragma unroll
            for (int mi = 0; mi < 2; ++mi) {
                int row = wm * 32 + mi * 16 + (lane & 15);
                int kbp = kc ^ (row & 7);
                af[kw][mi] = *reinterpret_cast<const bf16x8*>(&Als[cur][row * 64 + kbp * 8]);
            }
            #pragma unroll
            for (int nj = 0; nj < 4; ++nj) {
                int row = wn * 64 + nj * 16 + (lane & 15);
                int kbp = kc ^ (row & 7);
                bfr[kw][nj] = *reinterpret_cast<const bf16x8*>(&Bls[cur][row * 64 + kbp * 8]);
            }
        }
        #pragma unroll
        for (int kw = 0; kw < 2; ++kw)
            #pragma unroll
            for (int mi = 0; mi < 2; ++mi)
                #pragma unroll
                for (int nj = 0; nj < 4; ++nj)
                    acc[mi][nj] = __builtin_amdgcn_mfma_f32_16x16x32_bf16(af[kw][mi], bfr[kw][nj], acc[mi][nj], 0, 0, 0);
        __syncthreads();
        cur ^= 1;
    }
#undef STAGE

    #pragma unroll
    for (int mi = 0; mi < 2; ++mi) {
        #pragma unroll
        for (int nj = 0; nj < 4; ++nj) {
            int r0 = bm + wm * 32 + mi * 16 + ((lane >> 4) << 2);
            int col = bn + wn * 64 + nj * 16 + (lane & 15);
            if (col >= Nstore) continue;
            #pragma unroll
            for (int j = 0; j < 4; ++j) {
                int row = r0 + j;
                if (row >= M) continue;
                float v = acc[mi][nj][j];
                if (MODE == 4) {
                    if (col < 1024) {
                        float z = v + bias[col];
                        Cf[(size_t)row * 1024 + col] = (z > 20.f) ? z : log1pf(__expf(z));
                    } else {
                        Cf2[(size_t)row * 32 + (col - 1024)] = v;
                    }
                } else {
                    size_t o = (size_t)row * ldc + col;
                    if (MODE == 0) Cb[o] = __float2bfloat16(v);
                    else if (MODE == 2) Cf[o] = v + bias[col] + pos[(size_t)(row % L_SEQ) * D_MODEL + col];
                    else if (MODE == 3) Cf[o] += v;
                }
            }
        }
    }
}

// ---------------------------------------------------------------------------
__global__ __launch_bounds__(256) void rmsnorm_kernel(
    const float* __restrict__ h, const float* __restrict__ w, bf16* __restrict__ o)
{
    int row = blockIdx.x;
    int tid = threadIdx.x;
    const float* hr = h + (size_t)row * D_MODEL;
    float v0 = hr[tid], v1 = hr[tid + 256];
    float ss = v0 * v0 + v1 * v1;
    #pragma unroll
    for (int off = 32; off; off >>= 1) ss += __shfl_down(ss, off);
    __shared__ float ls[4];
    __shared__ float scale_s;
    if ((tid & 63) == 0) ls[tid >> 6] = ss;
    __syncthreads();
    if (tid == 0) {
        float t = ls[0] + ls[1] + ls[2] + ls[3];
        scale_s = rsqrtf(t * (1.f / D_MODEL) + 1e-5f);
    }
    __syncthreads();
    float sc = scale_s;
    o[(size_t)row * D_MODEL + tid]       = __float2bfloat16(v0 * sc * w[tid]);
    o[(size_t)row * D_MODEL + tid + 256] = __float2bfloat16(v1 * sc * w[tid + 256]);
}

// causal depthwise conv (k=4) + SiLU + gate precompute, vectorized x8 channels.
// cwT: [4][1024] f32.  Writes xs bf16 and ug = pack(u,g) bf16x2.
__global__ __launch_bounds__(256) void conv_silu_kernel(
    const bf16* __restrict__ xr, const float* __restrict__ cwT,
    bf16* __restrict__ xs, unsigned int* __restrict__ ug)
{
    int idx = blockIdx.x * 256 + threadIdx.x;
    if (idx >= ROWS * 128) return;
    int dg = idx & 127, row = idx >> 7;
    int d0 = dg << 3;
    int l = row % L_SEQ;
    float acc[8] = {0.f,0.f,0.f,0.f,0.f,0.f,0.f,0.f};
    #pragma unroll
    for (int k = 0; k < 4; ++k) {
        int ls = l - 3 + k;
        if (ls < 0) continue;
        short8 xv = *reinterpret_cast<const short8*>(xr + (size_t)(row - 3 + k) * 2048 + d0);
        const float* wk = cwT + k * 1024 + d0;
        #pragma unroll
        for (int j = 0; j < 8; ++j)
            acc[j] += bfbits2f(xv[j]) * wk[j];
    }
    short8 rv = *reinterpret_cast<const short8*>(xr + (size_t)row * 2048 + 1024 + d0);
    short8 xsv;
    unsigned ugv[8];
    #pragma unroll
    for (int j = 0; j < 8; ++j) {
        float u = acc[j] / (1.f + __expf(-acc[j]));
        unsigned short ub = f2bfbits(u);
        xsv[j] = (short)ub;
        float res = bfbits2f(rv[j]);
        float g = res / (1.f + __expf(-res));
        ugv[j] = (unsigned)ub | ((unsigned)f2bfbits(g) << 16);
    }
    *reinterpret_cast<short8*>(xs + (size_t)row * 1024 + d0) = xsv;
    uint4* up = reinterpret_cast<uint4*>(ug + (size_t)row * 1024 + d0);
    up[0] = make_uint4(ugv[0], ugv[1], ugv[2], ugv[3]);
    up[1] = make_uint4(ugv[4], ugv[5], ugv[6], ugv[7]);
}

// ---------------------------------------------------------------------------
// State-parallel selective scan + gate. 2 states/lane, 8 lanes/channel,
// 32 channels/block (256 thr), grid = 512 blocks.  Incremental pointers,
// clamp-free main body, statically peeled tail.
__global__ __launch_bounds__(256) void scan_sp_kernel(
    const unsigned int* __restrict__ ug, // {u,g} bf16x2  [rows,1024]
    const float* __restrict__ delta,     //               [rows,1024] f32
    const float* __restrict__ bc,        // [rows,32]  {B0,C0,B1,C1,...}
    const float* __restrict__ A_log,     // [1024,16]
    const float* __restrict__ Dv,        // [1024]
    bf16* __restrict__ y)                // [rows,1024] bf16
{
    int tid = threadIdx.x;
    int n2 = tid & 7, ch = tid >> 3;
    int b = blockIdx.x >> 5;
    int d = (((int)blockIdx.x & 31) << 5) | ch;
    size_t bbase = (size_t)b * L_SEQ;

    float A0 = -__expf(A_log[d * 16 + 2 * n2]);
    float A1 = -__expf(A_log[d * 16 + 2 * n2 + 1]);
    float Dd = Dv[d];
    float s0 = 0.f, s1 = 0.f;

    const unsigned* pu = ug + bbase * 1024 + d;
    const float*    pd = delta + bbase * 1024 + d;
    const float*    pb = bc + bbase * 32 + 4 * n2;
    bf16*           py = y + bbase * 1024 + d;

    unsigned uv[8];
    float dlv[8];
    f32x4 bcv[8];

#define LOADSLOT(i) { \
    uv[i]  = pu[(i) * 1024]; \
    dlv[i] = pd[(i) * 1024]; \
    bcv[i] = *reinterpret_cast<const f32x4*>(pb + (i) * 32); }

#define STEP(i) { \
    float _dl = dlv[i]; \
    float _u  = __int_as_float(uv[i] << 16); \
    float _a0 = __expf(_dl * A0), _a1 = __expf(_dl * A1); \
    float _du = _dl * _u; \
    s0 = _a0 * s0 + _du * bcv[i].x; \
    s1 = _a1 * s1 + _du * bcv[i].z; \
    float _p = s0 * bcv[i].y + s1 * bcv[i].w; \
    _p += __int_as_float(__builtin_amdgcn_mov_dpp(__float_as_int(_p), 0xB1, 0xF, 0xF, true)); \
    _p += __int_as_float(__builtin_amdgcn_mov_dpp(__float_as_int(_p), 0x4E, 0xF, 0xF, true)); \
    _p += __int_as_float(__builtin_amdgcn_mov_dpp(__float_as_int(_p), 0x141, 0xF, 0xF, true)); \
    if (n2 == 0) { \
        float _g = __int_as_float(uv[i] & 0xFFFF0000u); \
        py[(i) * 1024] = __float2bfloat16((_p + _u * Dd) * _g); \
    } }

    // prologue: steps 0..7
    LOADSLOT(0) LOADSLOT(1) LOADSLOT(2) LOADSLOT(3)
    LOADSLOT(4) LOADSLOT(5) LOADSLOT(6) LOADSLOT(7)
    pu += 8 * 1024; pd += 8 * 1024; pb += 8 * 32;

    // groups 0..22: steps 0..183, prefetch through 191
    for (int g = 0; g < 23; ++g) {
        STEP(0) LOADSLOT(0)
        STEP(1) LOADSLOT(1)
        STEP(2) LOADSLOT(2)
        STEP(3) LOADSLOT(3)
        STEP(4) LOADSLOT(4)
        STEP(5) LOADSLOT(5)
        STEP(6) LOADSLOT(6)
        STEP(7) LOADSLOT(7)
        pu += 8 * 1024; pd += 8 * 1024; pb += 8 * 32; py += 8 * 1024;
    }
    // group 23: steps 184..191, prefetch 192..195 into slots 0..3
    STEP(0) LOADSLOT(0)
    STEP(1) LOADSLOT(1)
    STEP(2) LOADSLOT(2)
    STEP(3) LOADSLOT(3)
    STEP(4) STEP(5) STEP(6) STEP(7)
    py += 8 * 1024;
    // tail: steps 192..195
    STEP(0) STEP(1) STEP(2) STEP(3)
#undef LOADSLOT
#undef STEP
}

// mean over sequence: h[16,196,512] f32 -> hm[16,512] f32.  grid (2,16)
__global__ __launch_bounds__(256) void mean_kernel(const float* __restrict__ h,
                                                   float* __restrict__ hm) {
    int c = blockIdx.x * 256 + threadIdx.x;
    int b = blockIdx.y;
    const float* hb = h + (size_t)b * L_SEQ * D_MODEL + c;
    float acc = 0.f;
    #pragma unroll 4
    for (int l = 0; l < L_SEQ; ++l) acc += hb[(size_t)l * D_MODEL];
    hm[b * D_MODEL + c] = acc * (1.f / L_SEQ);
}

// head: out[b][c] = hm[b,:] . head_w[:,c] + head_b[c].  grid (4,16)
__global__ __launch_bounds__(256) void head_kernel(
    const float* __restrict__ hm, const float* __restrict__ head_w,
    const float* __restrict__ head_b, float* __restrict__ out)
{
    __shared__ float hmr[D_MODEL];
    int tid = threadIdx.x;
    int b = blockIdx.y;
    hmr[tid]       = hm[b * D_MODEL + tid];
    hmr[tid + 256] = hm[b * D_MODEL + tid + 256];
    __syncthreads();
    int c = blockIdx.x * 256 + tid;
    if (c >= N_CLASSES) return;
    float acc = head_b[c];
    #pragma unroll 8
    for (int k = 0; k < D_MODEL; ++k)
        acc += hmr[k] * head_w[(size_t)k * N_CLASSES + c];
    out[(size_t)b * N_CLASSES + c] = acc;
}

// ---------------------------------------------------------------------------
extern "C" void kernel_launch(void* const* d_in, const int* in_sizes, int n_in,
                              void* d_out, int out_size, void* d_ws, size_t ws_size,
                              hipStream_t stream) {
    const float* x         = (const float*)d_in[0];
    const float* patch_w   = (const float*)d_in[1];
    const float* patch_b   = (const float*)d_in[2];
    const float* norm_w    = (const float*)d_in[3];
    const float* in_proj_w = (const float*)d_in[4];
    const float* conv_w    = (const float*)d_in[5];
    const float* x_proj_w  = (const float*)d_in[6];
    const float* dt_proj_w = (const float*)d_in[7];
    const float* dt_proj_b = (const float*)d_in[8];
    const float* A_log     = (const float*)d_in[9];
    const float* Dv        = (const float*)d_in[10];
    const float* out_proj_w= (const float*)d_in[11];
    const float* head_w    = (const float*)d_in[12];
    const float* head_b    = (const float*)d_in[13];
    float* out = (float*)d_out;

    char* base = (char*)d_ws;
    size_t off = 0;
    auto alloc = [&](size_t bytes) -> void* {
        void* p = base + off;
        off += (bytes + 255) & ~(size_t)255;
        return p;
    };
    float* pos   = (float*)alloc((size_t)L_SEQ * D_MODEL * 4);
    bf16*  pwT   = (bf16*) alloc((size_t)D_MODEL * PATCH_DIM * 2);
    bf16*  inT   = (bf16*) alloc((size_t)N_LAYERS * 2 * D_INNER * D_MODEL * 2);
    bf16*  WtBig = (bf16*) alloc((size_t)N_LAYERS * NBIG * D_INNER * 2);
    bf16*  opT   = (bf16*) alloc((size_t)N_LAYERS * D_MODEL * D_INNER * 2);
    float* cwT   = (float*)alloc((size_t)N_LAYERS * 4 * D_INNER * 4);
    float* h     = (float*)alloc((size_t)ROWS * D_MODEL * 4);
    bf16*  xn    = (bf16*) alloc((size_t)ROWSP * D_MODEL * 2);
    char*  reg0  = (char*) alloc((size_t)ROWSP * 2 * D_INNER * 2);
    bf16*  p     = (bf16*)reg0;
    bf16*  xr    = (bf16*)reg0;
    bf16*  xs    = (bf16*) alloc((size_t)ROWSP * D_INNER * 2);
    unsigned int* ug = (unsigned int*)alloc((size_t)ROWSP * D_INNER * 4);
    float* delta = (float*)alloc((size_t)ROWSP * D_INNER * 4);
    float* bcb   = (float*)alloc((size_t)ROWS * 32 * 4);
    bf16*  yb    = (bf16*) alloc((size_t)ROWSP * D_INNER * 2);
    float* hm    = (float*)alloc((size_t)BATCH * D_MODEL * 4);

    // ---- prologue + batched weight prep ----
    posemb_kernel<<<(L_SEQ * D_MODEL + 255) / 256, 256, 0, stream>>>(pos);
    patchify_kernel<<<(ROWS * PATCH_DIM + 255) / 256, 256, 0, stream>>>(x, p);
    transpose_bf16_kernel<<<dim3(16, 24), 256, 0, stream>>>(
        patch_w, pwT, PATCH_DIM, D_MODEL, D_MODEL, 0, 0);
    transpose_bf16_kernel<<<dim3(64, 16, N_LAYERS), 256, 0, stream>>>(
        in_proj_w, inT, D_MODEL, 2 * D_INNER, 2 * D_INNER,
        (size_t)D_MODEL * 2 * D_INNER, (size_t)2 * D_INNER * D_MODEL);
    transpose_bf16_kernel<<<dim3(16, 32, N_LAYERS), 256, 0, stream>>>(
        out_proj_w, opT, D_INNER, D_MODEL, D_MODEL,
        (size_t)D_INNER * D_MODEL, (size_t)D_MODEL * D_INNER);
    wcomb_kernel<<<dim3(64, 64, N_LAYERS), 256, 0, stream>>>(
        x_proj_w, dt_proj_w, WtBig);
    bcw_kernel<<<dim3(128, N_LAYERS), 256, 0, stream>>>(x_proj_w, WtBig);
    cwt_kernel<<<dim3(16, N_LAYERS), 256, 0, stream>>>(conv_w, cwT);

    // h = p @ patch_w + patch_b + pos   grid 4*50=200
    gemm64<2><<<(D_MODEL / 128) * (ROWSP / 64), 256, 0, stream>>>(
        p, pwT, PATCH_DIM, D_MODEL / 128, D_MODEL, ROWS, D_MODEL,
        h, nullptr, patch_b, pos, nullptr);

    for (int layer = 0; layer < N_LAYERS; ++layer) {
        rmsnorm_kernel<<<ROWS, 256, 0, stream>>>(h, norm_w + layer * D_MODEL, xn);

        // xr = xn @ in_proj  [3136,2048] bf16   grid 16*50=800
        gemm64<0><<<(2 * D_INNER / 128) * (ROWSP / 64), 256, 0, stream>>>(
            xn, inT + (size_t)layer * 2 * D_INNER * D_MODEL,
            D_MODEL, 2 * D_INNER / 128, 2 * D_INNER, ROWS, 2 * D_INNER,
            nullptr, xr, nullptr, nullptr, nullptr);

        conv_silu_kernel<<<(ROWS * 128 + 255) / 256, 256, 0, stream>>>(
            xr, cwT + (size_t)layer * 4 * D_INNER, xs, ug);

        // delta = softplus(xs @ W_comb + dtb); bc interleaved   grid 9*50=450
        gemm64<4><<<(NBIG / 128) * (ROWSP / 64), 256, 0, stream>>>(
            xs, WtBig + (size_t)layer * NBIG * D_INNER,
            D_INNER, NBIG / 128, 1056, ROWS, 0,
            delta, nullptr, dt_proj_b + (size_t)layer * D_INNER, nullptr, bcb);

        // state-parallel scan + gate -> yb bf16
        scan_sp_kernel<<<BATCH * (D_INNER / 32), 256, 0, stream>>>(
            ug, delta, bcb,
            A_log + (size_t)layer * D_INNER * D_STATE,
            Dv + (size_t)layer * D_INNER, yb);

        // h += yb @ out_proj    grid 4*50=200
        gemm64<3><<<(D_MODEL / 128) * (ROWSP / 64), 256, 0, stream>>>(
            yb, opT + (size_t)layer * D_MODEL * D_INNER,
            D_INNER, D_MODEL / 128, D_MODEL, ROWS, D_MODEL,
            h, nullptr, nullptr, nullptr, nullptr);
    }

    mean_kernel<<<dim3(2, BATCH), 256, 0, stream>>>(h, hm);
    head_kernel<<<dim3(4, BATCH), 256, 0, stream>>>(hm, head_w, head_b, out);
}

// Round 11
// 552.580 us; speedup vs baseline: 2.0819x; 1.0521x over previous
//
#include <hip/hip_runtime.h>
#include <hip/hip_bf16.h>
#include <math.h>

#define BATCH 16
#define L_SEQ 196
#define PATCH_DIM 768
#define D_MODEL 512
#define D_INNER 1024
#define D_STATE 16
#define D_CONV 4
#define DT_RANK 32
#define N_LAYERS 4
#define N_CLASSES 1000
#define ROWS (BATCH * L_SEQ)   // 3136
#define ROWSP 3200             // padded (multiple of 64)
#define NBIG 1152              // delta(1024) + bc(32), padded to 128

typedef __hip_bfloat16 bf16;
typedef __attribute__((ext_vector_type(8))) __bf16 bf16x8;
typedef __attribute__((ext_vector_type(8))) short short8;
typedef __attribute__((ext_vector_type(4))) float f32x4;

__device__ __forceinline__ void gload_lds16(const void* g, void* l) {
    __builtin_amdgcn_global_load_lds((const __attribute__((address_space(1))) void*)g,
                                     (__attribute__((address_space(3))) void*)l, 16, 0, 0);
}
__device__ __forceinline__ float bfbits2f(int b) {
    return __int_as_float(((unsigned)b & 0xFFFFu) << 16);
}
__device__ __forceinline__ unsigned short f2bfbits(float f) {
    __hip_bfloat16 h = __float2bfloat16(f);
    return *reinterpret_cast<unsigned short*>(&h);
}

// ---------------------------------------------------------------------------
__global__ void posemb_kernel(float* __restrict__ pos) {
    int idx = blockIdx.x * 256 + threadIdx.x;
    if (idx >= L_SEQ * D_MODEL) return;
    int l = idx >> 9, col = idx & 511;
    int q = col >> 7, wi = col & 127;
    float omega = powf(10000.f, -(float)wi / 127.f);
    float yv = (float)(l / 14), xv = (float)(l % 14);
    float arg = (q < 2 ? xv : yv) * omega;
    pos[idx] = (q & 1) ? cosf(arg) : sinf(arg);
}

// patchify: x[B,224,224,3] -> p[3136,768] bf16
__global__ void patchify_kernel(const float* __restrict__ x, bf16* __restrict__ p) {
    int idx = blockIdx.x * 256 + threadIdx.x;
    if (idx >= ROWS * PATCH_DIM) return;
    int k = idx % PATCH_DIM, row = idx / PATCH_DIM;
    int b = row / L_SEQ, l = row % L_SEQ;
    int i = l / 14, j = l % 14;
    int ph = k / 48, r = k % 48, pw = r / 3, c = r % 3;
    size_t src = (((size_t)b * 224 + i * 16 + ph) * 224 + (j * 16 + pw)) * 3 + c;
    p[idx] = __float2bfloat16(x[src]);
}

// transpose-convert: src[K][N] f32 -> dst[Npad][K] bf16 (zero-fill), z = layer
__global__ __launch_bounds__(256) void transpose_bf16_kernel(
    const float* __restrict__ src, bf16* __restrict__ dst,
    int K, int N, int Npad, size_t src_lstride, size_t dst_lstride)
{
    src += (size_t)blockIdx.z * src_lstride;
    dst += (size_t)blockIdx.z * dst_lstride;
    __shared__ float tile[32][33];
    int kb = blockIdx.y * 32, nb = blockIdx.x * 32;
    int tx = threadIdx.x & 31, ty = threadIdx.x >> 5;  // 32 x 8
    #pragma unroll
    for (int i = 0; i < 4; ++i) {
        int k = kb + ty + 8 * i, n = nb + tx;
        tile[ty + 8 * i][tx] = (k < K && n < N) ? src[(size_t)k * N + n] : 0.f;
    }
    __syncthreads();
    #pragma unroll
    for (int i = 0; i < 4; ++i) {
        int n = nb + ty + 8 * i, k = kb + tx;
        if (n < Npad && k < K) dst[(size_t)n * K + k] = __float2bfloat16(tile[tx][ty + 8 * i]);
    }
}

// W_comb^T directly in bf16: Wt[z][n][k] = sum_{r<32} dtw_z[r][n] * xpw_z[k][r]
__global__ __launch_bounds__(256) void wcomb_kernel(
    const float* __restrict__ xpw_all,   // [z][1024][64]
    const float* __restrict__ dtw_all,   // [z][32][1024]
    bf16* __restrict__ WtBig_all)        // [z][NBIG][1024]
{
    int z = blockIdx.z;
    const float* xpw = xpw_all + (size_t)z * D_INNER * 64;
    const float* dtw = dtw_all + (size_t)z * DT_RANK * D_INNER;
    bf16* Wt = WtBig_all + (size_t)z * NBIG * D_INNER;
    __shared__ float sd[32][17];  // [r][n]
    __shared__ float sx[16][33];  // [k][r]
    int n0 = blockIdx.x * 16, k0 = blockIdx.y * 16;
    int tid = threadIdx.x;
    {
        int e = tid;        sd[e >> 4][e & 15] = dtw[(e >> 4) * D_INNER + n0 + (e & 15)];
        e = tid + 256;      sd[e >> 4][e & 15] = dtw[(e >> 4) * D_INNER + n0 + (e & 15)];
    }
    {
        int e = tid;        sx[e >> 5][e & 31] = xpw[(size_t)(k0 + (e >> 5)) * 64 + (e & 31)];
        e = tid + 256;      sx[e >> 5][e & 31] = xpw[(size_t)(k0 + (e >> 5)) * 64 + (e & 31)];
    }
    __syncthreads();
    int nn = tid >> 4, kk = tid & 15;
    float acc = 0.f;
    #pragma unroll
    for (int r = 0; r < 32; ++r) acc += sd[r][nn] * sx[kk][r];
    Wt[(size_t)(n0 + nn) * D_INNER + k0 + kk] = __float2bfloat16(acc);
}

// fill WtBig rows 1024..1055: row 1024+j, col k = xpw[k][(j&1)?48+(j>>1):32+(j>>1)]
__global__ void bcw_kernel(const float* __restrict__ xpw_all, bf16* __restrict__ WtBig_all) {
    int z = blockIdx.y;
    const float* xpw = xpw_all + (size_t)z * D_INNER * 64;
    bf16* WtBig = WtBig_all + (size_t)z * NBIG * D_INNER;
    int idx = blockIdx.x * 256 + threadIdx.x;
    if (idx >= 32 * 1024) return;
    int j = idx >> 10, k = idx & 1023;
    int src = (j & 1) ? 48 + (j >> 1) : 32 + (j >> 1);
    WtBig[(size_t)(1024 + j) * 1024 + k] = __float2bfloat16(xpw[k * 64 + src]);
}

// conv weight transpose: cw[z][1024][4] -> cwT[z][4][1024]
__global__ void cwt_kernel(const float* __restrict__ cw, float* __restrict__ cwT) {
    int z = blockIdx.y;
    int idx = blockIdx.x * 256 + threadIdx.x;
    if (idx >= 4096) return;
    int d = idx >> 2, k = idx & 3;
    cwT[(size_t)z * 4096 + k * 1024 + d] = cw[(size_t)z * 4096 + d * 4 + k];
}

// ---------------------------------------------------------------------------
// Unified bf16 MFMA GEMM: BM∈{32,64}, BN=128, BK=64, 4 waves (2Mx2N), 16x16x32.
// Double-buffered LDS with COUNTED vmcnt (T4): raw s_barrier, next-tile loads
// stay in flight across the barrier.  8-chunk XOR swizzle on K.
// MODE 0: Cb = bf16(acc); 2: +bias+pos; 3: +=; 4: delta/bc split epilogue.
template<int MODE, int BM>
__global__ __launch_bounds__(256) void gemm64(
    const bf16* __restrict__ A, const bf16* __restrict__ Wt,
    int K, int gx, int Nstore, int M, int ldc,
    float* __restrict__ Cf, bf16* __restrict__ Cb,
    const float* __restrict__ bias, const float* __restrict__ pos,
    float* __restrict__ Cf2)
{
    constexpr int MI = BM / 32;              // acc row-fragments per wave
    constexpr int NL = 4 + 2 * MI;           // loads per STAGE (A: MI*? -> 2 or 1; B: 4)
    int nwg = gridDim.x, bid = blockIdx.x;
    int q = nwg >> 3, r = nwg & 7;
    int xcd = bid & 7, sub = bid >> 3;
    int wgid = (xcd < r ? xcd * (q + 1) : r * (q + 1) + (xcd - r) * q) + sub;
    int bx = wgid % gx, by = wgid / gx;
    int bm = by * BM, bn = bx * 128;

    __shared__ short Als[2][BM * 64];
    __shared__ short Bls[2][128 * 64];
    int tid = threadIdx.x;
    int lane = tid & 63, wid = tid >> 6;
    int wm = wid >> 1, wn = wid & 1;

    // staging source pointers (per lane) + LDS offsets
    int t3 = tid >> 3, t7 = tid & 7;
    int rA0 = t3,      kA0 = t7 ^ (rA0 & 7);
    int rA1 = 32 + t3, kA1 = t7 ^ (rA1 & 7);
    const bf16* gA0 = A + (size_t)(bm + rA0) * K + kA0 * 8;
    const bf16* gA1 = A + (size_t)(bm + rA1) * K + kA1 * 8;   // used only if BM==64
    const int aB0 = (wid * 64) * 8, aB1 = (256 + wid * 64) * 8;
    int rB0 = t3,      kB0 = t7 ^ (rB0 & 7);
    int rB1 = 32 + t3, kB1 = t7 ^ (rB1 & 7);
    int rB2 = 64 + t3, kB2 = t7 ^ (rB2 & 7);
    int rB3 = 96 + t3, kB3 = t7 ^ (rB3 & 7);
    const bf16* gB0 = Wt + (size_t)(bn + rB0) * K + kB0 * 8;
    const bf16* gB1 = Wt + (size_t)(bn + rB1) * K + kB1 * 8;
    const bf16* gB2 = Wt + (size_t)(bn + rB2) * K + kB2 * 8;
    const bf16* gB3 = Wt + (size_t)(bn + rB3) * K + kB3 * 8;
    const int bB0 = (wid * 64) * 8,       bB1 = (256 + wid * 64) * 8;
    const int bB2 = (512 + wid * 64) * 8, bB3 = (768 + wid * 64) * 8;

    auto stage = [&](int buf, int k0) {
        gload_lds16(gA0 + k0, &Als[buf][aB0]);
        if (BM == 64) gload_lds16(gA1 + k0, &Als[buf][aB1]);
        gload_lds16(gB0 + k0, &Bls[buf][bB0]);
        gload_lds16(gB1 + k0, &Bls[buf][bB1]);
        gload_lds16(gB2 + k0, &Bls[buf][bB2]);
        gload_lds16(gB3 + k0, &Bls[buf][bB3]);
    };

    f32x4 acc[MI][4];
    #pragma unroll
    for (int i = 0; i < MI; ++i)
        #pragma unroll
        for (int j = 0; j < 4; ++j)
            acc[i][j] = (f32x4){0.f, 0.f, 0.f, 0.f};

    stage(0, 0);
    int cur = 0;
    for (int k0 = 0; k0 < K; k0 += 64) {
        if (k0 + 64 < K) {
            stage(cur ^ 1, k0 + 64);
            __builtin_amdgcn_sched_barrier(0);
            // prev tile's NL loads complete; the NL just issued stay in flight
            asm volatile("s_waitcnt vmcnt(%0)" :: "n"(NL) : "memory");
        } else {
            asm volatile("s_waitcnt vmcnt(0)" ::: "memory");
        }
        __builtin_amdgcn_s_barrier();        // buf[cur] ready for all waves
        __builtin_amdgcn_sched_barrier(0);

        bf16x8 af[2][MI], bfr[2][4];
        #pragma unroll
        for (int kw = 0; kw < 2; ++kw) {
            int kc = kw * 4 + (lane >> 4);
            #pragma unroll
            for (int mi = 0; mi < MI; ++mi) {
                int row = wm * (BM / 2) + mi * 16 + (lane & 15);
                int kbp = kc ^ (row & 7);
                af[kw][mi] = *reinterpret_cast<const bf16x8*>(&Als[cur][row * 64 + kbp * 8]);
            }
            #pragma unroll
            for (int nj = 0; nj < 4; ++nj) {
                int row = wn * 64 + nj * 16 + (lane & 15);
                int kbp = kc ^ (row & 7);
                bfr[kw][nj] = *reinterpret_cast<const bf16x8*>(&Bls[cur][row * 64 + kbp * 8]);
            }
        }
        #pragma unroll
        for (int kw = 0; kw < 2; ++kw)
            #pragma unroll
            for (int mi = 0; mi < MI; ++mi)
                #pragma unroll
                for (int nj = 0; nj < 4; ++nj)
                    acc[mi][nj] = __builtin_amdgcn_mfma_f32_16x16x32_bf16(af[kw][mi], bfr[kw][nj], acc[mi][nj], 0, 0, 0);

        __builtin_amdgcn_sched_barrier(0);
        __builtin_amdgcn_s_barrier();        // buf[cur] free to overwrite next iter
        cur ^= 1;
    }

    #pragma unroll
    for (int mi = 0; mi < MI; ++mi) {
        #pragma unroll
        for (int nj = 0; nj < 4; ++nj) {
            int r0 = bm + wm * (BM / 2) + mi * 16 + ((lane >> 4) << 2);
            int col = bn + wn * 64 + nj * 16 + (lane & 15);
            if (col >= Nstore) continue;
            #pragma unroll
            for (int j = 0; j < 4; ++j) {
                int row = r0 + j;
                if (row >= M) continue;
                float v = acc[mi][nj][j];
                if (MODE == 4) {
                    if (col < 1024) {
                        float z = v + bias[col];
                        Cf[(size_t)row * 1024 + col] = (z > 20.f) ? z : log1pf(__expf(z));
                    } else {
                        Cf2[(size_t)row * 32 + (col - 1024)] = v;
                    }
                } else {
                    size_t o = (size_t)row * ldc + col;
                    if (MODE == 0) Cb[o] = __float2bfloat16(v);
                    else if (MODE == 2) Cf[o] = v + bias[col] + pos[(size_t)(row % L_SEQ) * D_MODEL + col];
                    else if (MODE == 3) Cf[o] += v;
                }
            }
        }
    }
}

// ---------------------------------------------------------------------------
__global__ __launch_bounds__(256) void rmsnorm_kernel(
    const float* __restrict__ h, const float* __restrict__ w, bf16* __restrict__ o)
{
    int row = blockIdx.x;
    int tid = threadIdx.x;
    const float* hr = h + (size_t)row * D_MODEL;
    float v0 = hr[tid], v1 = hr[tid + 256];
    float ss = v0 * v0 + v1 * v1;
    #pragma unroll
    for (int off = 32; off; off >>= 1) ss += __shfl_down(ss, off);
    __shared__ float ls[4];
    __shared__ float scale_s;
    if ((tid & 63) == 0) ls[tid >> 6] = ss;
    __syncthreads();
    if (tid == 0) {
        float t = ls[0] + ls[1] + ls[2] + ls[3];
        scale_s = rsqrtf(t * (1.f / D_MODEL) + 1e-5f);
    }
    __syncthreads();
    float sc = scale_s;
    o[(size_t)row * D_MODEL + tid]       = __float2bfloat16(v0 * sc * w[tid]);
    o[(size_t)row * D_MODEL + tid + 256] = __float2bfloat16(v1 * sc * w[tid + 256]);
}

// causal depthwise conv (k=4) + SiLU + gate precompute, vectorized x8 channels.
__global__ __launch_bounds__(256) void conv_silu_kernel(
    const bf16* __restrict__ xr, const float* __restrict__ cwT,
    bf16* __restrict__ xs, unsigned int* __restrict__ ug)
{
    int idx = blockIdx.x * 256 + threadIdx.x;
    if (idx >= ROWS * 128) return;
    int dg = idx & 127, row = idx >> 7;
    int d0 = dg << 3;
    int l = row % L_SEQ;
    float acc[8] = {0.f,0.f,0.f,0.f,0.f,0.f,0.f,0.f};
    #pragma unroll
    for (int k = 0; k < 4; ++k) {
        int ls = l - 3 + k;
        if (ls < 0) continue;
        short8 xv = *reinterpret_cast<const short8*>(xr + (size_t)(row - 3 + k) * 2048 + d0);
        const float* wk = cwT + k * 1024 + d0;
        #pragma unroll
        for (int j = 0; j < 8; ++j)
            acc[j] += bfbits2f(xv[j]) * wk[j];
    }
    short8 rv = *reinterpret_cast<const short8*>(xr + (size_t)row * 2048 + 1024 + d0);
    short8 xsv;
    unsigned ugv[8];
    #pragma unroll
    for (int j = 0; j < 8; ++j) {
        float u = acc[j] / (1.f + __expf(-acc[j]));
        unsigned short ub = f2bfbits(u);
        xsv[j] = (short)ub;
        float res = bfbits2f(rv[j]);
        float g = res / (1.f + __expf(-res));
        ugv[j] = (unsigned)ub | ((unsigned)f2bfbits(g) << 16);
    }
    *reinterpret_cast<short8*>(xs + (size_t)row * 1024 + d0) = xsv;
    uint4* up = reinterpret_cast<uint4*>(ug + (size_t)row * 1024 + d0);
    up[0] = make_uint4(ugv[0], ugv[1], ugv[2], ugv[3]);
    up[1] = make_uint4(ugv[4], ugv[5], ugv[6], ugv[7]);
}

// ---------------------------------------------------------------------------
// State-parallel selective scan + gate. 2 states/lane, 8 lanes/channel,
// 32 channels/block (256 thr), grid = 512 blocks.  exp2-folded A constants.
__global__ __launch_bounds__(256) void scan_sp_kernel(
    const unsigned int* __restrict__ ug, // {u,g} bf16x2  [rows,1024]
    const float* __restrict__ delta,     //               [rows,1024] f32
    const float* __restrict__ bc,        // [rows,32]  {B0,C0,B1,C1,...}
    const float* __restrict__ A_log,     // [1024,16]
    const float* __restrict__ Dv,        // [1024]
    bf16* __restrict__ y)                // [rows,1024] bf16
{
    int tid = threadIdx.x;
    int n2 = tid & 7, ch = tid >> 3;
    int b = blockIdx.x >> 5;
    int d = (((int)blockIdx.x & 31) << 5) | ch;
    size_t bbase = (size_t)b * L_SEQ;

    const float L2E = 1.4426950408889634f;
    float A0 = -__expf(A_log[d * 16 + 2 * n2]) * L2E;
    float A1 = -__expf(A_log[d * 16 + 2 * n2 + 1]) * L2E;
    float Dd = Dv[d];
    float s0 = 0.f, s1 = 0.f;

    const unsigned* pu = ug + bbase * 1024 + d;
    const float*    pd = delta + bbase * 1024 + d;
    const float*    pb = bc + bbase * 32 + 4 * n2;
    bf16*           py = y + bbase * 1024 + d;

    unsigned uv[8];
    float dlv[8];
    f32x4 bcv[8];

#define LOADSLOT(i) { \
    uv[i]  = pu[(i) * 1024]; \
    dlv[i] = pd[(i) * 1024]; \
    bcv[i] = *reinterpret_cast<const f32x4*>(pb + (i) * 32); }

#define STEP(i) { \
    float _dl = dlv[i]; \
    float _u  = __int_as_float(uv[i] << 16); \
    float _a0 = __builtin_amdgcn_exp2f(_dl * A0); \
    float _a1 = __builtin_amdgcn_exp2f(_dl * A1); \
    float _du = _dl * _u; \
    s0 = _a0 * s0 + _du * bcv[i].x; \
    s1 = _a1 * s1 + _du * bcv[i].z; \
    float _p = s0 * bcv[i].y + s1 * bcv[i].w; \
    _p += __int_as_float(__builtin_amdgcn_mov_dpp(__float_as_int(_p), 0xB1, 0xF, 0xF, true)); \
    _p += __int_as_float(__builtin_amdgcn_mov_dpp(__float_as_int(_p), 0x4E, 0xF, 0xF, true)); \
    _p += __int_as_float(__builtin_amdgcn_mov_dpp(__float_as_int(_p), 0x141, 0xF, 0xF, true)); \
    if (n2 == 0) { \
        float _g = __int_as_float(uv[i] & 0xFFFF0000u); \
        py[(i) * 1024] = __float2bfloat16((_p + _u * Dd) * _g); \
    } }

    LOADSLOT(0) LOADSLOT(1) LOADSLOT(2) LOADSLOT(3)
    LOADSLOT(4) LOADSLOT(5) LOADSLOT(6) LOADSLOT(7)
    pu += 8 * 1024; pd += 8 * 1024; pb += 8 * 32;

    for (int g = 0; g < 23; ++g) {
        STEP(0) LOADSLOT(0)
        STEP(1) LOADSLOT(1)
        STEP(2) LOADSLOT(2)
        STEP(3) LOADSLOT(3)
        STEP(4) LOADSLOT(4)
        STEP(5) LOADSLOT(5)
        STEP(6) LOADSLOT(6)
        STEP(7) LOADSLOT(7)
        pu += 8 * 1024; pd += 8 * 1024; pb += 8 * 32; py += 8 * 1024;
    }
    STEP(0) LOADSLOT(0)
    STEP(1) LOADSLOT(1)
    STEP(2) LOADSLOT(2)
    STEP(3) LOADSLOT(3)
    STEP(4) STEP(5) STEP(6) STEP(7)
    py += 8 * 1024;
    STEP(0) STEP(1) STEP(2) STEP(3)
#undef LOADSLOT
#undef STEP
}

// mean over sequence: h[16,196,512] f32 -> hm[16,512] f32.  grid (2,16)
__global__ __launch_bounds__(256) void mean_kernel(const float* __restrict__ h,
                                                   float* __restrict__ hm) {
    int c = blockIdx.x * 256 + threadIdx.x;
    int b = blockIdx.y;
    const float* hb = h + (size_t)b * L_SEQ * D_MODEL + c;
    float acc = 0.f;
    #pragma unroll 4
    for (int l = 0; l < L_SEQ; ++l) acc += hb[(size_t)l * D_MODEL];
    hm[b * D_MODEL + c] = acc * (1.f / L_SEQ);
}

// head: out[b][c] = hm[b,:] . head_w[:,c] + head_b[c].  grid (4,16)
__global__ __launch_bounds__(256) void head_kernel(
    const float* __restrict__ hm, const float* __restrict__ head_w,
    const float* __restrict__ head_b, float* __restrict__ out)
{
    __shared__ float hmr[D_MODEL];
    int tid = threadIdx.x;
    int b = blockIdx.y;
    hmr[tid]       = hm[b * D_MODEL + tid];
    hmr[tid + 256] = hm[b * D_MODEL + tid + 256];
    __syncthreads();
    int c = blockIdx.x * 256 + tid;
    if (c >= N_CLASSES) return;
    float acc = head_b[c];
    #pragma unroll 8
    for (int k = 0; k < D_MODEL; ++k)
        acc += hmr[k] * head_w[(size_t)k * N_CLASSES + c];
    out[(size_t)b * N_CLASSES + c] = acc;
}

// ---------------------------------------------------------------------------
extern "C" void kernel_launch(void* const* d_in, const int* in_sizes, int n_in,
                              void* d_out, int out_size, void* d_ws, size_t ws_size,
                              hipStream_t stream) {
    const float* x         = (const float*)d_in[0];
    const float* patch_w   = (const float*)d_in[1];
    const float* patch_b   = (const float*)d_in[2];
    const float* norm_w    = (const float*)d_in[3];
    const float* in_proj_w = (const float*)d_in[4];
    const float* conv_w    = (const float*)d_in[5];
    const float* x_proj_w  = (const float*)d_in[6];
    const float* dt_proj_w = (const float*)d_in[7];
    const float* dt_proj_b = (const float*)d_in[8];
    const float* A_log     = (const float*)d_in[9];
    const float* Dv        = (const float*)d_in[10];
    const float* out_proj_w= (const float*)d_in[11];
    const float* head_w    = (const float*)d_in[12];
    const float* head_b    = (const float*)d_in[13];
    float* out = (float*)d_out;

    char* base = (char*)d_ws;
    size_t off = 0;
    auto alloc = [&](size_t bytes) -> void* {
        void* p = base + off;
        off += (bytes + 255) & ~(size_t)255;
        return p;
    };
    float* pos   = (float*)alloc((size_t)L_SEQ * D_MODEL * 4);
    bf16*  pwT   = (bf16*) alloc((size_t)D_MODEL * PATCH_DIM * 2);
    bf16*  inT   = (bf16*) alloc((size_t)N_LAYERS * 2 * D_INNER * D_MODEL * 2);
    bf16*  WtBig = (bf16*) alloc((size_t)N_LAYERS * NBIG * D_INNER * 2);
    bf16*  opT   = (bf16*) alloc((size_t)N_LAYERS * D_MODEL * D_INNER * 2);
    float* cwT   = (float*)alloc((size_t)N_LAYERS * 4 * D_INNER * 4);
    float* h     = (float*)alloc((size_t)ROWS * D_MODEL * 4);
    bf16*  xn    = (bf16*) alloc((size_t)ROWSP * D_MODEL * 2);
    char*  reg0  = (char*) alloc((size_t)ROWSP * 2 * D_INNER * 2);
    bf16*  p     = (bf16*)reg0;
    bf16*  xr    = (bf16*)reg0;
    bf16*  xs    = (bf16*) alloc((size_t)ROWSP * D_INNER * 2);
    unsigned int* ug = (unsigned int*)alloc((size_t)ROWSP * D_INNER * 4);
    float* delta = (float*)alloc((size_t)ROWSP * D_INNER * 4);
    float* bcb   = (float*)alloc((size_t)ROWS * 32 * 4);
    bf16*  yb    = (bf16*) alloc((size_t)ROWSP * D_INNER * 2);
    float* hm    = (float*)alloc((size_t)BATCH * D_MODEL * 4);

    // ---- prologue + batched weight prep ----
    posemb_kernel<<<(L_SEQ * D_MODEL + 255) / 256, 256, 0, stream>>>(pos);
    patchify_kernel<<<(ROWS * PATCH_DIM + 255) / 256, 256, 0, stream>>>(x, p);
    transpose_bf16_kernel<<<dim3(16, 24), 256, 0, stream>>>(
        patch_w, pwT, PATCH_DIM, D_MODEL, D_MODEL, 0, 0);
    transpose_bf16_kernel<<<dim3(64, 16, N_LAYERS), 256, 0, stream>>>(
        in_proj_w, inT, D_MODEL, 2 * D_INNER, 2 * D_INNER,
        (size_t)D_MODEL * 2 * D_INNER, (size_t)2 * D_INNER * D_MODEL);
    transpose_bf16_kernel<<<dim3(16, 32, N_LAYERS), 256, 0, stream>>>(
        out_proj_w, opT, D_INNER, D_MODEL, D_MODEL,
        (size_t)D_INNER * D_MODEL, (size_t)D_MODEL * D_INNER);
    wcomb_kernel<<<dim3(64, 64, N_LAYERS), 256, 0, stream>>>(
        x_proj_w, dt_proj_w, WtBig);
    bcw_kernel<<<dim3(128, N_LAYERS), 256, 0, stream>>>(x_proj_w, WtBig);
    cwt_kernel<<<dim3(16, N_LAYERS), 256, 0, stream>>>(conv_w, cwT);

    // h = p @ patch_w + patch_b + pos   (BM=32, grid 4*100=400)
    gemm64<2, 32><<<(D_MODEL / 128) * (ROWSP / 32), 256, 0, stream>>>(
        p, pwT, PATCH_DIM, D_MODEL / 128, D_MODEL, ROWS, D_MODEL,
        h, nullptr, patch_b, pos, nullptr);

    for (int layer = 0; layer < N_LAYERS; ++layer) {
        rmsnorm_kernel<<<ROWS, 256, 0, stream>>>(h, norm_w + layer * D_MODEL, xn);

        // xr = xn @ in_proj  [3136,2048] bf16   (BM=64, grid 16*50=800)
        gemm64<0, 64><<<(2 * D_INNER / 128) * (ROWSP / 64), 256, 0, stream>>>(
            xn, inT + (size_t)layer * 2 * D_INNER * D_MODEL,
            D_MODEL, 2 * D_INNER / 128, 2 * D_INNER, ROWS, 2 * D_INNER,
            nullptr, xr, nullptr, nullptr, nullptr);

        conv_silu_kernel<<<(ROWS * 128 + 255) / 256, 256, 0, stream>>>(
            xr, cwT + (size_t)layer * 4 * D_INNER, xs, ug);

        // delta = softplus(xs @ W_comb + dtb); bc interleaved   (BM=64, grid 450)
        gemm64<4, 64><<<(NBIG / 128) * (ROWSP / 64), 256, 0, stream>>>(
            xs, WtBig + (size_t)layer * NBIG * D_INNER,
            D_INNER, NBIG / 128, 1056, ROWS, 0,
            delta, nullptr, dt_proj_b + (size_t)layer * D_INNER, nullptr, bcb);

        // state-parallel scan + gate -> yb bf16
        scan_sp_kernel<<<BATCH * (D_INNER / 32), 256, 0, stream>>>(
            ug, delta, bcb,
            A_log + (size_t)layer * D_INNER * D_STATE,
            Dv + (size_t)layer * D_INNER, yb);

        // h += yb @ out_proj   (BM=32, grid 4*100=400)
        gemm64<3, 32><<<(D_MODEL / 128) * (ROWSP / 32), 256, 0, stream>>>(
            yb, opT + (size_t)layer * D_MODEL * D_INNER,
            D_INNER, D_MODEL / 128, D_MODEL, ROWS, D_MODEL,
            h, nullptr, nullptr, nullptr, nullptr);
    }

    mean_kernel<<<dim3(2, BATCH), 256, 0, stream>>>(h, hm);
    head_kernel<<<dim3(4, BATCH), 256, 0, stream>>>(hm, head_w, head_b, out);
}

// Round 12
// 546.002 us; speedup vs baseline: 2.1069x; 1.0120x over previous
//
#include <hip/hip_runtime.h>
#include <hip/hip_bf16.h>
#include <math.h>

#define BATCH 16
#define L_SEQ 196
#define PATCH_DIM 768
#define D_MODEL 512
#define D_INNER 1024
#define D_STATE 16
#define D_CONV 4
#define DT_RANK 32
#define N_LAYERS 4
#define N_CLASSES 1000
#define ROWS (BATCH * L_SEQ)   // 3136
#define ROWSP 3200             // padded (multiple of 64)
#define NBIG 1152              // delta(1024) + bc(32), padded to 128

typedef __hip_bfloat16 bf16;
typedef __attribute__((ext_vector_type(8))) __bf16 bf16x8;
typedef __attribute__((ext_vector_type(8))) short short8;
typedef __attribute__((ext_vector_type(4))) float f32x4;

__device__ __forceinline__ void gload_lds16(const void* g, void* l) {
    __builtin_amdgcn_global_load_lds((const __attribute__((address_space(1))) void*)g,
                                     (__attribute__((address_space(3))) void*)l, 16, 0, 0);
}
__device__ __forceinline__ float bfbits2f(int b) {
    return __int_as_float(((unsigned)b & 0xFFFFu) << 16);
}
__device__ __forceinline__ unsigned short f2bfbits(float f) {
    __hip_bfloat16 h = __float2bfloat16(f);
    return *reinterpret_cast<unsigned short*>(&h);
}

// ---------------------------------------------------------------------------
// patchify: x[B,224,224,3] -> p[3136,768] bf16
__global__ void patchify_kernel(const float* __restrict__ x, bf16* __restrict__ p) {
    int idx = blockIdx.x * 256 + threadIdx.x;
    if (idx >= ROWS * PATCH_DIM) return;
    int k = idx % PATCH_DIM, row = idx / PATCH_DIM;
    int b = row / L_SEQ, l = row % L_SEQ;
    int i = l / 14, j = l % 14;
    int ph = k / 48, r = k % 48, pw = r / 3, c = r % 3;
    size_t src = (((size_t)b * 224 + i * 16 + ph) * 224 + (j * 16 + pw)) * 3 + c;
    p[idx] = __float2bfloat16(x[src]);
}

// merged small prep: [0,392) posemb; [392,904) bcw; [904,968) cwt
__global__ void smallprep_kernel(float* __restrict__ pos,
                                 const float* __restrict__ xpw_all,
                                 bf16* __restrict__ WtBig_all,
                                 const float* __restrict__ cw,
                                 float* __restrict__ cwT) {
    int bid = blockIdx.x, tid = threadIdx.x;
    if (bid < 392) {
        int idx = bid * 256 + tid;
        if (idx >= L_SEQ * D_MODEL) return;
        int l = idx >> 9, col = idx & 511;
        int qd = col >> 7, wi = col & 127;
        float omega = powf(10000.f, -(float)wi / 127.f);
        float yv = (float)(l / 14), xv = (float)(l % 14);
        float arg = (qd < 2 ? xv : yv) * omega;
        pos[idx] = (qd & 1) ? cosf(arg) : sinf(arg);
    } else if (bid < 904) {
        int z = (bid - 392) >> 7;
        int idx = ((bid - 392) & 127) * 256 + tid;
        const float* xpw = xpw_all + (size_t)z * D_INNER * 64;
        bf16* WtBig = WtBig_all + (size_t)z * NBIG * D_INNER;
        int j = idx >> 10, k = idx & 1023;
        int src = (j & 1) ? 48 + (j >> 1) : 32 + (j >> 1);
        WtBig[(size_t)(1024 + j) * 1024 + k] = __float2bfloat16(xpw[k * 64 + src]);
    } else {
        int z = (bid - 904) >> 4;
        int idx = ((bid - 904) & 15) * 256 + tid;
        int d = idx >> 2, k = idx & 3;
        cwT[(size_t)z * 4096 + k * 1024 + d] = cw[(size_t)z * 4096 + d * 4 + k];
    }
}

// transpose-convert: src[K][N] f32 -> dst[Npad][K] bf16 (zero-fill), z = layer
__global__ __launch_bounds__(256) void transpose_bf16_kernel(
    const float* __restrict__ src, bf16* __restrict__ dst,
    int K, int N, int Npad, size_t src_lstride, size_t dst_lstride)
{
    src += (size_t)blockIdx.z * src_lstride;
    dst += (size_t)blockIdx.z * dst_lstride;
    __shared__ float tile[32][33];
    int kb = blockIdx.y * 32, nb = blockIdx.x * 32;
    int tx = threadIdx.x & 31, ty = threadIdx.x >> 5;  // 32 x 8
    #pragma unroll
    for (int i = 0; i < 4; ++i) {
        int k = kb + ty + 8 * i, n = nb + tx;
        tile[ty + 8 * i][tx] = (k < K && n < N) ? src[(size_t)k * N + n] : 0.f;
    }
    __syncthreads();
    #pragma unroll
    for (int i = 0; i < 4; ++i) {
        int n = nb + ty + 8 * i, k = kb + tx;
        if (n < Npad && k < K) dst[(size_t)n * K + k] = __float2bfloat16(tile[tx][ty + 8 * i]);
    }
}

// W_comb^T directly in bf16: Wt[z][n][k] = sum_{r<32} dtw_z[r][n] * xpw_z[k][r]
__global__ __launch_bounds__(256) void wcomb_kernel(
    const float* __restrict__ xpw_all,   // [z][1024][64]
    const float* __restrict__ dtw_all,   // [z][32][1024]
    bf16* __restrict__ WtBig_all)        // [z][NBIG][1024]
{
    int z = blockIdx.z;
    const float* xpw = xpw_all + (size_t)z * D_INNER * 64;
    const float* dtw = dtw_all + (size_t)z * DT_RANK * D_INNER;
    bf16* Wt = WtBig_all + (size_t)z * NBIG * D_INNER;
    __shared__ float sd[32][17];  // [r][n]
    __shared__ float sx[16][33];  // [k][r]
    int n0 = blockIdx.x * 16, k0 = blockIdx.y * 16;
    int tid = threadIdx.x;
    {
        int e = tid;        sd[e >> 4][e & 15] = dtw[(e >> 4) * D_INNER + n0 + (e & 15)];
        e = tid + 256;      sd[e >> 4][e & 15] = dtw[(e >> 4) * D_INNER + n0 + (e & 15)];
    }
    {
        int e = tid;        sx[e >> 5][e & 31] = xpw[(size_t)(k0 + (e >> 5)) * 64 + (e & 31)];
        e = tid + 256;      sx[e >> 5][e & 31] = xpw[(size_t)(k0 + (e >> 5)) * 64 + (e & 31)];
    }
    __syncthreads();
    int nn = tid >> 4, kk = tid & 15;
    float acc = 0.f;
    #pragma unroll
    for (int r = 0; r < 32; ++r) acc += sd[r][nn] * sx[kk][r];
    Wt[(size_t)(n0 + nn) * D_INNER + k0 + kk] = __float2bfloat16(acc);
}

// ---------------------------------------------------------------------------
// Unified bf16 MFMA GEMM: BM∈{32,64}, BN=128, BK=64, 4 waves (2Mx2N), 16x16x32.
// RING-3 LDS, depth-2 prefetch, counted vmcnt (T4): stage tile s+2 while
// computing tile s; steady-state wait vmcnt(2*NL) retires exactly tile s's loads.
// MODE 0: Cb = bf16(acc); 2: +bias+pos; 3: +=; 4: delta/bc split epilogue.
template<int MODE, int BM>
__global__ __launch_bounds__(256) void gemm64(
    const bf16* __restrict__ A, const bf16* __restrict__ Wt,
    int K, int gx, int Nstore, int M, int ldc,
    float* __restrict__ Cf, bf16* __restrict__ Cb,
    const float* __restrict__ bias, const float* __restrict__ pos,
    float* __restrict__ Cf2)
{
    constexpr int MI = BM / 32;                  // acc row-fragments per wave
    constexpr int NL = (BM == 64) ? 6 : 5;       // gload_lds per stage (exact)
    int nwg = gridDim.x, bid = blockIdx.x;
    int q = nwg >> 3, r = nwg & 7;
    int xcd = bid & 7, sub = bid >> 3;
    int wgid = (xcd < r ? xcd * (q + 1) : r * (q + 1) + (xcd - r) * q) + sub;
    int bx = wgid % gx, by = wgid / gx;
    int bm = by * BM, bn = bx * 128;

    __shared__ short Als[3][BM * 64];
    __shared__ short Bls[3][128 * 64];
    int tid = threadIdx.x;
    int lane = tid & 63, wid = tid >> 6;
    int wm = wid >> 1, wn = wid & 1;

    int t3 = tid >> 3, t7 = tid & 7;
    int rA0 = t3,      kA0 = t7 ^ (rA0 & 7);
    int rA1 = 32 + t3, kA1 = t7 ^ (rA1 & 7);
    const bf16* gA0 = A + (size_t)(bm + rA0) * K + kA0 * 8;
    const bf16* gA1 = A + (size_t)(bm + rA1) * K + kA1 * 8;   // only if BM==64
    const int aB0 = (wid * 64) * 8, aB1 = (256 + wid * 64) * 8;
    int rB0 = t3,      kB0 = t7 ^ (rB0 & 7);
    int rB1 = 32 + t3, kB1 = t7 ^ (rB1 & 7);
    int rB2 = 64 + t3, kB2 = t7 ^ (rB2 & 7);
    int rB3 = 96 + t3, kB3 = t7 ^ (rB3 & 7);
    const bf16* gB0 = Wt + (size_t)(bn + rB0) * K + kB0 * 8;
    const bf16* gB1 = Wt + (size_t)(bn + rB1) * K + kB1 * 8;
    const bf16* gB2 = Wt + (size_t)(bn + rB2) * K + kB2 * 8;
    const bf16* gB3 = Wt + (size_t)(bn + rB3) * K + kB3 * 8;
    const int bB0 = (wid * 64) * 8,       bB1 = (256 + wid * 64) * 8;
    const int bB2 = (512 + wid * 64) * 8, bB3 = (768 + wid * 64) * 8;

    auto stage = [&](int buf, int k0) {
        gload_lds16(gA0 + k0, &Als[buf][aB0]);
        if (BM == 64) gload_lds16(gA1 + k0, &Als[buf][aB1]);
        gload_lds16(gB0 + k0, &Bls[buf][bB0]);
        gload_lds16(gB1 + k0, &Bls[buf][bB1]);
        gload_lds16(gB2 + k0, &Bls[buf][bB2]);
        gload_lds16(gB3 + k0, &Bls[buf][bB3]);
    };

    f32x4 acc[MI][4];
    #pragma unroll
    for (int i = 0; i < MI; ++i)
        #pragma unroll
        for (int j = 0; j < 4; ++j)
            acc[i][j] = (f32x4){0.f, 0.f, 0.f, 0.f};

    int nsteps = K >> 6;
    stage(0, 0);
    if (nsteps > 1) stage(1, 64);

    for (int s = 0; s < nsteps; ++s) {
        int buf = s % 3;
        if (s + 2 < nsteps) {
            stage((s + 2) % 3, (s + 2) * 64);
            __builtin_amdgcn_sched_barrier(0);
            asm volatile("s_waitcnt vmcnt(%0)" :: "n"(2 * NL) : "memory");
        } else if (s + 1 < nsteps) {
            asm volatile("s_waitcnt vmcnt(%0)" :: "n"(NL) : "memory");
        } else {
            asm volatile("s_waitcnt vmcnt(0)" ::: "memory");
        }
        __builtin_amdgcn_s_barrier();        // buf[s] ready across all waves
        __builtin_amdgcn_sched_barrier(0);

        bf16x8 af[2][MI], bfr[2][4];
        #pragma unroll
        for (int kw = 0; kw < 2; ++kw) {
            int kc = kw * 4 + (lane >> 4);
            #pragma unroll
            for (int mi = 0; mi < MI; ++mi) {
                int row = wm * (BM / 2) + mi * 16 + (lane & 15);
                int kbp = kc ^ (row & 7);
                af[kw][mi] = *reinterpret_cast<const bf16x8*>(&Als[buf][row * 64 + kbp * 8]);
            }
            #pragma unroll
            for (int nj = 0; nj < 4; ++nj) {
                int row = wn * 64 + nj * 16 + (lane & 15);
                int kbp = kc ^ (row & 7);
                bfr[kw][nj] = *reinterpret_cast<const bf16x8*>(&Bls[buf][row * 64 + kbp * 8]);
            }
        }
        #pragma unroll
        for (int kw = 0; kw < 2; ++kw)
            #pragma unroll
            for (int mi = 0; mi < MI; ++mi)
                #pragma unroll
                for (int nj = 0; nj < 4; ++nj)
                    acc[mi][nj] = __builtin_amdgcn_mfma_f32_16x16x32_bf16(af[kw][mi], bfr[kw][nj], acc[mi][nj], 0, 0, 0);

        __builtin_amdgcn_sched_barrier(0);
        __builtin_amdgcn_s_barrier();        // buf[s] free for stage at iter s+1
    }

    #pragma unroll
    for (int mi = 0; mi < MI; ++mi) {
        #pragma unroll
        for (int nj = 0; nj < 4; ++nj) {
            int r0 = bm + wm * (BM / 2) + mi * 16 + ((lane >> 4) << 2);
            int col = bn + wn * 64 + nj * 16 + (lane & 15);
            if (col >= Nstore) continue;
            #pragma unroll
            for (int j = 0; j < 4; ++j) {
                int row = r0 + j;
                if (row >= M) continue;
                float v = acc[mi][nj][j];
                if (MODE == 4) {
                    if (col < 1024) {
                        float z = v + bias[col];
                        Cf[(size_t)row * 1024 + col] = (z > 20.f) ? z : log1pf(__expf(z));
                    } else {
                        Cf2[(size_t)row * 32 + (col - 1024)] = v;
                    }
                } else {
                    size_t o = (size_t)row * ldc + col;
                    if (MODE == 0) Cb[o] = __float2bfloat16(v);
                    else if (MODE == 2) Cf[o] = v + bias[col] + pos[(size_t)(row % L_SEQ) * D_MODEL + col];
                    else if (MODE == 3) Cf[o] += v;
                }
            }
        }
    }
}

// ---------------------------------------------------------------------------
__global__ __launch_bounds__(256) void rmsnorm_kernel(
    const float* __restrict__ h, const float* __restrict__ w, bf16* __restrict__ o)
{
    int row = blockIdx.x;
    int tid = threadIdx.x;
    const float* hr = h + (size_t)row * D_MODEL;
    float v0 = hr[tid], v1 = hr[tid + 256];
    float ss = v0 * v0 + v1 * v1;
    #pragma unroll
    for (int off = 32; off; off >>= 1) ss += __shfl_down(ss, off);
    __shared__ float ls[4];
    __shared__ float scale_s;
    if ((tid & 63) == 0) ls[tid >> 6] = ss;
    __syncthreads();
    if (tid == 0) {
        float t = ls[0] + ls[1] + ls[2] + ls[3];
        scale_s = rsqrtf(t * (1.f / D_MODEL) + 1e-5f);
    }
    __syncthreads();
    float sc = scale_s;
    o[(size_t)row * D_MODEL + tid]       = __float2bfloat16(v0 * sc * w[tid]);
    o[(size_t)row * D_MODEL + tid + 256] = __float2bfloat16(v1 * sc * w[tid + 256]);
}

// causal depthwise conv (k=4) + SiLU + gate precompute, vectorized x8 channels.
__global__ __launch_bounds__(256) void conv_silu_kernel(
    const bf16* __restrict__ xr, const float* __restrict__ cwT,
    bf16* __restrict__ xs, unsigned int* __restrict__ ug)
{
    int idx = blockIdx.x * 256 + threadIdx.x;
    if (idx >= ROWS * 128) return;
    int dg = idx & 127, row = idx >> 7;
    int d0 = dg << 3;
    int l = row % L_SEQ;
    float acc[8] = {0.f,0.f,0.f,0.f,0.f,0.f,0.f,0.f};
    #pragma unroll
    for (int k = 0; k < 4; ++k) {
        int ls = l - 3 + k;
        if (ls < 0) continue;
        short8 xv = *reinterpret_cast<const short8*>(xr + (size_t)(row - 3 + k) * 2048 + d0);
        const float* wk = cwT + k * 1024 + d0;
        #pragma unroll
        for (int j = 0; j < 8; ++j)
            acc[j] += bfbits2f(xv[j]) * wk[j];
    }
    short8 rv = *reinterpret_cast<const short8*>(xr + (size_t)row * 2048 + 1024 + d0);
    short8 xsv;
    unsigned ugv[8];
    #pragma unroll
    for (int j = 0; j < 8; ++j) {
        float u = acc[j] / (1.f + __expf(-acc[j]));
        unsigned short ub = f2bfbits(u);
        xsv[j] = (short)ub;
        float res = bfbits2f(rv[j]);
        float g = res / (1.f + __expf(-res));
        ugv[j] = (unsigned)ub | ((unsigned)f2bfbits(g) << 16);
    }
    *reinterpret_cast<short8*>(xs + (size_t)row * 1024 + d0) = xsv;
    uint4* up = reinterpret_cast<uint4*>(ug + (size_t)row * 1024 + d0);
    up[0] = make_uint4(ugv[0], ugv[1], ugv[2], ugv[3]);
    up[1] = make_uint4(ugv[4], ugv[5], ugv[6], ugv[7]);
}

// ---------------------------------------------------------------------------
// State-parallel selective scan + gate. 2 states/lane, 8 lanes/channel,
// 32 channels/block (256 thr), grid = 512 blocks.  exp2-folded A constants.
__global__ __launch_bounds__(256) void scan_sp_kernel(
    const unsigned int* __restrict__ ug, // {u,g} bf16x2  [rows,1024]
    const float* __restrict__ delta,     //               [rows,1024] f32
    const float* __restrict__ bc,        // [rows,32]  {B0,C0,B1,C1,...}
    const float* __restrict__ A_log,     // [1024,16]
    const float* __restrict__ Dv,        // [1024]
    bf16* __restrict__ y)                // [rows,1024] bf16
{
    int tid = threadIdx.x;
    int n2 = tid & 7, ch = tid >> 3;
    int b = blockIdx.x >> 5;
    int d = (((int)blockIdx.x & 31) << 5) | ch;
    size_t bbase = (size_t)b * L_SEQ;

    const float L2E = 1.4426950408889634f;
    float A0 = -__expf(A_log[d * 16 + 2 * n2]) * L2E;
    float A1 = -__expf(A_log[d * 16 + 2 * n2 + 1]) * L2E;
    float Dd = Dv[d];
    float s0 = 0.f, s1 = 0.f;

    const unsigned* pu = ug + bbase * 1024 + d;
    const float*    pd = delta + bbase * 1024 + d;
    const float*    pb = bc + bbase * 32 + 4 * n2;
    bf16*           py = y + bbase * 1024 + d;

    unsigned uv[8];
    float dlv[8];
    f32x4 bcv[8];

#define LOADSLOT(i) { \
    uv[i]  = pu[(i) * 1024]; \
    dlv[i] = pd[(i) * 1024]; \
    bcv[i] = *reinterpret_cast<const f32x4*>(pb + (i) * 32); }

#define STEP(i) { \
    float _dl = dlv[i]; \
    float _u  = __int_as_float(uv[i] << 16); \
    float _a0 = __builtin_amdgcn_exp2f(_dl * A0); \
    float _a1 = __builtin_amdgcn_exp2f(_dl * A1); \
    float _du = _dl * _u; \
    s0 = _a0 * s0 + _du * bcv[i].x; \
    s1 = _a1 * s1 + _du * bcv[i].z; \
    float _p = s0 * bcv[i].y + s1 * bcv[i].w; \
    _p += __int_as_float(__builtin_amdgcn_mov_dpp(__float_as_int(_p), 0xB1, 0xF, 0xF, true)); \
    _p += __int_as_float(__builtin_amdgcn_mov_dpp(__float_as_int(_p), 0x4E, 0xF, 0xF, true)); \
    _p += __int_as_float(__builtin_amdgcn_mov_dpp(__float_as_int(_p), 0x141, 0xF, 0xF, true)); \
    if (n2 == 0) { \
        float _g = __int_as_float(uv[i] & 0xFFFF0000u); \
        py[(i) * 1024] = __float2bfloat16((_p + _u * Dd) * _g); \
    } }

    LOADSLOT(0) LOADSLOT(1) LOADSLOT(2) LOADSLOT(3)
    LOADSLOT(4) LOADSLOT(5) LOADSLOT(6) LOADSLOT(7)
    pu += 8 * 1024; pd += 8 * 1024; pb += 8 * 32;

    for (int g = 0; g < 23; ++g) {
        STEP(0) LOADSLOT(0)
        STEP(1) LOADSLOT(1)
        STEP(2) LOADSLOT(2)
        STEP(3) LOADSLOT(3)
        STEP(4) LOADSLOT(4)
        STEP(5) LOADSLOT(5)
        STEP(6) LOADSLOT(6)
        STEP(7) LOADSLOT(7)
        pu += 8 * 1024; pd += 8 * 1024; pb += 8 * 32; py += 8 * 1024;
    }
    STEP(0) LOADSLOT(0)
    STEP(1) LOADSLOT(1)
    STEP(2) LOADSLOT(2)
    STEP(3) LOADSLOT(3)
    STEP(4) STEP(5) STEP(6) STEP(7)
    py += 8 * 1024;
    STEP(0) STEP(1) STEP(2) STEP(3)
#undef LOADSLOT
#undef STEP
}

// mean over sequence: h[16,196,512] f32 -> hm[16,512] f32.  grid (2,16)
__global__ __launch_bounds__(256) void mean_kernel(const float* __restrict__ h,
                                                   float* __restrict__ hm) {
    int c = blockIdx.x * 256 + threadIdx.x;
    int b = blockIdx.y;
    const float* hb = h + (size_t)b * L_SEQ * D_MODEL + c;
    float acc = 0.f;
    #pragma unroll 4
    for (int l = 0; l < L_SEQ; ++l) acc += hb[(size_t)l * D_MODEL];
    hm[b * D_MODEL + c] = acc * (1.f / L_SEQ);
}

// head: out[b][c] = hm[b,:] . head_w[:,c] + head_b[c].  grid (4,16)
__global__ __launch_bounds__(256) void head_kernel(
    const float* __restrict__ hm, const float* __restrict__ head_w,
    const float* __restrict__ head_b, float* __restrict__ out)
{
    __shared__ float hmr[D_MODEL];
    int tid = threadIdx.x;
    int b = blockIdx.y;
    hmr[tid]       = hm[b * D_MODEL + tid];
    hmr[tid + 256] = hm[b * D_MODEL + tid + 256];
    __syncthreads();
    int c = blockIdx.x * 256 + tid;
    if (c >= N_CLASSES) return;
    float acc = head_b[c];
    #pragma unroll 8
    for (int k = 0; k < D_MODEL; ++k)
        acc += hmr[k] * head_w[(size_t)k * N_CLASSES + c];
    out[(size_t)b * N_CLASSES + c] = acc;
}

// ---------------------------------------------------------------------------
extern "C" void kernel_launch(void* const* d_in, const int* in_sizes, int n_in,
                              void* d_out, int out_size, void* d_ws, size_t ws_size,
                              hipStream_t stream) {
    const float* x         = (const float*)d_in[0];
    const float* patch_w   = (const float*)d_in[1];
    const float* patch_b   = (const float*)d_in[2];
    const float* norm_w    = (const float*)d_in[3];
    const float* in_proj_w = (const float*)d_in[4];
    const float* conv_w    = (const float*)d_in[5];
    const float* x_proj_w  = (const float*)d_in[6];
    const float* dt_proj_w = (const float*)d_in[7];
    const float* dt_proj_b = (const float*)d_in[8];
    const float* A_log     = (const float*)d_in[9];
    const float* Dv        = (const float*)d_in[10];
    const float* out_proj_w= (const float*)d_in[11];
    const float* head_w    = (const float*)d_in[12];
    const float* head_b    = (const float*)d_in[13];
    float* out = (float*)d_out;

    char* base = (char*)d_ws;
    size_t off = 0;
    auto alloc = [&](size_t bytes) -> void* {
        void* p = base + off;
        off += (bytes + 255) & ~(size_t)255;
        return p;
    };
    float* pos   = (float*)alloc((size_t)L_SEQ * D_MODEL * 4);
    bf16*  pwT   = (bf16*) alloc((size_t)D_MODEL * PATCH_DIM * 2);
    bf16*  inT   = (bf16*) alloc((size_t)N_LAYERS * 2 * D_INNER * D_MODEL * 2);
    bf16*  WtBig = (bf16*) alloc((size_t)N_LAYERS * NBIG * D_INNER * 2);
    bf16*  opT   = (bf16*) alloc((size_t)N_LAYERS * D_MODEL * D_INNER * 2);
    float* cwT   = (float*)alloc((size_t)N_LAYERS * 4 * D_INNER * 4);
    float* h     = (float*)alloc((size_t)ROWS * D_MODEL * 4);
    bf16*  xn    = (bf16*) alloc((size_t)ROWSP * D_MODEL * 2);
    char*  reg0  = (char*) alloc((size_t)ROWSP * 2 * D_INNER * 2);
    bf16*  p     = (bf16*)reg0;
    bf16*  xr    = (bf16*)reg0;
    bf16*  xs    = (bf16*) alloc((size_t)ROWSP * D_INNER * 2);
    unsigned int* ug = (unsigned int*)alloc((size_t)ROWSP * D_INNER * 4);
    float* delta = (float*)alloc((size_t)ROWSP * D_INNER * 4);
    float* bcb   = (float*)alloc((size_t)ROWS * 32 * 4);
    bf16*  yb    = (bf16*) alloc((size_t)ROWSP * D_INNER * 2);
    float* hm    = (float*)alloc((size_t)BATCH * D_MODEL * 4);

    // ---- prologue + batched weight prep ----
    patchify_kernel<<<(ROWS * PATCH_DIM + 255) / 256, 256, 0, stream>>>(x, p);
    smallprep_kernel<<<968, 256, 0, stream>>>(pos, x_proj_w, WtBig, conv_w, cwT);
    transpose_bf16_kernel<<<dim3(16, 24), 256, 0, stream>>>(
        patch_w, pwT, PATCH_DIM, D_MODEL, D_MODEL, 0, 0);
    transpose_bf16_kernel<<<dim3(64, 16, N_LAYERS), 256, 0, stream>>>(
        in_proj_w, inT, D_MODEL, 2 * D_INNER, 2 * D_INNER,
        (size_t)D_MODEL * 2 * D_INNER, (size_t)2 * D_INNER * D_MODEL);
    transpose_bf16_kernel<<<dim3(16, 32, N_LAYERS), 256, 0, stream>>>(
        out_proj_w, opT, D_INNER, D_MODEL, D_MODEL,
        (size_t)D_INNER * D_MODEL, (size_t)D_MODEL * D_INNER);
    wcomb_kernel<<<dim3(64, 64, N_LAYERS), 256, 0, stream>>>(
        x_proj_w, dt_proj_w, WtBig);

    // h = p @ patch_w + patch_b + pos   (BM=32, grid 400)
    gemm64<2, 32><<<(D_MODEL / 128) * (ROWSP / 32), 256, 0, stream>>>(
        p, pwT, PATCH_DIM, D_MODEL / 128, D_MODEL, ROWS, D_MODEL,
        h, nullptr, patch_b, pos, nullptr);

    for (int layer = 0; layer < N_LAYERS; ++layer) {
        rmsnorm_kernel<<<ROWS, 256, 0, stream>>>(h, norm_w + layer * D_MODEL, xn);

        // xr = xn @ in_proj  [3136,2048] bf16   (BM=64, grid 800)
        gemm64<0, 64><<<(2 * D_INNER / 128) * (ROWSP / 64), 256, 0, stream>>>(
            xn, inT + (size_t)layer * 2 * D_INNER * D_MODEL,
            D_MODEL, 2 * D_INNER / 128, 2 * D_INNER, ROWS, 2 * D_INNER,
            nullptr, xr, nullptr, nullptr, nullptr);

        conv_silu_kernel<<<(ROWS * 128 + 255) / 256, 256, 0, stream>>>(
            xr, cwT + (size_t)layer * 4 * D_INNER, xs, ug);

        // delta = softplus(xs @ W_comb + dtb); bc interleaved   (BM=64, grid 450)
        gemm64<4, 64><<<(NBIG / 128) * (ROWSP / 64), 256, 0, stream>>>(
            xs, WtBig + (size_t)layer * NBIG * D_INNER,
            D_INNER, NBIG / 128, 1056, ROWS, 0,
            delta, nullptr, dt_proj_b + (size_t)layer * D_INNER, nullptr, bcb);

        // state-parallel scan + gate -> yb bf16
        scan_sp_kernel<<<BATCH * (D_INNER / 32), 256, 0, stream>>>(
            ug, delta, bcb,
            A_log + (size_t)layer * D_INNER * D_STATE,
            Dv + (size_t)layer * D_INNER, yb);

        // h += yb @ out_proj   (BM=32, grid 400)
        gemm64<3, 32><<<(D_MODEL / 128) * (ROWSP / 32), 256, 0, stream>>>(
            yb, opT + (size_t)layer * D_MODEL * D_INNER,
            D_INNER, D_MODEL / 128, D_MODEL, ROWS, D_MODEL,
            h, nullptr, nullptr, nullptr, nullptr);
    }

    mean_kernel<<<dim3(2, BATCH), 256, 0, stream>>>(h, hm);
    head_kernel<<<dim3(4, BATCH), 256, 0, stream>>>(hm, head_w, head_b, out);
}

// Round 13
// 523.892 us; speedup vs baseline: 2.1959x; 1.0422x over previous
//
#include <hip/hip_runtime.h>
#include <hip/hip_bf16.h>
#include <math.h>

#define BATCH 16
#define L_SEQ 196
#define PATCH_DIM 768
#define D_MODEL 512
#define D_INNER 1024
#define D_STATE 16
#define D_CONV 4
#define DT_RANK 32
#define N_LAYERS 4
#define N_CLASSES 1000
#define ROWS (BATCH * L_SEQ)   // 3136
#define ROWSP 3200             // padded (multiple of 64)
#define NBIG 1152              // delta(1024) + bc(32), padded to 128

typedef __hip_bfloat16 bf16;
typedef __attribute__((ext_vector_type(8))) __bf16 bf16x8;
typedef __attribute__((ext_vector_type(8))) short short8;
typedef __attribute__((ext_vector_type(4))) float f32x4;

__device__ __forceinline__ void gload_lds16(const void* g, void* l) {
    __builtin_amdgcn_global_load_lds((const __attribute__((address_space(1))) void*)g,
                                     (__attribute__((address_space(3))) void*)l, 16, 0, 0);
}
__device__ __forceinline__ float bfbits2f(int b) {
    return __int_as_float(((unsigned)b & 0xFFFFu) << 16);
}
__device__ __forceinline__ unsigned short f2bfbits(float f) {
    __hip_bfloat16 h = __float2bfloat16(f);
    return *reinterpret_cast<unsigned short*>(&h);
}

// ---------------------------------------------------------------------------
// patchify: x[B,224,224,3] -> p[3136,768] bf16
__global__ void patchify_kernel(const float* __restrict__ x, bf16* __restrict__ p) {
    int idx = blockIdx.x * 256 + threadIdx.x;
    if (idx >= ROWS * PATCH_DIM) return;
    int k = idx % PATCH_DIM, row = idx / PATCH_DIM;
    int b = row / L_SEQ, l = row % L_SEQ;
    int i = l / 14, j = l % 14;
    int ph = k / 48, r = k % 48, pw = r / 3, c = r % 3;
    size_t src = (((size_t)b * 224 + i * 16 + ph) * 224 + (j * 16 + pw)) * 3 + c;
    p[idx] = __float2bfloat16(x[src]);
}

// merged small prep: [0,392) posemb; [392,904) bcw; [904,968) cwt
__global__ void smallprep_kernel(float* __restrict__ pos,
                                 const float* __restrict__ xpw_all,
                                 bf16* __restrict__ WtBig_all,
                                 const float* __restrict__ cw,
                                 float* __restrict__ cwT) {
    int bid = blockIdx.x, tid = threadIdx.x;
    if (bid < 392) {
        int idx = bid * 256 + tid;
        if (idx >= L_SEQ * D_MODEL) return;
        int l = idx >> 9, col = idx & 511;
        int qd = col >> 7, wi = col & 127;
        float omega = powf(10000.f, -(float)wi / 127.f);
        float yv = (float)(l / 14), xv = (float)(l % 14);
        float arg = (qd < 2 ? xv : yv) * omega;
        pos[idx] = (qd & 1) ? cosf(arg) : sinf(arg);
    } else if (bid < 904) {
        int z = (bid - 392) >> 7;
        int idx = ((bid - 392) & 127) * 256 + tid;
        const float* xpw = xpw_all + (size_t)z * D_INNER * 64;
        bf16* WtBig = WtBig_all + (size_t)z * NBIG * D_INNER;
        int j = idx >> 10, k = idx & 1023;
        int src = (j & 1) ? 48 + (j >> 1) : 32 + (j >> 1);
        WtBig[(size_t)(1024 + j) * 1024 + k] = __float2bfloat16(xpw[k * 64 + src]);
    } else {
        int z = (bid - 904) >> 4;
        int idx = ((bid - 904) & 15) * 256 + tid;
        int d = idx >> 2, k = idx & 3;
        cwT[(size_t)z * 4096 + k * 1024 + d] = cw[(size_t)z * 4096 + d * 4 + k];
    }
}

// transpose-convert: src[K][N] f32 -> dst[Npad][K] bf16 (zero-fill), z = layer
__global__ __launch_bounds__(256) void transpose_bf16_kernel(
    const float* __restrict__ src, bf16* __restrict__ dst,
    int K, int N, int Npad, size_t src_lstride, size_t dst_lstride)
{
    src += (size_t)blockIdx.z * src_lstride;
    dst += (size_t)blockIdx.z * dst_lstride;
    __shared__ float tile[32][33];
    int kb = blockIdx.y * 32, nb = blockIdx.x * 32;
    int tx = threadIdx.x & 31, ty = threadIdx.x >> 5;  // 32 x 8
    #pragma unroll
    for (int i = 0; i < 4; ++i) {
        int k = kb + ty + 8 * i, n = nb + tx;
        tile[ty + 8 * i][tx] = (k < K && n < N) ? src[(size_t)k * N + n] : 0.f;
    }
    __syncthreads();
    #pragma unroll
    for (int i = 0; i < 4; ++i) {
        int n = nb + ty + 8 * i, k = kb + tx;
        if (n < Npad && k < K) dst[(size_t)n * K + k] = __float2bfloat16(tile[tx][ty + 8 * i]);
    }
}

// W_comb^T bf16: Wt[z][n][k] = sum_{r<32} dtw_z[r][n] * xpw_z[k][r]
// 32x32 tile per block, 2x2 outputs per thread.
__global__ __launch_bounds__(256) void wcomb_kernel(
    const float* __restrict__ xpw_all,   // [z][1024][64]
    const float* __restrict__ dtw_all,   // [z][32][1024]
    bf16* __restrict__ WtBig_all)        // [z][NBIG][1024]
{
    int z = blockIdx.z;
    const float* xpw = xpw_all + (size_t)z * D_INNER * 64;
    const float* dtw = dtw_all + (size_t)z * DT_RANK * D_INNER;
    bf16* Wt = WtBig_all + (size_t)z * NBIG * D_INNER;
    __shared__ float sd[32][33];  // [r][n]
    __shared__ float sx[32][33];  // [k][r]
    int n0 = blockIdx.x * 32, k0 = blockIdx.y * 32;
    int tid = threadIdx.x;
    #pragma unroll
    for (int i = 0; i < 4; ++i) {
        int e = tid + 256 * i;
        sd[e >> 5][e & 31] = dtw[(size_t)(e >> 5) * D_INNER + n0 + (e & 31)];
        sx[e >> 5][e & 31] = xpw[(size_t)(k0 + (e >> 5)) * 64 + (e & 31)];
    }
    __syncthreads();
    int ty = tid >> 4, tx = tid & 15;
    int nn = ty * 2, kk = tx * 2;
    float a00 = 0.f, a01 = 0.f, a10 = 0.f, a11 = 0.f;
    #pragma unroll
    for (int r = 0; r < 32; ++r) {
        float d0 = sd[r][nn], d1 = sd[r][nn + 1];
        float x0 = sx[kk][r], x1 = sx[kk + 1][r];
        a00 += d0 * x0; a01 += d0 * x1;
        a10 += d1 * x0; a11 += d1 * x1;
    }
    Wt[(size_t)(n0 + nn) * D_INNER + k0 + kk]           = __float2bfloat16(a00);
    Wt[(size_t)(n0 + nn) * D_INNER + k0 + kk + 1]       = __float2bfloat16(a01);
    Wt[(size_t)(n0 + nn + 1) * D_INNER + k0 + kk]       = __float2bfloat16(a10);
    Wt[(size_t)(n0 + nn + 1) * D_INNER + k0 + kk + 1]   = __float2bfloat16(a11);
}

// ---------------------------------------------------------------------------
// Unified bf16 MFMA GEMM: BM∈{32,64}, BN=128, BK=64, 4 waves (2Mx2N), 16x16x32.
// RING-3 LDS, depth-2 prefetch, counted vmcnt (T4).
template<int MODE, int BM>
__global__ __launch_bounds__(256) void gemm64(
    const bf16* __restrict__ A, const bf16* __restrict__ Wt,
    int K, int gx, int Nstore, int M, int ldc,
    float* __restrict__ Cf, bf16* __restrict__ Cb,
    const float* __restrict__ bias, const float* __restrict__ pos,
    float* __restrict__ Cf2)
{
    constexpr int MI = BM / 32;
    constexpr int NL = (BM == 64) ? 6 : 5;
    int nwg = gridDim.x, bid = blockIdx.x;
    int q = nwg >> 3, r = nwg & 7;
    int xcd = bid & 7, sub = bid >> 3;
    int wgid = (xcd < r ? xcd * (q + 1) : r * (q + 1) + (xcd - r) * q) + sub;
    int bx = wgid % gx, by = wgid / gx;
    int bm = by * BM, bn = bx * 128;

    __shared__ short Als[3][BM * 64];
    __shared__ short Bls[3][128 * 64];
    int tid = threadIdx.x;
    int lane = tid & 63, wid = tid >> 6;
    int wm = wid >> 1, wn = wid & 1;

    int t3 = tid >> 3, t7 = tid & 7;
    int rA0 = t3,      kA0 = t7 ^ (rA0 & 7);
    int rA1 = 32 + t3, kA1 = t7 ^ (rA1 & 7);
    const bf16* gA0 = A + (size_t)(bm + rA0) * K + kA0 * 8;
    const bf16* gA1 = A + (size_t)(bm + rA1) * K + kA1 * 8;
    const int aB0 = (wid * 64) * 8, aB1 = (256 + wid * 64) * 8;
    int rB0 = t3,      kB0 = t7 ^ (rB0 & 7);
    int rB1 = 32 + t3, kB1 = t7 ^ (rB1 & 7);
    int rB2 = 64 + t3, kB2 = t7 ^ (rB2 & 7);
    int rB3 = 96 + t3, kB3 = t7 ^ (rB3 & 7);
    const bf16* gB0 = Wt + (size_t)(bn + rB0) * K + kB0 * 8;
    const bf16* gB1 = Wt + (size_t)(bn + rB1) * K + kB1 * 8;
    const bf16* gB2 = Wt + (size_t)(bn + rB2) * K + kB2 * 8;
    const bf16* gB3 = Wt + (size_t)(bn + rB3) * K + kB3 * 8;
    const int bB0 = (wid * 64) * 8,       bB1 = (256 + wid * 64) * 8;
    const int bB2 = (512 + wid * 64) * 8, bB3 = (768 + wid * 64) * 8;

    auto stage = [&](int buf, int k0) {
        gload_lds16(gA0 + k0, &Als[buf][aB0]);
        if (BM == 64) gload_lds16(gA1 + k0, &Als[buf][aB1]);
        gload_lds16(gB0 + k0, &Bls[buf][bB0]);
        gload_lds16(gB1 + k0, &Bls[buf][bB1]);
        gload_lds16(gB2 + k0, &Bls[buf][bB2]);
        gload_lds16(gB3 + k0, &Bls[buf][bB3]);
    };

    f32x4 acc[MI][4];
    #pragma unroll
    for (int i = 0; i < MI; ++i)
        #pragma unroll
        for (int j = 0; j < 4; ++j)
            acc[i][j] = (f32x4){0.f, 0.f, 0.f, 0.f};

    int nsteps = K >> 6;
    stage(0, 0);
    if (nsteps > 1) stage(1, 64);

    for (int s = 0; s < nsteps; ++s) {
        int buf = s % 3;
        if (s + 2 < nsteps) {
            stage((s + 2) % 3, (s + 2) * 64);
            __builtin_amdgcn_sched_barrier(0);
            asm volatile("s_waitcnt vmcnt(%0)" :: "n"(2 * NL) : "memory");
        } else if (s + 1 < nsteps) {
            asm volatile("s_waitcnt vmcnt(%0)" :: "n"(NL) : "memory");
        } else {
            asm volatile("s_waitcnt vmcnt(0)" ::: "memory");
        }
        __builtin_amdgcn_s_barrier();
        __builtin_amdgcn_sched_barrier(0);

        bf16x8 af[2][MI], bfr[2][4];
        #pragma unroll
        for (int kw = 0; kw < 2; ++kw) {
            int kc = kw * 4 + (lane >> 4);
            #pragma unroll
            for (int mi = 0; mi < MI; ++mi) {
                int row = wm * (BM / 2) + mi * 16 + (lane & 15);
                int kbp = kc ^ (row & 7);
                af[kw][mi] = *reinterpret_cast<const bf16x8*>(&Als[buf][row * 64 + kbp * 8]);
            }
            #pragma unroll
            for (int nj = 0; nj < 4; ++nj) {
                int row = wn * 64 + nj * 16 + (lane & 15);
                int kbp = kc ^ (row & 7);
                bfr[kw][nj] = *reinterpret_cast<const bf16x8*>(&Bls[buf][row * 64 + kbp * 8]);
            }
        }
        #pragma unroll
        for (int kw = 0; kw < 2; ++kw)
            #pragma unroll
            for (int mi = 0; mi < MI; ++mi)
                #pragma unroll
                for (int nj = 0; nj < 4; ++nj)
                    acc[mi][nj] = __builtin_amdgcn_mfma_f32_16x16x32_bf16(af[kw][mi], bfr[kw][nj], acc[mi][nj], 0, 0, 0);

        __builtin_amdgcn_sched_barrier(0);
        __builtin_amdgcn_s_barrier();
    }

    #pragma unroll
    for (int mi = 0; mi < MI; ++mi) {
        #pragma unroll
        for (int nj = 0; nj < 4; ++nj) {
            int r0 = bm + wm * (BM / 2) + mi * 16 + ((lane >> 4) << 2);
            int col = bn + wn * 64 + nj * 16 + (lane & 15);
            if (col >= Nstore) continue;
            #pragma unroll
            for (int j = 0; j < 4; ++j) {
                int row = r0 + j;
                if (row >= M) continue;
                float v = acc[mi][nj][j];
                if (MODE == 4) {
                    if (col < 1024) {
                        float z = v + bias[col];
                        Cf[(size_t)row * 1024 + col] = (z > 20.f) ? z : log1pf(__expf(z));
                    } else {
                        Cf2[(size_t)row * 32 + (col - 1024)] = v;
                    }
                } else {
                    size_t o = (size_t)row * ldc + col;
                    if (MODE == 0) Cb[o] = __float2bfloat16(v);
                    else if (MODE == 2) Cf[o] = v + bias[col] + pos[(size_t)(row % L_SEQ) * D_MODEL + col];
                    else if (MODE == 3) Cf[o] += v;
                }
            }
        }
    }
}

// ---------------------------------------------------------------------------
// RMSNorm, wave-per-row: 4 rows/block, no barriers, shfl_xor reduce.
__global__ __launch_bounds__(256) void rmsnorm_kernel(
    const float* __restrict__ h, const float* __restrict__ w, bf16* __restrict__ o)
{
    int row = (blockIdx.x << 2) | (threadIdx.x >> 6);
    int lane = threadIdx.x & 63;
    const float* hr = h + (size_t)row * D_MODEL + lane * 8;
    f32x4 v0 = *reinterpret_cast<const f32x4*>(hr);
    f32x4 v1 = *reinterpret_cast<const f32x4*>(hr + 4);
    float ss = v0.x*v0.x + v0.y*v0.y + v0.z*v0.z + v0.w*v0.w
             + v1.x*v1.x + v1.y*v1.y + v1.z*v1.z + v1.w*v1.w;
    #pragma unroll
    for (int off = 32; off; off >>= 1) ss += __shfl_xor(ss, off);
    float sc = rsqrtf(ss * (1.f / D_MODEL) + 1e-5f);
    const float* wr = w + lane * 8;
    f32x4 w0 = *reinterpret_cast<const f32x4*>(wr);
    f32x4 w1 = *reinterpret_cast<const f32x4*>(wr + 4);
    short8 ov;
    ov[0] = (short)f2bfbits(v0.x * sc * w0.x);
    ov[1] = (short)f2bfbits(v0.y * sc * w0.y);
    ov[2] = (short)f2bfbits(v0.z * sc * w0.z);
    ov[3] = (short)f2bfbits(v0.w * sc * w0.w);
    ov[4] = (short)f2bfbits(v1.x * sc * w1.x);
    ov[5] = (short)f2bfbits(v1.y * sc * w1.y);
    ov[6] = (short)f2bfbits(v1.z * sc * w1.z);
    ov[7] = (short)f2bfbits(v1.w * sc * w1.w);
    *reinterpret_cast<short8*>(o + (size_t)row * D_MODEL + lane * 8) = ov;
}

// causal depthwise conv (k=4) + SiLU + gate precompute, vectorized x8 channels.
__global__ __launch_bounds__(256) void conv_silu_kernel(
    const bf16* __restrict__ xr, const float* __restrict__ cwT,
    bf16* __restrict__ xs, unsigned int* __restrict__ ug)
{
    int idx = blockIdx.x * 256 + threadIdx.x;
    if (idx >= ROWS * 128) return;
    int dg = idx & 127, row = idx >> 7;
    int d0 = dg << 3;
    int l = row % L_SEQ;
    float acc[8] = {0.f,0.f,0.f,0.f,0.f,0.f,0.f,0.f};
    #pragma unroll
    for (int k = 0; k < 4; ++k) {
        int ls = l - 3 + k;
        if (ls < 0) continue;
        short8 xv = *reinterpret_cast<const short8*>(xr + (size_t)(row - 3 + k) * 2048 + d0);
        const float* wk = cwT + k * 1024 + d0;
        #pragma unroll
        for (int j = 0; j < 8; ++j)
            acc[j] += bfbits2f(xv[j]) * wk[j];
    }
    short8 rv = *reinterpret_cast<const short8*>(xr + (size_t)row * 2048 + 1024 + d0);
    short8 xsv;
    unsigned ugv[8];
    #pragma unroll
    for (int j = 0; j < 8; ++j) {
        float u = acc[j] / (1.f + __expf(-acc[j]));
        unsigned short ub = f2bfbits(u);
        xsv[j] = (short)ub;
        float res = bfbits2f(rv[j]);
        float g = res / (1.f + __expf(-res));
        ugv[j] = (unsigned)ub | ((unsigned)f2bfbits(g) << 16);
    }
    *reinterpret_cast<short8*>(xs + (size_t)row * 1024 + d0) = xsv;
    uint4* up = reinterpret_cast<uint4*>(ug + (size_t)row * 1024 + d0);
    up[0] = make_uint4(ugv[0], ugv[1], ugv[2], ugv[3]);
    up[1] = make_uint4(ugv[4], ugv[5], ugv[6], ugv[7]);
}

// ---------------------------------------------------------------------------
// State-parallel scan + gate: 4 states/lane, 4 lanes/channel, 64 ch/block.
// grid = 16 x 16 = 256 blocks.  DPP quad-perm 2-stage reduce.
__global__ __launch_bounds__(256) void scan_sp_kernel(
    const unsigned int* __restrict__ ug, // {u,g} bf16x2  [rows,1024]
    const float* __restrict__ delta,     //               [rows,1024] f32
    const float* __restrict__ bc,        // [rows,32]  {B0,C0,B1,C1,...}
    const float* __restrict__ A_log,     // [1024,16]
    const float* __restrict__ Dv,        // [1024]
    bf16* __restrict__ y)                // [rows,1024] bf16
{
    int tid = threadIdx.x;
    int n3 = tid & 3, ch = tid >> 2;
    int b = blockIdx.x >> 4;
    int d = (((int)blockIdx.x & 15) << 6) | ch;
    size_t bbase = (size_t)b * L_SEQ;

    const float L2E = 1.4426950408889634f;
    float A0 = -__expf(A_log[d * 16 + 4 * n3])     * L2E;
    float A1 = -__expf(A_log[d * 16 + 4 * n3 + 1]) * L2E;
    float A2 = -__expf(A_log[d * 16 + 4 * n3 + 2]) * L2E;
    float A3 = -__expf(A_log[d * 16 + 4 * n3 + 3]) * L2E;
    float Dd = Dv[d];
    float s0 = 0.f, s1 = 0.f, s2 = 0.f, s3 = 0.f;

    const unsigned* pu = ug + bbase * 1024 + d;
    const float*    pd = delta + bbase * 1024 + d;
    const float*    pb = bc + bbase * 32 + 8 * n3;
    bf16*           py = y + bbase * 1024 + d;

    unsigned uv[8];
    float dlv[8];
    f32x4 bc0[8], bc1[8];

#define LOADSLOT(i) { \
    uv[i]  = pu[(i) * 1024]; \
    dlv[i] = pd[(i) * 1024]; \
    bc0[i] = *reinterpret_cast<const f32x4*>(pb + (i) * 32); \
    bc1[i] = *reinterpret_cast<const f32x4*>(pb + (i) * 32 + 4); }

#define STEP(i) { \
    float _dl = dlv[i]; \
    float _u  = __int_as_float(uv[i] << 16); \
    float _a0 = __builtin_amdgcn_exp2f(_dl * A0); \
    float _a1 = __builtin_amdgcn_exp2f(_dl * A1); \
    float _a2 = __builtin_amdgcn_exp2f(_dl * A2); \
    float _a3 = __builtin_amdgcn_exp2f(_dl * A3); \
    float _du = _dl * _u; \
    s0 = _a0 * s0 + _du * bc0[i].x; \
    s1 = _a1 * s1 + _du * bc0[i].z; \
    s2 = _a2 * s2 + _du * bc1[i].x; \
    s3 = _a3 * s3 + _du * bc1[i].z; \
    float _p  = s0 * bc0[i].y + s1 * bc0[i].w; \
    float _p2 = s2 * bc1[i].y + s3 * bc1[i].w; \
    _p += _p2; \
    _p += __int_as_float(__builtin_amdgcn_mov_dpp(__float_as_int(_p), 0xB1, 0xF, 0xF, true)); \
    _p += __int_as_float(__builtin_amdgcn_mov_dpp(__float_as_int(_p), 0x4E, 0xF, 0xF, true)); \
    if (n3 == 0) { \
        float _g = __int_as_float(uv[i] & 0xFFFF0000u); \
        py[(i) * 1024] = __float2bfloat16((_p + _u * Dd) * _g); \
    } }

    LOADSLOT(0) LOADSLOT(1) LOADSLOT(2) LOADSLOT(3)
    LOADSLOT(4) LOADSLOT(5) LOADSLOT(6) LOADSLOT(7)
    pu += 8 * 1024; pd += 8 * 1024; pb += 8 * 32;

    for (int g = 0; g < 23; ++g) {
        STEP(0) LOADSLOT(0)
        STEP(1) LOADSLOT(1)
        STEP(2) LOADSLOT(2)
        STEP(3) LOADSLOT(3)
        STEP(4) LOADSLOT(4)
        STEP(5) LOADSLOT(5)
        STEP(6) LOADSLOT(6)
        STEP(7) LOADSLOT(7)
        pu += 8 * 1024; pd += 8 * 1024; pb += 8 * 32; py += 8 * 1024;
    }
    STEP(0) LOADSLOT(0)
    STEP(1) LOADSLOT(1)
    STEP(2) LOADSLOT(2)
    STEP(3) LOADSLOT(3)
    STEP(4) STEP(5) STEP(6) STEP(7)
    py += 8 * 1024;
    STEP(0) STEP(1) STEP(2) STEP(3)
#undef LOADSLOT
#undef STEP
}

// mean over sequence: h[16,196,512] f32 -> hm[16,512] f32.  grid (2,16)
__global__ __launch_bounds__(256) void mean_kernel(const float* __restrict__ h,
                                                   float* __restrict__ hm) {
    int c = blockIdx.x * 256 + threadIdx.x;
    int b = blockIdx.y;
    const float* hb = h + (size_t)b * L_SEQ * D_MODEL + c;
    float acc = 0.f;
    #pragma unroll 4
    for (int l = 0; l < L_SEQ; ++l) acc += hb[(size_t)l * D_MODEL];
    hm[b * D_MODEL + c] = acc * (1.f / L_SEQ);
}

// head: out[b][c] = hm[b,:] . head_w[:,c] + head_b[c].  grid (4,16)
__global__ __launch_bounds__(256) void head_kernel(
    const float* __restrict__ hm, const float* __restrict__ head_w,
    const float* __restrict__ head_b, float* __restrict__ out)
{
    __shared__ float hmr[D_MODEL];
    int tid = threadIdx.x;
    int b = blockIdx.y;
    hmr[tid]       = hm[b * D_MODEL + tid];
    hmr[tid + 256] = hm[b * D_MODEL + tid + 256];
    __syncthreads();
    int c = blockIdx.x * 256 + tid;
    if (c >= N_CLASSES) return;
    float acc = head_b[c];
    #pragma unroll 8
    for (int k = 0; k < D_MODEL; ++k)
        acc += hmr[k] * head_w[(size_t)k * N_CLASSES + c];
    out[(size_t)b * N_CLASSES + c] = acc;
}

// ---------------------------------------------------------------------------
extern "C" void kernel_launch(void* const* d_in, const int* in_sizes, int n_in,
                              void* d_out, int out_size, void* d_ws, size_t ws_size,
                              hipStream_t stream) {
    const float* x         = (const float*)d_in[0];
    const float* patch_w   = (const float*)d_in[1];
    const float* patch_b   = (const float*)d_in[2];
    const float* norm_w    = (const float*)d_in[3];
    const float* in_proj_w = (const float*)d_in[4];
    const float* conv_w    = (const float*)d_in[5];
    const float* x_proj_w  = (const float*)d_in[6];
    const float* dt_proj_w = (const float*)d_in[7];
    const float* dt_proj_b = (const float*)d_in[8];
    const float* A_log     = (const float*)d_in[9];
    const float* Dv        = (const float*)d_in[10];
    const float* out_proj_w= (const float*)d_in[11];
    const float* head_w    = (const float*)d_in[12];
    const float* head_b    = (const float*)d_in[13];
    float* out = (float*)d_out;

    char* base = (char*)d_ws;
    size_t off = 0;
    auto alloc = [&](size_t bytes) -> void* {
        void* p = base + off;
        off += (bytes + 255) & ~(size_t)255;
        return p;
    };
    float* pos   = (float*)alloc((size_t)L_SEQ * D_MODEL * 4);
    bf16*  pwT   = (bf16*) alloc((size_t)D_MODEL * PATCH_DIM * 2);
    bf16*  inT   = (bf16*) alloc((size_t)N_LAYERS * 2 * D_INNER * D_MODEL * 2);
    bf16*  WtBig = (bf16*) alloc((size_t)N_LAYERS * NBIG * D_INNER * 2);
    bf16*  opT   = (bf16*) alloc((size_t)N_LAYERS * D_MODEL * D_INNER * 2);
    float* cwT   = (float*)alloc((size_t)N_LAYERS * 4 * D_INNER * 4);
    float* h     = (float*)alloc((size_t)ROWS * D_MODEL * 4);
    bf16*  xn    = (bf16*) alloc((size_t)ROWSP * D_MODEL * 2);
    char*  reg0  = (char*) alloc((size_t)ROWSP * 2 * D_INNER * 2);
    bf16*  p     = (bf16*)reg0;
    bf16*  xr    = (bf16*)reg0;
    bf16*  xs    = (bf16*) alloc((size_t)ROWSP * D_INNER * 2);
    unsigned int* ug = (unsigned int*)alloc((size_t)ROWSP * D_INNER * 4);
    float* delta = (float*)alloc((size_t)ROWSP * D_INNER * 4);
    float* bcb   = (float*)alloc((size_t)ROWS * 32 * 4);
    bf16*  yb    = (bf16*) alloc((size_t)ROWSP * D_INNER * 2);
    float* hm    = (float*)alloc((size_t)BATCH * D_MODEL * 4);

    // ---- prologue + batched weight prep ----
    patchify_kernel<<<(ROWS * PATCH_DIM + 255) / 256, 256, 0, stream>>>(x, p);
    smallprep_kernel<<<968, 256, 0, stream>>>(pos, x_proj_w, WtBig, conv_w, cwT);
    transpose_bf16_kernel<<<dim3(16, 24), 256, 0, stream>>>(
        patch_w, pwT, PATCH_DIM, D_MODEL, D_MODEL, 0, 0);
    transpose_bf16_kernel<<<dim3(64, 16, N_LAYERS), 256, 0, stream>>>(
        in_proj_w, inT, D_MODEL, 2 * D_INNER, 2 * D_INNER,
        (size_t)D_MODEL * 2 * D_INNER, (size_t)2 * D_INNER * D_MODEL);
    transpose_bf16_kernel<<<dim3(16, 32, N_LAYERS), 256, 0, stream>>>(
        out_proj_w, opT, D_INNER, D_MODEL, D_MODEL,
        (size_t)D_INNER * D_MODEL, (size_t)D_MODEL * D_INNER);
    wcomb_kernel<<<dim3(32, 32, N_LAYERS), 256, 0, stream>>>(
        x_proj_w, dt_proj_w, WtBig);

    // h = p @ patch_w + patch_b + pos   (BM=32, grid 400)
    gemm64<2, 32><<<(D_MODEL / 128) * (ROWSP / 32), 256, 0, stream>>>(
        p, pwT, PATCH_DIM, D_MODEL / 128, D_MODEL, ROWS, D_MODEL,
        h, nullptr, patch_b, pos, nullptr);

    for (int layer = 0; layer < N_LAYERS; ++layer) {
        rmsnorm_kernel<<<ROWS / 4, 256, 0, stream>>>(h, norm_w + layer * D_MODEL, xn);

        // xr = xn @ in_proj  [3136,2048] bf16   (BM=64, grid 800)
        gemm64<0, 64><<<(2 * D_INNER / 128) * (ROWSP / 64), 256, 0, stream>>>(
            xn, inT + (size_t)layer * 2 * D_INNER * D_MODEL,
            D_MODEL, 2 * D_INNER / 128, 2 * D_INNER, ROWS, 2 * D_INNER,
            nullptr, xr, nullptr, nullptr, nullptr);

        conv_silu_kernel<<<(ROWS * 128 + 255) / 256, 256, 0, stream>>>(
            xr, cwT + (size_t)layer * 4 * D_INNER, xs, ug);

        // delta = softplus(xs @ W_comb + dtb); bc interleaved   (BM=64, grid 450)
        gemm64<4, 64><<<(NBIG / 128) * (ROWSP / 64), 256, 0, stream>>>(
            xs, WtBig + (size_t)layer * NBIG * D_INNER,
            D_INNER, NBIG / 128, 1056, ROWS, 0,
            delta, nullptr, dt_proj_b + (size_t)layer * D_INNER, nullptr, bcb);

        // state-parallel scan + gate -> yb bf16  (grid 256)
        scan_sp_kernel<<<BATCH * (D_INNER / 64), 256, 0, stream>>>(
            ug, delta, bcb,
            A_log + (size_t)layer * D_INNER * D_STATE,
            Dv + (size_t)layer * D_INNER, yb);

        // h += yb @ out_proj   (BM=32, grid 400)
        gemm64<3, 32><<<(D_MODEL / 128) * (ROWSP / 32), 256, 0, stream>>>(
            yb, opT + (size_t)layer * D_MODEL * D_INNER,
            D_INNER, D_MODEL / 128, D_MODEL, ROWS, D_MODEL,
            h, nullptr, nullptr, nullptr, nullptr);
    }

    mean_kernel<<<dim3(2, BATCH), 256, 0, stream>>>(h, hm);
    head_kernel<<<dim3(4, BATCH), 256, 0, stream>>>(hm, head_w, head_b, out);
}

// Round 14
// 480.924 us; speedup vs baseline: 2.3920x; 1.0893x over previous
//
#include <hip/hip_runtime.h>
#include <hip/hip_bf16.h>
#include <math.h>

#define BATCH 16
#define L_SEQ 196
#define PATCH_DIM 768
#define D_MODEL 512
#define D_INNER 1024
#define D_STATE 16
#define D_CONV 4
#define DT_RANK 32
#define N_LAYERS 4
#define N_CLASSES 1000
#define ROWS (BATCH * L_SEQ)   // 3136
#define ROWSP 3200             // padded (multiple of 64)
#define NBIG 1152              // delta(1024) + bc(32), padded to 128

typedef __hip_bfloat16 bf16;
typedef __attribute__((ext_vector_type(8))) __bf16 bf16x8;
typedef __attribute__((ext_vector_type(8))) short short8;
typedef __attribute__((ext_vector_type(4))) float f32x4;

__device__ __forceinline__ void gload_lds16(const void* g, void* l) {
    __builtin_amdgcn_global_load_lds((const __attribute__((address_space(1))) void*)g,
                                     (__attribute__((address_space(3))) void*)l, 16, 0, 0);
}
__device__ __forceinline__ float bfbits2f(int b) {
    return __int_as_float(((unsigned)b & 0xFFFFu) << 16);
}
__device__ __forceinline__ unsigned short f2bfbits(float f) {
    __hip_bfloat16 h = __float2bfloat16(f);
    return *reinterpret_cast<unsigned short*>(&h);
}

// ---------------------------------------------------------------------------
// patchify: x[B,224,224,3] -> p[3136,768] bf16
__global__ void patchify_kernel(const float* __restrict__ x, bf16* __restrict__ p) {
    int idx = blockIdx.x * 256 + threadIdx.x;
    if (idx >= ROWS * PATCH_DIM) return;
    int k = idx % PATCH_DIM, row = idx / PATCH_DIM;
    int b = row / L_SEQ, l = row % L_SEQ;
    int i = l / 14, j = l % 14;
    int ph = k / 48, r = k % 48, pw = r / 3, c = r % 3;
    size_t src = (((size_t)b * 224 + i * 16 + ph) * 224 + (j * 16 + pw)) * 3 + c;
    p[idx] = __float2bfloat16(x[src]);
}

// merged small prep: [0,392) posemb; [392,904) bcw; [904,968) cwt
__global__ void smallprep_kernel(float* __restrict__ pos,
                                 const float* __restrict__ xpw_all,
                                 bf16* __restrict__ WtBig_all,
                                 const float* __restrict__ cw,
                                 float* __restrict__ cwT) {
    int bid = blockIdx.x, tid = threadIdx.x;
    if (bid < 392) {
        int idx = bid * 256 + tid;
        if (idx >= L_SEQ * D_MODEL) return;
        int l = idx >> 9, col = idx & 511;
        int qd = col >> 7, wi = col & 127;
        float omega = powf(10000.f, -(float)wi / 127.f);
        float yv = (float)(l / 14), xv = (float)(l % 14);
        float arg = (qd < 2 ? xv : yv) * omega;
        pos[idx] = (qd & 1) ? cosf(arg) : sinf(arg);
    } else if (bid < 904) {
        int z = (bid - 392) >> 7;
        int idx = ((bid - 392) & 127) * 256 + tid;
        const float* xpw = xpw_all + (size_t)z * D_INNER * 64;
        bf16* WtBig = WtBig_all + (size_t)z * NBIG * D_INNER;
        int j = idx >> 10, k = idx & 1023;
        int src = (j & 1) ? 48 + (j >> 1) : 32 + (j >> 1);
        WtBig[(size_t)(1024 + j) * 1024 + k] = __float2bfloat16(xpw[k * 64 + src]);
    } else {
        int z = (bid - 904) >> 4;
        int idx = ((bid - 904) & 15) * 256 + tid;
        int d = idx >> 2, k = idx & 3;
        cwT[(size_t)z * 4096 + k * 1024 + d] = cw[(size_t)z * 4096 + d * 4 + k];
    }
}

// transpose-convert: src[K][N] f32 -> dst[Npad][K] bf16 (zero-fill), z = layer
__global__ __launch_bounds__(256) void transpose_bf16_kernel(
    const float* __restrict__ src, bf16* __restrict__ dst,
    int K, int N, int Npad, size_t src_lstride, size_t dst_lstride)
{
    src += (size_t)blockIdx.z * src_lstride;
    dst += (size_t)blockIdx.z * dst_lstride;
    __shared__ float tile[32][33];
    int kb = blockIdx.y * 32, nb = blockIdx.x * 32;
    int tx = threadIdx.x & 31, ty = threadIdx.x >> 5;  // 32 x 8
    #pragma unroll
    for (int i = 0; i < 4; ++i) {
        int k = kb + ty + 8 * i, n = nb + tx;
        tile[ty + 8 * i][tx] = (k < K && n < N) ? src[(size_t)k * N + n] : 0.f;
    }
    __syncthreads();
    #pragma unroll
    for (int i = 0; i < 4; ++i) {
        int n = nb + ty + 8 * i, k = kb + tx;
        if (n < Npad && k < K) dst[(size_t)n * K + k] = __float2bfloat16(tile[tx][ty + 8 * i]);
    }
}

// W_comb^T bf16: Wt[z][n][k] = sum_{r<32} dtw_z[r][n] * xpw_z[k][r]
__global__ __launch_bounds__(256) void wcomb_kernel(
    const float* __restrict__ xpw_all,   // [z][1024][64]
    const float* __restrict__ dtw_all,   // [z][32][1024]
    bf16* __restrict__ WtBig_all)        // [z][NBIG][1024]
{
    int z = blockIdx.z;
    const float* xpw = xpw_all + (size_t)z * D_INNER * 64;
    const float* dtw = dtw_all + (size_t)z * DT_RANK * D_INNER;
    bf16* Wt = WtBig_all + (size_t)z * NBIG * D_INNER;
    __shared__ float sd[32][33];  // [r][n]
    __shared__ float sx[32][33];  // [k][r]
    int n0 = blockIdx.x * 32, k0 = blockIdx.y * 32;
    int tid = threadIdx.x;
    #pragma unroll
    for (int i = 0; i < 4; ++i) {
        int e = tid + 256 * i;
        sd[e >> 5][e & 31] = dtw[(size_t)(e >> 5) * D_INNER + n0 + (e & 31)];
        sx[e >> 5][e & 31] = xpw[(size_t)(k0 + (e >> 5)) * 64 + (e & 31)];
    }
    __syncthreads();
    int ty = tid >> 4, tx = tid & 15;
    int nn = ty * 2, kk = tx * 2;
    float a00 = 0.f, a01 = 0.f, a10 = 0.f, a11 = 0.f;
    #pragma unroll
    for (int r = 0; r < 32; ++r) {
        float d0 = sd[r][nn], d1 = sd[r][nn + 1];
        float x0 = sx[kk][r], x1 = sx[kk + 1][r];
        a00 += d0 * x0; a01 += d0 * x1;
        a10 += d1 * x0; a11 += d1 * x1;
    }
    Wt[(size_t)(n0 + nn) * D_INNER + k0 + kk]           = __float2bfloat16(a00);
    Wt[(size_t)(n0 + nn) * D_INNER + k0 + kk + 1]       = __float2bfloat16(a01);
    Wt[(size_t)(n0 + nn + 1) * D_INNER + k0 + kk]       = __float2bfloat16(a10);
    Wt[(size_t)(n0 + nn + 1) * D_INNER + k0 + kk + 1]   = __float2bfloat16(a11);
}

// ---------------------------------------------------------------------------
// Unified bf16 MFMA GEMM: BM∈{32,64}, BN=128, BK=64, 4 waves (2Mx2N), 16x16x32.
// RING-3 LDS, depth-2 prefetch, counted vmcnt.  Stage issue moved INTO the
// compute phase (after ds_reads): wait only covers loads issued 2 steps ago.
// setprio(1) around MFMA cluster (T5).
template<int MODE, int BM>
__global__ __launch_bounds__(256) void gemm64(
    const bf16* __restrict__ A, const bf16* __restrict__ Wt,
    int K, int gx, int Nstore, int M, int ldc,
    float* __restrict__ Cf, bf16* __restrict__ Cb,
    const float* __restrict__ bias, const float* __restrict__ pos,
    float* __restrict__ Cf2)
{
    constexpr int MI = BM / 32;
    constexpr int NL = (BM == 64) ? 6 : 5;
    int nwg = gridDim.x, bid = blockIdx.x;
    int q = nwg >> 3, r = nwg & 7;
    int xcd = bid & 7, sub = bid >> 3;
    int wgid = (xcd < r ? xcd * (q + 1) : r * (q + 1) + (xcd - r) * q) + sub;
    int bx = wgid % gx, by = wgid / gx;
    int bm = by * BM, bn = bx * 128;

    __shared__ short Als[3][BM * 64];
    __shared__ short Bls[3][128 * 64];
    int tid = threadIdx.x;
    int lane = tid & 63, wid = tid >> 6;
    int wm = wid >> 1, wn = wid & 1;

    int t3 = tid >> 3, t7 = tid & 7;
    int rA0 = t3,      kA0 = t7 ^ (rA0 & 7);
    int rA1 = 32 + t3, kA1 = t7 ^ (rA1 & 7);
    const bf16* gA0 = A + (size_t)(bm + rA0) * K + kA0 * 8;
    const bf16* gA1 = A + (size_t)(bm + rA1) * K + kA1 * 8;
    const int aB0 = (wid * 64) * 8, aB1 = (256 + wid * 64) * 8;
    int rB0 = t3,      kB0 = t7 ^ (rB0 & 7);
    int rB1 = 32 + t3, kB1 = t7 ^ (rB1 & 7);
    int rB2 = 64 + t3, kB2 = t7 ^ (rB2 & 7);
    int rB3 = 96 + t3, kB3 = t7 ^ (rB3 & 7);
    const bf16* gB0 = Wt + (size_t)(bn + rB0) * K + kB0 * 8;
    const bf16* gB1 = Wt + (size_t)(bn + rB1) * K + kB1 * 8;
    const bf16* gB2 = Wt + (size_t)(bn + rB2) * K + kB2 * 8;
    const bf16* gB3 = Wt + (size_t)(bn + rB3) * K + kB3 * 8;
    const int bB0 = (wid * 64) * 8,       bB1 = (256 + wid * 64) * 8;
    const int bB2 = (512 + wid * 64) * 8, bB3 = (768 + wid * 64) * 8;

    auto stage = [&](int buf, int k0) {
        gload_lds16(gA0 + k0, &Als[buf][aB0]);
        if (BM == 64) gload_lds16(gA1 + k0, &Als[buf][aB1]);
        gload_lds16(gB0 + k0, &Bls[buf][bB0]);
        gload_lds16(gB1 + k0, &Bls[buf][bB1]);
        gload_lds16(gB2 + k0, &Bls[buf][bB2]);
        gload_lds16(gB3 + k0, &Bls[buf][bB3]);
    };

    f32x4 acc[MI][4];
    #pragma unroll
    for (int i = 0; i < MI; ++i)
        #pragma unroll
        for (int j = 0; j < 4; ++j)
            acc[i][j] = (f32x4){0.f, 0.f, 0.f, 0.f};

    int nsteps = K >> 6;
    stage(0, 0);
    if (nsteps > 1) stage(1, 64);

    for (int s = 0; s < nsteps; ++s) {
        int buf = s % 3;
        // wait for tile s's loads (issued >=1 full step ago); s+1's stay in flight
        if (s + 1 < nsteps) {
            asm volatile("s_waitcnt vmcnt(%0)" :: "n"(NL) : "memory");
        } else {
            asm volatile("s_waitcnt vmcnt(0)" ::: "memory");
        }
        __builtin_amdgcn_s_barrier();
        __builtin_amdgcn_sched_barrier(0);

        bf16x8 af[2][MI], bfr[2][4];
        #pragma unroll
        for (int kw = 0; kw < 2; ++kw) {
            int kc = kw * 4 + (lane >> 4);
            #pragma unroll
            for (int mi = 0; mi < MI; ++mi) {
                int row = wm * (BM / 2) + mi * 16 + (lane & 15);
                int kbp = kc ^ (row & 7);
                af[kw][mi] = *reinterpret_cast<const bf16x8*>(&Als[buf][row * 64 + kbp * 8]);
            }
            #pragma unroll
            for (int nj = 0; nj < 4; ++nj) {
                int row = wn * 64 + nj * 16 + (lane & 15);
                int kbp = kc ^ (row & 7);
                bfr[kw][nj] = *reinterpret_cast<const bf16x8*>(&Bls[buf][row * 64 + kbp * 8]);
            }
        }
        // issue next-next tile's loads while ds_reads are in flight
        if (s + 2 < nsteps) stage((s + 2) % 3, (s + 2) * 64);

        __builtin_amdgcn_s_setprio(1);
        #pragma unroll
        for (int kw = 0; kw < 2; ++kw)
            #pragma unroll
            for (int mi = 0; mi < MI; ++mi)
                #pragma unroll
                for (int nj = 0; nj < 4; ++nj)
                    acc[mi][nj] = __builtin_amdgcn_mfma_f32_16x16x32_bf16(af[kw][mi], bfr[kw][nj], acc[mi][nj], 0, 0, 0);
        __builtin_amdgcn_s_setprio(0);

        __builtin_amdgcn_sched_barrier(0);
        __builtin_amdgcn_s_barrier();
    }

    #pragma unroll
    for (int mi = 0; mi < MI; ++mi) {
        #pragma unroll
        for (int nj = 0; nj < 4; ++nj) {
            int r0 = bm + wm * (BM / 2) + mi * 16 + ((lane >> 4) << 2);
            int col = bn + wn * 64 + nj * 16 + (lane & 15);
            if (col >= Nstore) continue;
            #pragma unroll
            for (int j = 0; j < 4; ++j) {
                int row = r0 + j;
                if (row >= M) continue;
                float v = acc[mi][nj][j];
                if (MODE == 4) {
                    if (col < 1024) {
                        float z = v + bias[col];
                        Cf[(size_t)row * 1024 + col] = (z > 20.f) ? z : log1pf(__expf(z));
                    } else {
                        Cf2[(size_t)row * 32 + (col - 1024)] = v;
                    }
                } else {
                    size_t o = (size_t)row * ldc + col;
                    if (MODE == 0) Cb[o] = __float2bfloat16(v);
                    else if (MODE == 2) Cf[o] = v + bias[col] + pos[(size_t)(row % L_SEQ) * D_MODEL + col];
                    else if (MODE == 3) Cf[o] += v;
                }
            }
        }
    }
}

// ---------------------------------------------------------------------------
// RMSNorm, wave-per-row: 4 rows/block, no barriers, shfl_xor reduce.
__global__ __launch_bounds__(256) void rmsnorm_kernel(
    const float* __restrict__ h, const float* __restrict__ w, bf16* __restrict__ o)
{
    int row = (blockIdx.x << 2) | (threadIdx.x >> 6);
    int lane = threadIdx.x & 63;
    const float* hr = h + (size_t)row * D_MODEL + lane * 8;
    f32x4 v0 = *reinterpret_cast<const f32x4*>(hr);
    f32x4 v1 = *reinterpret_cast<const f32x4*>(hr + 4);
    float ss = v0.x*v0.x + v0.y*v0.y + v0.z*v0.z + v0.w*v0.w
             + v1.x*v1.x + v1.y*v1.y + v1.z*v1.z + v1.w*v1.w;
    #pragma unroll
    for (int off = 32; off; off >>= 1) ss += __shfl_xor(ss, off);
    float sc = rsqrtf(ss * (1.f / D_MODEL) + 1e-5f);
    const float* wr = w + lane * 8;
    f32x4 w0 = *reinterpret_cast<const f32x4*>(wr);
    f32x4 w1 = *reinterpret_cast<const f32x4*>(wr + 4);
    short8 ov;
    ov[0] = (short)f2bfbits(v0.x * sc * w0.x);
    ov[1] = (short)f2bfbits(v0.y * sc * w0.y);
    ov[2] = (short)f2bfbits(v0.z * sc * w0.z);
    ov[3] = (short)f2bfbits(v0.w * sc * w0.w);
    ov[4] = (short)f2bfbits(v1.x * sc * w1.x);
    ov[5] = (short)f2bfbits(v1.y * sc * w1.y);
    ov[6] = (short)f2bfbits(v1.z * sc * w1.z);
    ov[7] = (short)f2bfbits(v1.w * sc * w1.w);
    *reinterpret_cast<short8*>(o + (size_t)row * D_MODEL + lane * 8) = ov;
}

// causal depthwise conv (k=4) + SiLU + gate precompute, vectorized x8 channels.
__global__ __launch_bounds__(256) void conv_silu_kernel(
    const bf16* __restrict__ xr, const float* __restrict__ cwT,
    bf16* __restrict__ xs, unsigned int* __restrict__ ug)
{
    int idx = blockIdx.x * 256 + threadIdx.x;
    if (idx >= ROWS * 128) return;
    int dg = idx & 127, row = idx >> 7;
    int d0 = dg << 3;
    int l = row % L_SEQ;
    float acc[8] = {0.f,0.f,0.f,0.f,0.f,0.f,0.f,0.f};
    #pragma unroll
    for (int k = 0; k < 4; ++k) {
        int ls = l - 3 + k;
        if (ls < 0) continue;
        short8 xv = *reinterpret_cast<const short8*>(xr + (size_t)(row - 3 + k) * 2048 + d0);
        const float* wk = cwT + k * 1024 + d0;
        #pragma unroll
        for (int j = 0; j < 8; ++j)
            acc[j] += bfbits2f(xv[j]) * wk[j];
    }
    short8 rv = *reinterpret_cast<const short8*>(xr + (size_t)row * 2048 + 1024 + d0);
    short8 xsv;
    unsigned ugv[8];
    #pragma unroll
    for (int j = 0; j < 8; ++j) {
        float u = acc[j] / (1.f + __expf(-acc[j]));
        unsigned short ub = f2bfbits(u);
        xsv[j] = (short)ub;
        float res = bfbits2f(rv[j]);
        float g = res / (1.f + __expf(-res));
        ugv[j] = (unsigned)ub | ((unsigned)f2bfbits(g) << 16);
    }
    *reinterpret_cast<short8*>(xs + (size_t)row * 1024 + d0) = xsv;
    uint4* up = reinterpret_cast<uint4*>(ug + (size_t)row * 1024 + d0);
    up[0] = make_uint4(ugv[0], ugv[1], ugv[2], ugv[3]);
    up[1] = make_uint4(ugv[4], ugv[5], ugv[6], ugv[7]);
}

// ---------------------------------------------------------------------------
// State-parallel scan + gate: 4 states/lane, 4 lanes/channel, 64 ch/block.
__global__ __launch_bounds__(256) void scan_sp_kernel(
    const unsigned int* __restrict__ ug, // {u,g} bf16x2  [rows,1024]
    const float* __restrict__ delta,     //               [rows,1024] f32
    const float* __restrict__ bc,        // [rows,32]  {B0,C0,B1,C1,...}
    const float* __restrict__ A_log,     // [1024,16]
    const float* __restrict__ Dv,        // [1024]
    bf16* __restrict__ y)                // [rows,1024] bf16
{
    int tid = threadIdx.x;
    int n3 = tid & 3, ch = tid >> 2;
    int b = blockIdx.x >> 4;
    int d = (((int)blockIdx.x & 15) << 6) | ch;
    size_t bbase = (size_t)b * L_SEQ;

    const float L2E = 1.4426950408889634f;
    float A0 = -__expf(A_log[d * 16 + 4 * n3])     * L2E;
    float A1 = -__expf(A_log[d * 16 + 4 * n3 + 1]) * L2E;
    float A2 = -__expf(A_log[d * 16 + 4 * n3 + 2]) * L2E;
    float A3 = -__expf(A_log[d * 16 + 4 * n3 + 3]) * L2E;
    float Dd = Dv[d];
    float s0 = 0.f, s1 = 0.f, s2 = 0.f, s3 = 0.f;

    const unsigned* pu = ug + bbase * 1024 + d;
    const float*    pd = delta + bbase * 1024 + d;
    const float*    pb = bc + bbase * 32 + 8 * n3;
    bf16*           py = y + bbase * 1024 + d;

    unsigned uv[8];
    float dlv[8];
    f32x4 bc0[8], bc1[8];

#define LOADSLOT(i) { \
    uv[i]  = pu[(i) * 1024]; \
    dlv[i] = pd[(i) * 1024]; \
    bc0[i] = *reinterpret_cast<const f32x4*>(pb + (i) * 32); \
    bc1[i] = *reinterpret_cast<const f32x4*>(pb + (i) * 32 + 4); }

#define STEP(i) { \
    float _dl = dlv[i]; \
    float _u  = __int_as_float(uv[i] << 16); \
    float _a0 = __builtin_amdgcn_exp2f(_dl * A0); \
    float _a1 = __builtin_amdgcn_exp2f(_dl * A1); \
    float _a2 = __builtin_amdgcn_exp2f(_dl * A2); \
    float _a3 = __builtin_amdgcn_exp2f(_dl * A3); \
    float _du = _dl * _u; \
    s0 = _a0 * s0 + _du * bc0[i].x; \
    s1 = _a1 * s1 + _du * bc0[i].z; \
    s2 = _a2 * s2 + _du * bc1[i].x; \
    s3 = _a3 * s3 + _du * bc1[i].z; \
    float _p  = s0 * bc0[i].y + s1 * bc0[i].w; \
    float _p2 = s2 * bc1[i].y + s3 * bc1[i].w; \
    _p += _p2; \
    _p += __int_as_float(__builtin_amdgcn_mov_dpp(__float_as_int(_p), 0xB1, 0xF, 0xF, true)); \
    _p += __int_as_float(__builtin_amdgcn_mov_dpp(__float_as_int(_p), 0x4E, 0xF, 0xF, true)); \
    if (n3 == 0) { \
        float _g = __int_as_float(uv[i] & 0xFFFF0000u); \
        py[(i) * 1024] = __float2bfloat16((_p + _u * Dd) * _g); \
    } }

    LOADSLOT(0) LOADSLOT(1) LOADSLOT(2) LOADSLOT(3)
    LOADSLOT(4) LOADSLOT(5) LOADSLOT(6) LOADSLOT(7)
    pu += 8 * 1024; pd += 8 * 1024; pb += 8 * 32;

    for (int g = 0; g < 23; ++g) {
        STEP(0) LOADSLOT(0)
        STEP(1) LOADSLOT(1)
        STEP(2) LOADSLOT(2)
        STEP(3) LOADSLOT(3)
        STEP(4) LOADSLOT(4)
        STEP(5) LOADSLOT(5)
        STEP(6) LOADSLOT(6)
        STEP(7) LOADSLOT(7)
        pu += 8 * 1024; pd += 8 * 1024; pb += 8 * 32; py += 8 * 1024;
    }
    STEP(0) LOADSLOT(0)
    STEP(1) LOADSLOT(1)
    STEP(2) LOADSLOT(2)
    STEP(3) LOADSLOT(3)
    STEP(4) STEP(5) STEP(6) STEP(7)
    py += 8 * 1024;
    STEP(0) STEP(1) STEP(2) STEP(3)
#undef LOADSLOT
#undef STEP
}

// ---------------------------------------------------------------------------
// fused mean+head: block b owns batch row b.  Phase 1: all 256 threads reduce
// h[b,:,:] over L into hm_s[512] (LDS).  Phase 2: out[b][c] per thread.
__global__ __launch_bounds__(256) void meanhead_kernel(
    const float* __restrict__ h, const float* __restrict__ head_w,
    const float* __restrict__ head_b, float* __restrict__ out)
{
    __shared__ float hm_s[D_MODEL];
    int tid = threadIdx.x;
    int b = blockIdx.y;
    const float* hb = h + (size_t)b * L_SEQ * D_MODEL;
    #pragma unroll
    for (int half = 0; half < 2; ++half) {
        int c = tid + half * 256;
        float acc = 0.f;
        #pragma unroll 4
        for (int l = 0; l < L_SEQ; ++l) acc += hb[(size_t)l * D_MODEL + c];
        hm_s[c] = acc * (1.f / L_SEQ);
    }
    __syncthreads();
    int c = blockIdx.x * 256 + tid;
    if (c >= N_CLASSES) return;
    float acc = head_b[c];
    #pragma unroll 8
    for (int k = 0; k < D_MODEL; ++k)
        acc += hm_s[k] * head_w[(size_t)k * N_CLASSES + c];
    out[(size_t)b * N_CLASSES + c] = acc;
}

// ---------------------------------------------------------------------------
extern "C" void kernel_launch(void* const* d_in, const int* in_sizes, int n_in,
                              void* d_out, int out_size, void* d_ws, size_t ws_size,
                              hipStream_t stream) {
    const float* x         = (const float*)d_in[0];
    const float* patch_w   = (const float*)d_in[1];
    const float* patch_b   = (const float*)d_in[2];
    const float* norm_w    = (const float*)d_in[3];
    const float* in_proj_w = (const float*)d_in[4];
    const float* conv_w    = (const float*)d_in[5];
    const float* x_proj_w  = (const float*)d_in[6];
    const float* dt_proj_w = (const float*)d_in[7];
    const float* dt_proj_b = (const float*)d_in[8];
    const float* A_log     = (const float*)d_in[9];
    const float* Dv        = (const float*)d_in[10];
    const float* out_proj_w= (const float*)d_in[11];
    const float* head_w    = (const float*)d_in[12];
    const float* head_b    = (const float*)d_in[13];
    float* out = (float*)d_out;

    char* base = (char*)d_ws;
    size_t off = 0;
    auto alloc = [&](size_t bytes) -> void* {
        void* p = base + off;
        off += (bytes + 255) & ~(size_t)255;
        return p;
    };
    float* pos   = (float*)alloc((size_t)L_SEQ * D_MODEL * 4);
    bf16*  pwT   = (bf16*) alloc((size_t)D_MODEL * PATCH_DIM * 2);
    bf16*  inT   = (bf16*) alloc((size_t)N_LAYERS * 2 * D_INNER * D_MODEL * 2);
    bf16*  WtBig = (bf16*) alloc((size_t)N_LAYERS * NBIG * D_INNER * 2);
    bf16*  opT   = (bf16*) alloc((size_t)N_LAYERS * D_MODEL * D_INNER * 2);
    float* cwT   = (float*)alloc((size_t)N_LAYERS * 4 * D_INNER * 4);
    float* h     = (float*)alloc((size_t)ROWS * D_MODEL * 4);
    bf16*  xn    = (bf16*) alloc((size_t)ROWSP * D_MODEL * 2);
    char*  reg0  = (char*) alloc((size_t)ROWSP * 2 * D_INNER * 2);
    bf16*  p     = (bf16*)reg0;
    bf16*  xr    = (bf16*)reg0;
    bf16*  xs    = (bf16*) alloc((size_t)ROWSP * D_INNER * 2);
    unsigned int* ug = (unsigned int*)alloc((size_t)ROWSP * D_INNER * 4);
    float* delta = (float*)alloc((size_t)ROWSP * D_INNER * 4);
    float* bcb   = (float*)alloc((size_t)ROWS * 32 * 4);
    bf16*  yb    = (bf16*) alloc((size_t)ROWSP * D_INNER * 2);

    // ---- prologue + batched weight prep ----
    patchify_kernel<<<(ROWS * PATCH_DIM + 255) / 256, 256, 0, stream>>>(x, p);
    smallprep_kernel<<<968, 256, 0, stream>>>(pos, x_proj_w, WtBig, conv_w, cwT);
    transpose_bf16_kernel<<<dim3(16, 24), 256, 0, stream>>>(
        patch_w, pwT, PATCH_DIM, D_MODEL, D_MODEL, 0, 0);
    transpose_bf16_kernel<<<dim3(64, 16, N_LAYERS), 256, 0, stream>>>(
        in_proj_w, inT, D_MODEL, 2 * D_INNER, 2 * D_INNER,
        (size_t)D_MODEL * 2 * D_INNER, (size_t)2 * D_INNER * D_MODEL);
    transpose_bf16_kernel<<<dim3(16, 32, N_LAYERS), 256, 0, stream>>>(
        out_proj_w, opT, D_INNER, D_MODEL, D_MODEL,
        (size_t)D_INNER * D_MODEL, (size_t)D_MODEL * D_INNER);
    wcomb_kernel<<<dim3(32, 32, N_LAYERS), 256, 0, stream>>>(
        x_proj_w, dt_proj_w, WtBig);

    // h = p @ patch_w + patch_b + pos   (BM=32, grid 400)
    gemm64<2, 32><<<(D_MODEL / 128) * (ROWSP / 32), 256, 0, stream>>>(
        p, pwT, PATCH_DIM, D_MODEL / 128, D_MODEL, ROWS, D_MODEL,
        h, nullptr, patch_b, pos, nullptr);

    for (int layer = 0; layer < N_LAYERS; ++layer) {
        rmsnorm_kernel<<<ROWS / 4, 256, 0, stream>>>(h, norm_w + layer * D_MODEL, xn);

        // xr = xn @ in_proj  [3136,2048] bf16   (BM=64, grid 800)
        gemm64<0, 64><<<(2 * D_INNER / 128) * (ROWSP / 64), 256, 0, stream>>>(
            xn, inT + (size_t)layer * 2 * D_INNER * D_MODEL,
            D_MODEL, 2 * D_INNER / 128, 2 * D_INNER, ROWS, 2 * D_INNER,
            nullptr, xr, nullptr, nullptr, nullptr);

        conv_silu_kernel<<<(ROWS * 128 + 255) / 256, 256, 0, stream>>>(
            xr, cwT + (size_t)layer * 4 * D_INNER, xs, ug);

        // delta = softplus(xs @ W_comb + dtb); bc interleaved   (BM=64, grid 450)
        gemm64<4, 64><<<(NBIG / 128) * (ROWSP / 64), 256, 0, stream>>>(
            xs, WtBig + (size_t)layer * NBIG * D_INNER,
            D_INNER, NBIG / 128, 1056, ROWS, 0,
            delta, nullptr, dt_proj_b + (size_t)layer * D_INNER, nullptr, bcb);

        // state-parallel scan + gate -> yb bf16  (grid 256)
        scan_sp_kernel<<<BATCH * (D_INNER / 64), 256, 0, stream>>>(
            ug, delta, bcb,
            A_log + (size_t)layer * D_INNER * D_STATE,
            Dv + (size_t)layer * D_INNER, yb);

        // h += yb @ out_proj   (BM=32, grid 400)
        gemm64<3, 32><<<(D_MODEL / 128) * (ROWSP / 32), 256, 0, stream>>>(
            yb, opT + (size_t)layer * D_MODEL * D_INNER,
            D_INNER, D_MODEL / 128, D_MODEL, ROWS, D_MODEL,
            h, nullptr, nullptr, nullptr, nullptr);
    }

    meanhead_kernel<<<dim3(4, BATCH), 256, 0, stream>>>(h, head_w, head_b, out);
}

// Round 15
// 479.584 us; speedup vs baseline: 2.3987x; 1.0028x over previous
//
#include <hip/hip_runtime.h>
#include <hip/hip_bf16.h>
#include <math.h>

#define BATCH 16
#define L_SEQ 196
#define PATCH_DIM 768
#define D_MODEL 512
#define D_INNER 1024
#define D_STATE 16
#define D_CONV 4
#define DT_RANK 32
#define N_LAYERS 4
#define N_CLASSES 1000
#define ROWS (BATCH * L_SEQ)   // 3136
#define ROWSP 3200             // padded (multiple of 64)
#define NBIG 1152              // delta(1024) + bc(32), padded to 128

typedef __hip_bfloat16 bf16;
typedef __attribute__((ext_vector_type(8))) __bf16 bf16x8;
typedef __attribute__((ext_vector_type(8))) short short8;
typedef __attribute__((ext_vector_type(4))) float f32x4;

__device__ __forceinline__ void gload_lds16(const void* g, void* l) {
    __builtin_amdgcn_global_load_lds((const __attribute__((address_space(1))) void*)g,
                                     (__attribute__((address_space(3))) void*)l, 16, 0, 0);
}
__device__ __forceinline__ float bfbits2f(int b) {
    return __int_as_float(((unsigned)b & 0xFFFFu) << 16);
}
__device__ __forceinline__ unsigned short f2bfbits(float f) {
    __hip_bfloat16 h = __float2bfloat16(f);
    return *reinterpret_cast<unsigned short*>(&h);
}

// ---------------------------------------------------------------------------
// patchify: x[B,224,224,3] -> p[3136,768] bf16
__global__ void patchify_kernel(const float* __restrict__ x, bf16* __restrict__ p) {
    int idx = blockIdx.x * 256 + threadIdx.x;
    if (idx >= ROWS * PATCH_DIM) return;
    int k = idx % PATCH_DIM, row = idx / PATCH_DIM;
    int b = row / L_SEQ, l = row % L_SEQ;
    int i = l / 14, j = l % 14;
    int ph = k / 48, r = k % 48, pw = r / 3, c = r % 3;
    size_t src = (((size_t)b * 224 + i * 16 + ph) * 224 + (j * 16 + pw)) * 3 + c;
    p[idx] = __float2bfloat16(x[src]);
}

// merged small prep: [0,392) posemb; [392,904) bcw; [904,968) cwt
__global__ void smallprep_kernel(float* __restrict__ pos,
                                 const float* __restrict__ xpw_all,
                                 bf16* __restrict__ WtBig_all,
                                 const float* __restrict__ cw,
                                 float* __restrict__ cwT) {
    int bid = blockIdx.x, tid = threadIdx.x;
    if (bid < 392) {
        int idx = bid * 256 + tid;
        if (idx >= L_SEQ * D_MODEL) return;
        int l = idx >> 9, col = idx & 511;
        int qd = col >> 7, wi = col & 127;
        float omega = powf(10000.f, -(float)wi / 127.f);
        float yv = (float)(l / 14), xv = (float)(l % 14);
        float arg = (qd < 2 ? xv : yv) * omega;
        pos[idx] = (qd & 1) ? cosf(arg) : sinf(arg);
    } else if (bid < 904) {
        int z = (bid - 392) >> 7;
        int idx = ((bid - 392) & 127) * 256 + tid;
        const float* xpw = xpw_all + (size_t)z * D_INNER * 64;
        bf16* WtBig = WtBig_all + (size_t)z * NBIG * D_INNER;
        int j = idx >> 10, k = idx & 1023;
        int src = (j & 1) ? 48 + (j >> 1) : 32 + (j >> 1);
        WtBig[(size_t)(1024 + j) * 1024 + k] = __float2bfloat16(xpw[k * 64 + src]);
    } else {
        int z = (bid - 904) >> 4;
        int idx = ((bid - 904) & 15) * 256 + tid;
        int d = idx >> 2, k = idx & 3;
        cwT[(size_t)z * 4096 + k * 1024 + d] = cw[(size_t)z * 4096 + d * 4 + k];
    }
}

// transpose-convert: src[K][N] f32 -> dst[Npad][K] bf16 (zero-fill), z = layer
__global__ __launch_bounds__(256) void transpose_bf16_kernel(
    const float* __restrict__ src, bf16* __restrict__ dst,
    int K, int N, int Npad, size_t src_lstride, size_t dst_lstride)
{
    src += (size_t)blockIdx.z * src_lstride;
    dst += (size_t)blockIdx.z * dst_lstride;
    __shared__ float tile[32][33];
    int kb = blockIdx.y * 32, nb = blockIdx.x * 32;
    int tx = threadIdx.x & 31, ty = threadIdx.x >> 5;  // 32 x 8
    #pragma unroll
    for (int i = 0; i < 4; ++i) {
        int k = kb + ty + 8 * i, n = nb + tx;
        tile[ty + 8 * i][tx] = (k < K && n < N) ? src[(size_t)k * N + n] : 0.f;
    }
    __syncthreads();
    #pragma unroll
    for (int i = 0; i < 4; ++i) {
        int n = nb + ty + 8 * i, k = kb + tx;
        if (n < Npad && k < K) dst[(size_t)n * K + k] = __float2bfloat16(tile[tx][ty + 8 * i]);
    }
}

// W_comb^T bf16: Wt[z][n][k] = sum_{r<32} dtw_z[r][n] * xpw_z[k][r]
__global__ __launch_bounds__(256) void wcomb_kernel(
    const float* __restrict__ xpw_all,   // [z][1024][64]
    const float* __restrict__ dtw_all,   // [z][32][1024]
    bf16* __restrict__ WtBig_all)        // [z][NBIG][1024]
{
    int z = blockIdx.z;
    const float* xpw = xpw_all + (size_t)z * D_INNER * 64;
    const float* dtw = dtw_all + (size_t)z * DT_RANK * D_INNER;
    bf16* Wt = WtBig_all + (size_t)z * NBIG * D_INNER;
    __shared__ float sd[32][33];  // [r][n]
    __shared__ float sx[32][33];  // [k][r]
    int n0 = blockIdx.x * 32, k0 = blockIdx.y * 32;
    int tid = threadIdx.x;
    #pragma unroll
    for (int i = 0; i < 4; ++i) {
        int e = tid + 256 * i;
        sd[e >> 5][e & 31] = dtw[(size_t)(e >> 5) * D_INNER + n0 + (e & 31)];
        sx[e >> 5][e & 31] = xpw[(size_t)(k0 + (e >> 5)) * 64 + (e & 31)];
    }
    __syncthreads();
    int ty = tid >> 4, tx = tid & 15;
    int nn = ty * 2, kk = tx * 2;
    float a00 = 0.f, a01 = 0.f, a10 = 0.f, a11 = 0.f;
    #pragma unroll
    for (int r = 0; r < 32; ++r) {
        float d0 = sd[r][nn], d1 = sd[r][nn + 1];
        float x0 = sx[kk][r], x1 = sx[kk + 1][r];
        a00 += d0 * x0; a01 += d0 * x1;
        a10 += d1 * x0; a11 += d1 * x1;
    }
    Wt[(size_t)(n0 + nn) * D_INNER + k0 + kk]           = __float2bfloat16(a00);
    Wt[(size_t)(n0 + nn) * D_INNER + k0 + kk + 1]       = __float2bfloat16(a01);
    Wt[(size_t)(n0 + nn + 1) * D_INNER + k0 + kk]       = __float2bfloat16(a10);
    Wt[(size_t)(n0 + nn + 1) * D_INNER + k0 + kk + 1]   = __float2bfloat16(a11);
}

// ---------------------------------------------------------------------------
// Unified bf16 MFMA GEMM: BM∈{32,64}, BN=128, BK=64, 4 waves (2Mx2N), 16x16x32.
// RING-3 LDS, depth-2 prefetch, counted vmcnt; stage issued inside compute
// phase; setprio(1) around MFMA cluster.
template<int MODE, int BM>
__global__ __launch_bounds__(256) void gemm64(
    const bf16* __restrict__ A, const bf16* __restrict__ Wt,
    int K, int gx, int Nstore, int M, int ldc,
    float* __restrict__ Cf, bf16* __restrict__ Cb,
    const float* __restrict__ bias, const float* __restrict__ pos,
    float* __restrict__ Cf2)
{
    constexpr int MI = BM / 32;
    constexpr int NL = (BM == 64) ? 6 : 5;
    int nwg = gridDim.x, bid = blockIdx.x;
    int q = nwg >> 3, r = nwg & 7;
    int xcd = bid & 7, sub = bid >> 3;
    int wgid = (xcd < r ? xcd * (q + 1) : r * (q + 1) + (xcd - r) * q) + sub;
    int bx = wgid % gx, by = wgid / gx;
    int bm = by * BM, bn = bx * 128;

    __shared__ short Als[3][BM * 64];
    __shared__ short Bls[3][128 * 64];
    int tid = threadIdx.x;
    int lane = tid & 63, wid = tid >> 6;
    int wm = wid >> 1, wn = wid & 1;

    int t3 = tid >> 3, t7 = tid & 7;
    int rA0 = t3,      kA0 = t7 ^ (rA0 & 7);
    int rA1 = 32 + t3, kA1 = t7 ^ (rA1 & 7);
    const bf16* gA0 = A + (size_t)(bm + rA0) * K + kA0 * 8;
    const bf16* gA1 = A + (size_t)(bm + rA1) * K + kA1 * 8;
    const int aB0 = (wid * 64) * 8, aB1 = (256 + wid * 64) * 8;
    int rB0 = t3,      kB0 = t7 ^ (rB0 & 7);
    int rB1 = 32 + t3, kB1 = t7 ^ (rB1 & 7);
    int rB2 = 64 + t3, kB2 = t7 ^ (rB2 & 7);
    int rB3 = 96 + t3, kB3 = t7 ^ (rB3 & 7);
    const bf16* gB0 = Wt + (size_t)(bn + rB0) * K + kB0 * 8;
    const bf16* gB1 = Wt + (size_t)(bn + rB1) * K + kB1 * 8;
    const bf16* gB2 = Wt + (size_t)(bn + rB2) * K + kB2 * 8;
    const bf16* gB3 = Wt + (size_t)(bn + rB3) * K + kB3 * 8;
    const int bB0 = (wid * 64) * 8,       bB1 = (256 + wid * 64) * 8;
    const int bB2 = (512 + wid * 64) * 8, bB3 = (768 + wid * 64) * 8;

    auto stage = [&](int buf, int k0) {
        gload_lds16(gA0 + k0, &Als[buf][aB0]);
        if (BM == 64) gload_lds16(gA1 + k0, &Als[buf][aB1]);
        gload_lds16(gB0 + k0, &Bls[buf][bB0]);
        gload_lds16(gB1 + k0, &Bls[buf][bB1]);
        gload_lds16(gB2 + k0, &Bls[buf][bB2]);
        gload_lds16(gB3 + k0, &Bls[buf][bB3]);
    };

    f32x4 acc[MI][4];
    #pragma unroll
    for (int i = 0; i < MI; ++i)
        #pragma unroll
        for (int j = 0; j < 4; ++j)
            acc[i][j] = (f32x4){0.f, 0.f, 0.f, 0.f};

    int nsteps = K >> 6;
    stage(0, 0);
    if (nsteps > 1) stage(1, 64);

    for (int s = 0; s < nsteps; ++s) {
        int buf = s % 3;
        if (s + 1 < nsteps) {
            asm volatile("s_waitcnt vmcnt(%0)" :: "n"(NL) : "memory");
        } else {
            asm volatile("s_waitcnt vmcnt(0)" ::: "memory");
        }
        __builtin_amdgcn_s_barrier();
        __builtin_amdgcn_sched_barrier(0);

        bf16x8 af[2][MI], bfr[2][4];
        #pragma unroll
        for (int kw = 0; kw < 2; ++kw) {
            int kc = kw * 4 + (lane >> 4);
            #pragma unroll
            for (int mi = 0; mi < MI; ++mi) {
                int row = wm * (BM / 2) + mi * 16 + (lane & 15);
                int kbp = kc ^ (row & 7);
                af[kw][mi] = *reinterpret_cast<const bf16x8*>(&Als[buf][row * 64 + kbp * 8]);
            }
            #pragma unroll
            for (int nj = 0; nj < 4; ++nj) {
                int row = wn * 64 + nj * 16 + (lane & 15);
                int kbp = kc ^ (row & 7);
                bfr[kw][nj] = *reinterpret_cast<const bf16x8*>(&Bls[buf][row * 64 + kbp * 8]);
            }
        }
        if (s + 2 < nsteps) stage((s + 2) % 3, (s + 2) * 64);

        __builtin_amdgcn_s_setprio(1);
        #pragma unroll
        for (int kw = 0; kw < 2; ++kw)
            #pragma unroll
            for (int mi = 0; mi < MI; ++mi)
                #pragma unroll
                for (int nj = 0; nj < 4; ++nj)
                    acc[mi][nj] = __builtin_amdgcn_mfma_f32_16x16x32_bf16(af[kw][mi], bfr[kw][nj], acc[mi][nj], 0, 0, 0);
        __builtin_amdgcn_s_setprio(0);

        __builtin_amdgcn_sched_barrier(0);
        __builtin_amdgcn_s_barrier();
    }

    #pragma unroll
    for (int mi = 0; mi < MI; ++mi) {
        #pragma unroll
        for (int nj = 0; nj < 4; ++nj) {
            int r0 = bm + wm * (BM / 2) + mi * 16 + ((lane >> 4) << 2);
            int col = bn + wn * 64 + nj * 16 + (lane & 15);
            if (col >= Nstore) continue;
            #pragma unroll
            for (int j = 0; j < 4; ++j) {
                int row = r0 + j;
                if (row >= M) continue;
                float v = acc[mi][nj][j];
                if (MODE == 4) {
                    if (col < 1024) {
                        float z = v + bias[col];
                        Cf[(size_t)row * 1024 + col] = (z > 20.f) ? z : log1pf(__expf(z));
                    } else {
                        Cf2[(size_t)row * 32 + (col - 1024)] = v;
                    }
                } else {
                    size_t o = (size_t)row * ldc + col;
                    if (MODE == 0) Cb[o] = __float2bfloat16(v);
                    else if (MODE == 2) Cf[o] = v + bias[col] + pos[(size_t)(row % L_SEQ) * D_MODEL + col];
                    else if (MODE == 3) Cf[o] += v;
                }
            }
        }
    }
}

// ---------------------------------------------------------------------------
// RMSNorm, wave-per-row: 4 rows/block, no barriers, shfl_xor reduce.
__global__ __launch_bounds__(256) void rmsnorm_kernel(
    const float* __restrict__ h, const float* __restrict__ w, bf16* __restrict__ o)
{
    int row = (blockIdx.x << 2) | (threadIdx.x >> 6);
    int lane = threadIdx.x & 63;
    const float* hr = h + (size_t)row * D_MODEL + lane * 8;
    f32x4 v0 = *reinterpret_cast<const f32x4*>(hr);
    f32x4 v1 = *reinterpret_cast<const f32x4*>(hr + 4);
    float ss = v0.x*v0.x + v0.y*v0.y + v0.z*v0.z + v0.w*v0.w
             + v1.x*v1.x + v1.y*v1.y + v1.z*v1.z + v1.w*v1.w;
    #pragma unroll
    for (int off = 32; off; off >>= 1) ss += __shfl_xor(ss, off);
    float sc = rsqrtf(ss * (1.f / D_MODEL) + 1e-5f);
    const float* wr = w + lane * 8;
    f32x4 w0 = *reinterpret_cast<const f32x4*>(wr);
    f32x4 w1 = *reinterpret_cast<const f32x4*>(wr + 4);
    short8 ov;
    ov[0] = (short)f2bfbits(v0.x * sc * w0.x);
    ov[1] = (short)f2bfbits(v0.y * sc * w0.y);
    ov[2] = (short)f2bfbits(v0.z * sc * w0.z);
    ov[3] = (short)f2bfbits(v0.w * sc * w0.w);
    ov[4] = (short)f2bfbits(v1.x * sc * w1.x);
    ov[5] = (short)f2bfbits(v1.y * sc * w1.y);
    ov[6] = (short)f2bfbits(v1.z * sc * w1.z);
    ov[7] = (short)f2bfbits(v1.w * sc * w1.w);
    *reinterpret_cast<short8*>(o + (size_t)row * D_MODEL + lane * 8) = ov;
}

// causal depthwise conv (k=4) + SiLU + gate precompute, vectorized x8 channels.
__global__ __launch_bounds__(256) void conv_silu_kernel(
    const bf16* __restrict__ xr, const float* __restrict__ cwT,
    bf16* __restrict__ xs, unsigned int* __restrict__ ug)
{
    int idx = blockIdx.x * 256 + threadIdx.x;
    if (idx >= ROWS * 128) return;
    int dg = idx & 127, row = idx >> 7;
    int d0 = dg << 3;
    int l = row % L_SEQ;
    float acc[8] = {0.f,0.f,0.f,0.f,0.f,0.f,0.f,0.f};
    #pragma unroll
    for (int k = 0; k < 4; ++k) {
        int ls = l - 3 + k;
        if (ls < 0) continue;
        short8 xv = *reinterpret_cast<const short8*>(xr + (size_t)(row - 3 + k) * 2048 + d0);
        const float* wk = cwT + k * 1024 + d0;
        #pragma unroll
        for (int j = 0; j < 8; ++j)
            acc[j] += bfbits2f(xv[j]) * wk[j];
    }
    short8 rv = *reinterpret_cast<const short8*>(xr + (size_t)row * 2048 + 1024 + d0);
    short8 xsv;
    unsigned ugv[8];
    #pragma unroll
    for (int j = 0; j < 8; ++j) {
        float u = acc[j] / (1.f + __expf(-acc[j]));
        unsigned short ub = f2bfbits(u);
        xsv[j] = (short)ub;
        float res = bfbits2f(rv[j]);
        float g = res / (1.f + __expf(-res));
        ugv[j] = (unsigned)ub | ((unsigned)f2bfbits(g) << 16);
    }
    *reinterpret_cast<short8*>(xs + (size_t)row * 1024 + d0) = xsv;
    uint4* up = reinterpret_cast<uint4*>(ug + (size_t)row * 1024 + d0);
    up[0] = make_uint4(ugv[0], ugv[1], ugv[2], ugv[3]);
    up[1] = make_uint4(ugv[4], ugv[5], ugv[6], ugv[7]);
}

// ---------------------------------------------------------------------------
// State-parallel scan + gate: 4 states/lane, 4 lanes/channel, 64 ch/block.
__global__ __launch_bounds__(256) void scan_sp_kernel(
    const unsigned int* __restrict__ ug, // {u,g} bf16x2  [rows,1024]
    const float* __restrict__ delta,     //               [rows,1024] f32
    const float* __restrict__ bc,        // [rows,32]  {B0,C0,B1,C1,...}
    const float* __restrict__ A_log,     // [1024,16]
    const float* __restrict__ Dv,        // [1024]
    bf16* __restrict__ y)                // [rows,1024] bf16
{
    int tid = threadIdx.x;
    int n3 = tid & 3, ch = tid >> 2;
    int b = blockIdx.x >> 4;
    int d = (((int)blockIdx.x & 15) << 6) | ch;
    size_t bbase = (size_t)b * L_SEQ;

    const float L2E = 1.4426950408889634f;
    float A0 = -__expf(A_log[d * 16 + 4 * n3])     * L2E;
    float A1 = -__expf(A_log[d * 16 + 4 * n3 + 1]) * L2E;
    float A2 = -__expf(A_log[d * 16 + 4 * n3 + 2]) * L2E;
    float A3 = -__expf(A_log[d * 16 + 4 * n3 + 3]) * L2E;
    float Dd = Dv[d];
    float s0 = 0.f, s1 = 0.f, s2 = 0.f, s3 = 0.f;

    const unsigned* pu = ug + bbase * 1024 + d;
    const float*    pd = delta + bbase * 1024 + d;
    const float*    pb = bc + bbase * 32 + 8 * n3;
    bf16*           py = y + bbase * 1024 + d;

    unsigned uv[8];
    float dlv[8];
    f32x4 bc0[8], bc1[8];

#define LOADSLOT(i) { \
    uv[i]  = pu[(i) * 1024]; \
    dlv[i] = pd[(i) * 1024]; \
    bc0[i] = *reinterpret_cast<const f32x4*>(pb + (i) * 32); \
    bc1[i] = *reinterpret_cast<const f32x4*>(pb + (i) * 32 + 4); }

#define STEP(i) { \
    float _dl = dlv[i]; \
    float _u  = __int_as_float(uv[i] << 16); \
    float _a0 = __builtin_amdgcn_exp2f(_dl * A0); \
    float _a1 = __builtin_amdgcn_exp2f(_dl * A1); \
    float _a2 = __builtin_amdgcn_exp2f(_dl * A2); \
    float _a3 = __builtin_amdgcn_exp2f(_dl * A3); \
    float _du = _dl * _u; \
    s0 = _a0 * s0 + _du * bc0[i].x; \
    s1 = _a1 * s1 + _du * bc0[i].z; \
    s2 = _a2 * s2 + _du * bc1[i].x; \
    s3 = _a3 * s3 + _du * bc1[i].z; \
    float _p  = s0 * bc0[i].y + s1 * bc0[i].w; \
    float _p2 = s2 * bc1[i].y + s3 * bc1[i].w; \
    _p += _p2; \
    _p += __int_as_float(__builtin_amdgcn_mov_dpp(__float_as_int(_p), 0xB1, 0xF, 0xF, true)); \
    _p += __int_as_float(__builtin_amdgcn_mov_dpp(__float_as_int(_p), 0x4E, 0xF, 0xF, true)); \
    if (n3 == 0) { \
        float _g = __int_as_float(uv[i] & 0xFFFF0000u); \
        py[(i) * 1024] = __float2bfloat16((_p + _u * Dd) * _g); \
    } }

    LOADSLOT(0) LOADSLOT(1) LOADSLOT(2) LOADSLOT(3)
    LOADSLOT(4) LOADSLOT(5) LOADSLOT(6) LOADSLOT(7)
    pu += 8 * 1024; pd += 8 * 1024; pb += 8 * 32;

    for (int g = 0; g < 23; ++g) {
        STEP(0) LOADSLOT(0)
        STEP(1) LOADSLOT(1)
        STEP(2) LOADSLOT(2)
        STEP(3) LOADSLOT(3)
        STEP(4) LOADSLOT(4)
        STEP(5) LOADSLOT(5)
        STEP(6) LOADSLOT(6)
        STEP(7) LOADSLOT(7)
        pu += 8 * 1024; pd += 8 * 1024; pb += 8 * 32; py += 8 * 1024;
    }
    STEP(0) LOADSLOT(0)
    STEP(1) LOADSLOT(1)
    STEP(2) LOADSLOT(2)
    STEP(3) LOADSLOT(3)
    STEP(4) STEP(5) STEP(6) STEP(7)
    py += 8 * 1024;
    STEP(0) STEP(1) STEP(2) STEP(3)
#undef LOADSLOT
#undef STEP
}

// mean over sequence: h[16,196,512] f32 -> hm[16,512] f32.  grid (2,16)
__global__ __launch_bounds__(256) void mean_kernel(const float* __restrict__ h,
                                                   float* __restrict__ hm) {
    int c = blockIdx.x * 256 + threadIdx.x;
    int b = blockIdx.y;
    const float* hb = h + (size_t)b * L_SEQ * D_MODEL + c;
    float acc = 0.f;
    #pragma unroll 8
    for (int l = 0; l < L_SEQ; ++l) acc += hb[(size_t)l * D_MODEL];
    hm[b * D_MODEL + c] = acc * (1.f / L_SEQ);
}

// head: out[b][c] = hm[b,:] . head_w[:,c] + head_b[c].  grid (4,16)
__global__ __launch_bounds__(256) void head_kernel(
    const float* __restrict__ hm, const float* __restrict__ head_w,
    const float* __restrict__ head_b, float* __restrict__ out)
{
    __shared__ float hmr[D_MODEL];
    int tid = threadIdx.x;
    int b = blockIdx.y;
    hmr[tid]       = hm[b * D_MODEL + tid];
    hmr[tid + 256] = hm[b * D_MODEL + tid + 256];
    __syncthreads();
    int c = blockIdx.x * 256 + tid;
    if (c >= N_CLASSES) return;
    float acc = head_b[c];
    #pragma unroll 8
    for (int k = 0; k < D_MODEL; ++k)
        acc += hmr[k] * head_w[(size_t)k * N_CLASSES + c];
    out[(size_t)b * N_CLASSES + c] = acc;
}

// ---------------------------------------------------------------------------
extern "C" void kernel_launch(void* const* d_in, const int* in_sizes, int n_in,
                              void* d_out, int out_size, void* d_ws, size_t ws_size,
                              hipStream_t stream) {
    const float* x         = (const float*)d_in[0];
    const float* patch_w   = (const float*)d_in[1];
    const float* patch_b   = (const float*)d_in[2];
    const float* norm_w    = (const float*)d_in[3];
    const float* in_proj_w = (const float*)d_in[4];
    const float* conv_w    = (const float*)d_in[5];
    const float* x_proj_w  = (const float*)d_in[6];
    const float* dt_proj_w = (const float*)d_in[7];
    const float* dt_proj_b = (const float*)d_in[8];
    const float* A_log     = (const float*)d_in[9];
    const float* Dv        = (const float*)d_in[10];
    const float* out_proj_w= (const float*)d_in[11];
    const float* head_w    = (const float*)d_in[12];
    const float* head_b    = (const float*)d_in[13];
    float* out = (float*)d_out;

    char* base = (char*)d_ws;
    size_t off = 0;
    auto alloc = [&](size_t bytes) -> void* {
        void* p = base + off;
        off += (bytes + 255) & ~(size_t)255;
        return p;
    };
    float* pos   = (float*)alloc((size_t)L_SEQ * D_MODEL * 4);
    bf16*  pwT   = (bf16*) alloc((size_t)D_MODEL * PATCH_DIM * 2);
    bf16*  inT   = (bf16*) alloc((size_t)N_LAYERS * 2 * D_INNER * D_MODEL * 2);
    bf16*  WtBig = (bf16*) alloc((size_t)N_LAYERS * NBIG * D_INNER * 2);
    bf16*  opT   = (bf16*) alloc((size_t)N_LAYERS * D_MODEL * D_INNER * 2);
    float* cwT   = (float*)alloc((size_t)N_LAYERS * 4 * D_INNER * 4);
    float* h     = (float*)alloc((size_t)ROWS * D_MODEL * 4);
    bf16*  xn    = (bf16*) alloc((size_t)ROWSP * D_MODEL * 2);
    char*  reg0  = (char*) alloc((size_t)ROWSP * 2 * D_INNER * 2);
    bf16*  p     = (bf16*)reg0;
    bf16*  xr    = (bf16*)reg0;
    bf16*  xs    = (bf16*) alloc((size_t)ROWSP * D_INNER * 2);
    unsigned int* ug = (unsigned int*)alloc((size_t)ROWSP * D_INNER * 4);
    float* delta = (float*)alloc((size_t)ROWSP * D_INNER * 4);
    float* bcb   = (float*)alloc((size_t)ROWS * 32 * 4);
    bf16*  yb    = (bf16*) alloc((size_t)ROWSP * D_INNER * 2);
    float* hm    = (float*)alloc((size_t)BATCH * D_MODEL * 4);

    // ---- prologue + batched weight prep ----
    patchify_kernel<<<(ROWS * PATCH_DIM + 255) / 256, 256, 0, stream>>>(x, p);
    smallprep_kernel<<<968, 256, 0, stream>>>(pos, x_proj_w, WtBig, conv_w, cwT);
    transpose_bf16_kernel<<<dim3(16, 24), 256, 0, stream>>>(
        patch_w, pwT, PATCH_DIM, D_MODEL, D_MODEL, 0, 0);
    transpose_bf16_kernel<<<dim3(64, 16, N_LAYERS), 256, 0, stream>>>(
        in_proj_w, inT, D_MODEL, 2 * D_INNER, 2 * D_INNER,
        (size_t)D_MODEL * 2 * D_INNER, (size_t)2 * D_INNER * D_MODEL);
    transpose_bf16_kernel<<<dim3(16, 32, N_LAYERS), 256, 0, stream>>>(
        out_proj_w, opT, D_INNER, D_MODEL, D_MODEL,
        (size_t)D_INNER * D_MODEL, (size_t)D_MODEL * D_INNER);
    wcomb_kernel<<<dim3(32, 32, N_LAYERS), 256, 0, stream>>>(
        x_proj_w, dt_proj_w, WtBig);

    // h = p @ patch_w + patch_b + pos   (BM=32, grid 400)
    gemm64<2, 32><<<(D_MODEL / 128) * (ROWSP / 32), 256, 0, stream>>>(
        p, pwT, PATCH_DIM, D_MODEL / 128, D_MODEL, ROWS, D_MODEL,
        h, nullptr, patch_b, pos, nullptr);

    for (int layer = 0; layer < N_LAYERS; ++layer) {
        rmsnorm_kernel<<<ROWS / 4, 256, 0, stream>>>(h, norm_w + layer * D_MODEL, xn);

        // xr = xn @ in_proj  [3136,2048] bf16   (BM=64, grid 800)
        gemm64<0, 64><<<(2 * D_INNER / 128) * (ROWSP / 64), 256, 0, stream>>>(
            xn, inT + (size_t)layer * 2 * D_INNER * D_MODEL,
            D_MODEL, 2 * D_INNER / 128, 2 * D_INNER, ROWS, 2 * D_INNER,
            nullptr, xr, nullptr, nullptr, nullptr);

        conv_silu_kernel<<<(ROWS * 128 + 255) / 256, 256, 0, stream>>>(
            xr, cwT + (size_t)layer * 4 * D_INNER, xs, ug);

        // delta = softplus(xs @ W_comb + dtb); bc interleaved   (BM=64, grid 450)
        gemm64<4, 64><<<(NBIG / 128) * (ROWSP / 64), 256, 0, stream>>>(
            xs, WtBig + (size_t)layer * NBIG * D_INNER,
            D_INNER, NBIG / 128, 1056, ROWS, 0,
            delta, nullptr, dt_proj_b + (size_t)layer * D_INNER, nullptr, bcb);

        // state-parallel scan + gate -> yb bf16  (grid 256)
        scan_sp_kernel<<<BATCH * (D_INNER / 64), 256, 0, stream>>>(
            ug, delta, bcb,
            A_log + (size_t)layer * D_INNER * D_STATE,
            Dv + (size_t)layer * D_INNER, yb);

        // h += yb @ out_proj   (BM=32, grid 400)
        gemm64<3, 32><<<(D_MODEL / 128) * (ROWSP / 32), 256, 0, stream>>>(
            yb, opT + (size_t)layer * D_MODEL * D_INNER,
            D_INNER, D_MODEL / 128, D_MODEL, ROWS, D_MODEL,
            h, nullptr, nullptr, nullptr, nullptr);
    }

    mean_kernel<<<dim3(2, BATCH), 256, 0, stream>>>(h, hm);
    head_kernel<<<dim3(4, BATCH), 256, 0, stream>>>(hm, head_w, head_b, out);
}

// Round 16
// 478.805 us; speedup vs baseline: 2.4026x; 1.0016x over previous
//
#include <hip/hip_runtime.h>
#include <hip/hip_bf16.h>
#include <math.h>

#define BATCH 16
#define L_SEQ 196
#define PATCH_DIM 768
#define D_MODEL 512
#define D_INNER 1024
#define D_STATE 16
#define D_CONV 4
#define DT_RANK 32
#define N_LAYERS 4
#define N_CLASSES 1000
#define ROWS (BATCH * L_SEQ)   // 3136
#define ROWSP 3200             // padded (multiple of 64)
#define NBIG 1152              // delta(1024) + bc(32), padded to 128

typedef __hip_bfloat16 bf16;
typedef __attribute__((ext_vector_type(8))) __bf16 bf16x8;
typedef __attribute__((ext_vector_type(8))) short short8;
typedef __attribute__((ext_vector_type(4))) float f32x4;

__device__ __forceinline__ void gload_lds16(const void* g, void* l) {
    __builtin_amdgcn_global_load_lds((const __attribute__((address_space(1))) void*)g,
                                     (__attribute__((address_space(3))) void*)l, 16, 0, 0);
}
__device__ __forceinline__ float bfbits2f(int b) {
    return __int_as_float(((unsigned)b & 0xFFFFu) << 16);
}
__device__ __forceinline__ unsigned short f2bfbits(float f) {
    __hip_bfloat16 h = __float2bfloat16(f);
    return *reinterpret_cast<unsigned short*>(&h);
}

// ---------------------------------------------------------------------------
// patchify: x[B,224,224,3] -> p[3136,768] bf16.  One thread = one pixel (3 ch).
__global__ __launch_bounds__(256) void patchify_kernel(
    const float* __restrict__ x, bf16* __restrict__ p)
{
    int row = blockIdx.x;              // 0..3135
    int t = threadIdx.x;               // pixel within patch: ph*16+pw
    int b = row / L_SEQ, l = row % L_SEQ;
    int i = l / 14, j = l % 14;
    int ph = t >> 4, pw = t & 15;
    const float* src = x + (((size_t)b * 224 + i * 16 + ph) * 224 + (j * 16 + pw)) * 3;
    bf16* dst = p + (size_t)row * PATCH_DIM + t * 3;
    dst[0] = __float2bfloat16(src[0]);
    dst[1] = __float2bfloat16(src[1]);
    dst[2] = __float2bfloat16(src[2]);
}

// merged small prep: [0,392) posemb; [392,904) bcw; [904,968) cwt
__global__ void smallprep_kernel(float* __restrict__ pos,
                                 const float* __restrict__ xpw_all,
                                 bf16* __restrict__ WtBig_all,
                                 const float* __restrict__ cw,
                                 float* __restrict__ cwT) {
    int bid = blockIdx.x, tid = threadIdx.x;
    if (bid < 392) {
        int idx = bid * 256 + tid;
        if (idx >= L_SEQ * D_MODEL) return;
        int l = idx >> 9, col = idx & 511;
        int qd = col >> 7, wi = col & 127;
        float omega = powf(10000.f, -(float)wi / 127.f);
        float yv = (float)(l / 14), xv = (float)(l % 14);
        float arg = (qd < 2 ? xv : yv) * omega;
        pos[idx] = (qd & 1) ? cosf(arg) : sinf(arg);
    } else if (bid < 904) {
        int z = (bid - 392) >> 7;
        int idx = ((bid - 392) & 127) * 256 + tid;
        const float* xpw = xpw_all + (size_t)z * D_INNER * 64;
        bf16* WtBig = WtBig_all + (size_t)z * NBIG * D_INNER;
        int j = idx >> 10, k = idx & 1023;
        int src = (j & 1) ? 48 + (j >> 1) : 32 + (j >> 1);
        WtBig[(size_t)(1024 + j) * 1024 + k] = __float2bfloat16(xpw[k * 64 + src]);
    } else {
        int z = (bid - 904) >> 4;
        int idx = ((bid - 904) & 15) * 256 + tid;
        int d = idx >> 2, k = idx & 3;
        cwT[(size_t)z * 4096 + k * 1024 + d] = cw[(size_t)z * 4096 + d * 4 + k];
    }
}

// transpose-convert: src[K][N] f32 -> dst[Npad][K] bf16 (zero-fill), z = layer
__global__ __launch_bounds__(256) void transpose_bf16_kernel(
    const float* __restrict__ src, bf16* __restrict__ dst,
    int K, int N, int Npad, size_t src_lstride, size_t dst_lstride)
{
    src += (size_t)blockIdx.z * src_lstride;
    dst += (size_t)blockIdx.z * dst_lstride;
    __shared__ float tile[32][33];
    int kb = blockIdx.y * 32, nb = blockIdx.x * 32;
    int tx = threadIdx.x & 31, ty = threadIdx.x >> 5;  // 32 x 8
    #pragma unroll
    for (int i = 0; i < 4; ++i) {
        int k = kb + ty + 8 * i, n = nb + tx;
        tile[ty + 8 * i][tx] = (k < K && n < N) ? src[(size_t)k * N + n] : 0.f;
    }
    __syncthreads();
    #pragma unroll
    for (int i = 0; i < 4; ++i) {
        int n = nb + ty + 8 * i, k = kb + tx;
        if (n < Npad && k < K) dst[(size_t)n * K + k] = __float2bfloat16(tile[tx][ty + 8 * i]);
    }
}

// W_comb^T bf16: Wt[z][n][k] = sum_{r<32} dtw_z[r][n] * xpw_z[k][r]
__global__ __launch_bounds__(256) void wcomb_kernel(
    const float* __restrict__ xpw_all,   // [z][1024][64]
    const float* __restrict__ dtw_all,   // [z][32][1024]
    bf16* __restrict__ WtBig_all)        // [z][NBIG][1024]
{
    int z = blockIdx.z;
    const float* xpw = xpw_all + (size_t)z * D_INNER * 64;
    const float* dtw = dtw_all + (size_t)z * DT_RANK * D_INNER;
    bf16* Wt = WtBig_all + (size_t)z * NBIG * D_INNER;
    __shared__ float sd[32][33];  // [r][n]
    __shared__ float sx[32][33];  // [k][r]
    int n0 = blockIdx.x * 32, k0 = blockIdx.y * 32;
    int tid = threadIdx.x;
    #pragma unroll
    for (int i = 0; i < 4; ++i) {
        int e = tid + 256 * i;
        sd[e >> 5][e & 31] = dtw[(size_t)(e >> 5) * D_INNER + n0 + (e & 31)];
        sx[e >> 5][e & 31] = xpw[(size_t)(k0 + (e >> 5)) * 64 + (e & 31)];
    }
    __syncthreads();
    int ty = tid >> 4, tx = tid & 15;
    int nn = ty * 2, kk = tx * 2;
    float a00 = 0.f, a01 = 0.f, a10 = 0.f, a11 = 0.f;
    #pragma unroll
    for (int r = 0; r < 32; ++r) {
        float d0 = sd[r][nn], d1 = sd[r][nn + 1];
        float x0 = sx[kk][r], x1 = sx[kk + 1][r];
        a00 += d0 * x0; a01 += d0 * x1;
        a10 += d1 * x0; a11 += d1 * x1;
    }
    Wt[(size_t)(n0 + nn) * D_INNER + k0 + kk]           = __float2bfloat16(a00);
    Wt[(size_t)(n0 + nn) * D_INNER + k0 + kk + 1]       = __float2bfloat16(a01);
    Wt[(size_t)(n0 + nn + 1) * D_INNER + k0 + kk]       = __float2bfloat16(a10);
    Wt[(size_t)(n0 + nn + 1) * D_INNER + k0 + kk + 1]   = __float2bfloat16(a11);
}

// ---------------------------------------------------------------------------
// Unified bf16 MFMA GEMM: BM∈{32,64}, BN=128, BK=64, 4 waves (2Mx2N), 16x16x32.
// RING-3 LDS, depth-2 prefetch, counted vmcnt; stage issued inside compute
// phase; setprio(1) around MFMA cluster.
template<int MODE, int BM>
__global__ __launch_bounds__(256) void gemm64(
    const bf16* __restrict__ A, const bf16* __restrict__ Wt,
    int K, int gx, int Nstore, int M, int ldc,
    float* __restrict__ Cf, bf16* __restrict__ Cb,
    const float* __restrict__ bias, const float* __restrict__ pos,
    float* __restrict__ Cf2)
{
    constexpr int MI = BM / 32;
    constexpr int NL = (BM == 64) ? 6 : 5;
    int nwg = gridDim.x, bid = blockIdx.x;
    int q = nwg >> 3, r = nwg & 7;
    int xcd = bid & 7, sub = bid >> 3;
    int wgid = (xcd < r ? xcd * (q + 1) : r * (q + 1) + (xcd - r) * q) + sub;
    int bx = wgid % gx, by = wgid / gx;
    int bm = by * BM, bn = bx * 128;

    __shared__ short Als[3][BM * 64];
    __shared__ short Bls[3][128 * 64];
    int tid = threadIdx.x;
    int lane = tid & 63, wid = tid >> 6;
    int wm = wid >> 1, wn = wid & 1;

    int t3 = tid >> 3, t7 = tid & 7;
    int rA0 = t3,      kA0 = t7 ^ (rA0 & 7);
    int rA1 = 32 + t3, kA1 = t7 ^ (rA1 & 7);
    const bf16* gA0 = A + (size_t)(bm + rA0) * K + kA0 * 8;
    const bf16* gA1 = A + (size_t)(bm + rA1) * K + kA1 * 8;
    const int aB0 = (wid * 64) * 8, aB1 = (256 + wid * 64) * 8;
    int rB0 = t3,      kB0 = t7 ^ (rB0 & 7);
    int rB1 = 32 + t3, kB1 = t7 ^ (rB1 & 7);
    int rB2 = 64 + t3, kB2 = t7 ^ (rB2 & 7);
    int rB3 = 96 + t3, kB3 = t7 ^ (rB3 & 7);
    const bf16* gB0 = Wt + (size_t)(bn + rB0) * K + kB0 * 8;
    const bf16* gB1 = Wt + (size_t)(bn + rB1) * K + kB1 * 8;
    const bf16* gB2 = Wt + (size_t)(bn + rB2) * K + kB2 * 8;
    const bf16* gB3 = Wt + (size_t)(bn + rB3) * K + kB3 * 8;
    const int bB0 = (wid * 64) * 8,       bB1 = (256 + wid * 64) * 8;
    const int bB2 = (512 + wid * 64) * 8, bB3 = (768 + wid * 64) * 8;

    auto stage = [&](int buf, int k0) {
        gload_lds16(gA0 + k0, &Als[buf][aB0]);
        if (BM == 64) gload_lds16(gA1 + k0, &Als[buf][aB1]);
        gload_lds16(gB0 + k0, &Bls[buf][bB0]);
        gload_lds16(gB1 + k0, &Bls[buf][bB1]);
        gload_lds16(gB2 + k0, &Bls[buf][bB2]);
        gload_lds16(gB3 + k0, &Bls[buf][bB3]);
    };

    f32x4 acc[MI][4];
    #pragma unroll
    for (int i = 0; i < MI; ++i)
        #pragma unroll
        for (int j = 0; j < 4; ++j)
            acc[i][j] = (f32x4){0.f, 0.f, 0.f, 0.f};

    int nsteps = K >> 6;
    stage(0, 0);
    if (nsteps > 1) stage(1, 64);

    for (int s = 0; s < nsteps; ++s) {
        int buf = s % 3;
        if (s + 1 < nsteps) {
            asm volatile("s_waitcnt vmcnt(%0)" :: "n"(NL) : "memory");
        } else {
            asm volatile("s_waitcnt vmcnt(0)" ::: "memory");
        }
        __builtin_amdgcn_s_barrier();
        __builtin_amdgcn_sched_barrier(0);

        bf16x8 af[2][MI], bfr[2][4];
        #pragma unroll
        for (int kw = 0; kw < 2; ++kw) {
            int kc = kw * 4 + (lane >> 4);
            #pragma unroll
            for (int mi = 0; mi < MI; ++mi) {
                int row = wm * (BM / 2) + mi * 16 + (lane & 15);
                int kbp = kc ^ (row & 7);
                af[kw][mi] = *reinterpret_cast<const bf16x8*>(&Als[buf][row * 64 + kbp * 8]);
            }
            #pragma unroll
            for (int nj = 0; nj < 4; ++nj) {
                int row = wn * 64 + nj * 16 + (lane & 15);
                int kbp = kc ^ (row & 7);
                bfr[kw][nj] = *reinterpret_cast<const bf16x8*>(&Bls[buf][row * 64 + kbp * 8]);
            }
        }
        if (s + 2 < nsteps) stage((s + 2) % 3, (s + 2) * 64);

        __builtin_amdgcn_s_setprio(1);
        #pragma unroll
        for (int kw = 0; kw < 2; ++kw)
            #pragma unroll
            for (int mi = 0; mi < MI; ++mi)
                #pragma unroll
                for (int nj = 0; nj < 4; ++nj)
                    acc[mi][nj] = __builtin_amdgcn_mfma_f32_16x16x32_bf16(af[kw][mi], bfr[kw][nj], acc[mi][nj], 0, 0, 0);
        __builtin_amdgcn_s_setprio(0);

        __builtin_amdgcn_sched_barrier(0);
        __builtin_amdgcn_s_barrier();
    }

    #pragma unroll
    for (int mi = 0; mi < MI; ++mi) {
        #pragma unroll
        for (int nj = 0; nj < 4; ++nj) {
            int r0 = bm + wm * (BM / 2) + mi * 16 + ((lane >> 4) << 2);
            int col = bn + wn * 64 + nj * 16 + (lane & 15);
            if (col >= Nstore) continue;
            #pragma unroll
            for (int j = 0; j < 4; ++j) {
                int row = r0 + j;
                if (row >= M) continue;
                float v = acc[mi][nj][j];
                if (MODE == 4) {
                    if (col < 1024) {
                        float z = v + bias[col];
                        Cf[(size_t)row * 1024 + col] = (z > 20.f) ? z : log1pf(__expf(z));
                    } else {
                        Cf2[(size_t)row * 32 + (col - 1024)] = v;
                    }
                } else {
                    size_t o = (size_t)row * ldc + col;
                    if (MODE == 0) Cb[o] = __float2bfloat16(v);
                    else if (MODE == 2) Cf[o] = v + bias[col] + pos[(size_t)(row % L_SEQ) * D_MODEL + col];
                    else if (MODE == 3) Cf[o] += v;
                }
            }
        }
    }
}

// ---------------------------------------------------------------------------
// RMSNorm, wave-per-row: 4 rows/block, no barriers, shfl_xor reduce.
__global__ __launch_bounds__(256) void rmsnorm_kernel(
    const float* __restrict__ h, const float* __restrict__ w, bf16* __restrict__ o)
{
    int row = (blockIdx.x << 2) | (threadIdx.x >> 6);
    int lane = threadIdx.x & 63;
    const float* hr = h + (size_t)row * D_MODEL + lane * 8;
    f32x4 v0 = *reinterpret_cast<const f32x4*>(hr);
    f32x4 v1 = *reinterpret_cast<const f32x4*>(hr + 4);
    float ss = v0.x*v0.x + v0.y*v0.y + v0.z*v0.z + v0.w*v0.w
             + v1.x*v1.x + v1.y*v1.y + v1.z*v1.z + v1.w*v1.w;
    #pragma unroll
    for (int off = 32; off; off >>= 1) ss += __shfl_xor(ss, off);
    float sc = rsqrtf(ss * (1.f / D_MODEL) + 1e-5f);
    const float* wr = w + lane * 8;
    f32x4 w0 = *reinterpret_cast<const f32x4*>(wr);
    f32x4 w1 = *reinterpret_cast<const f32x4*>(wr + 4);
    short8 ov;
    ov[0] = (short)f2bfbits(v0.x * sc * w0.x);
    ov[1] = (short)f2bfbits(v0.y * sc * w0.y);
    ov[2] = (short)f2bfbits(v0.z * sc * w0.z);
    ov[3] = (short)f2bfbits(v0.w * sc * w0.w);
    ov[4] = (short)f2bfbits(v1.x * sc * w1.x);
    ov[5] = (short)f2bfbits(v1.y * sc * w1.y);
    ov[6] = (short)f2bfbits(v1.z * sc * w1.z);
    ov[7] = (short)f2bfbits(v1.w * sc * w1.w);
    *reinterpret_cast<short8*>(o + (size_t)row * D_MODEL + lane * 8) = ov;
}

// causal depthwise conv (k=4) + SiLU + gate precompute, vectorized x8 channels.
__global__ __launch_bounds__(256) void conv_silu_kernel(
    const bf16* __restrict__ xr, const float* __restrict__ cwT,
    bf16* __restrict__ xs, unsigned int* __restrict__ ug)
{
    int idx = blockIdx.x * 256 + threadIdx.x;
    if (idx >= ROWS * 128) return;
    int dg = idx & 127, row = idx >> 7;
    int d0 = dg << 3;
    int l = row % L_SEQ;
    float acc[8] = {0.f,0.f,0.f,0.f,0.f,0.f,0.f,0.f};
    #pragma unroll
    for (int k = 0; k < 4; ++k) {
        int ls = l - 3 + k;
        if (ls < 0) continue;
        short8 xv = *reinterpret_cast<const short8*>(xr + (size_t)(row - 3 + k) * 2048 + d0);
        const float* wk = cwT + k * 1024 + d0;
        #pragma unroll
        for (int j = 0; j < 8; ++j)
            acc[j] += bfbits2f(xv[j]) * wk[j];
    }
    short8 rv = *reinterpret_cast<const short8*>(xr + (size_t)row * 2048 + 1024 + d0);
    short8 xsv;
    unsigned ugv[8];
    #pragma unroll
    for (int j = 0; j < 8; ++j) {
        float u = acc[j] / (1.f + __expf(-acc[j]));
        unsigned short ub = f2bfbits(u);
        xsv[j] = (short)ub;
        float res = bfbits2f(rv[j]);
        float g = res / (1.f + __expf(-res));
        ugv[j] = (unsigned)ub | ((unsigned)f2bfbits(g) << 16);
    }
    *reinterpret_cast<short8*>(xs + (size_t)row * 1024 + d0) = xsv;
    uint4* up = reinterpret_cast<uint4*>(ug + (size_t)row * 1024 + d0);
    up[0] = make_uint4(ugv[0], ugv[1], ugv[2], ugv[3]);
    up[1] = make_uint4(ugv[4], ugv[5], ugv[6], ugv[7]);
}

// ---------------------------------------------------------------------------
// State-parallel scan + gate: 4 states/lane, 4 lanes/channel, 64 ch/block.
__global__ __launch_bounds__(256) void scan_sp_kernel(
    const unsigned int* __restrict__ ug, // {u,g} bf16x2  [rows,1024]
    const float* __restrict__ delta,     //               [rows,1024] f32
    const float* __restrict__ bc,        // [rows,32]  {B0,C0,B1,C1,...}
    const float* __restrict__ A_log,     // [1024,16]
    const float* __restrict__ Dv,        // [1024]
    bf16* __restrict__ y)                // [rows,1024] bf16
{
    int tid = threadIdx.x;
    int n3 = tid & 3, ch = tid >> 2;
    int b = blockIdx.x >> 4;
    int d = (((int)blockIdx.x & 15) << 6) | ch;
    size_t bbase = (size_t)b * L_SEQ;

    const float L2E = 1.4426950408889634f;
    float A0 = -__expf(A_log[d * 16 + 4 * n3])     * L2E;
    float A1 = -__expf(A_log[d * 16 + 4 * n3 + 1]) * L2E;
    float A2 = -__expf(A_log[d * 16 + 4 * n3 + 2]) * L2E;
    float A3 = -__expf(A_log[d * 16 + 4 * n3 + 3]) * L2E;
    float Dd = Dv[d];
    float s0 = 0.f, s1 = 0.f, s2 = 0.f, s3 = 0.f;

    const unsigned* pu = ug + bbase * 1024 + d;
    const float*    pd = delta + bbase * 1024 + d;
    const float*    pb = bc + bbase * 32 + 8 * n3;
    bf16*           py = y + bbase * 1024 + d;

    unsigned uv[8];
    float dlv[8];
    f32x4 bc0[8], bc1[8];

#define LOADSLOT(i) { \
    uv[i]  = pu[(i) * 1024]; \
    dlv[i] = pd[(i) * 1024]; \
    bc0[i] = *reinterpret_cast<const f32x4*>(pb + (i) * 32); \
    bc1[i] = *reinterpret_cast<const f32x4*>(pb + (i) * 32 + 4); }

#define STEP(i) { \
    float _dl = dlv[i]; \
    float _u  = __int_as_float(uv[i] << 16); \
    float _a0 = __builtin_amdgcn_exp2f(_dl * A0); \
    float _a1 = __builtin_amdgcn_exp2f(_dl * A1); \
    float _a2 = __builtin_amdgcn_exp2f(_dl * A2); \
    float _a3 = __builtin_amdgcn_exp2f(_dl * A3); \
    float _du = _dl * _u; \
    s0 = _a0 * s0 + _du * bc0[i].x; \
    s1 = _a1 * s1 + _du * bc0[i].z; \
    s2 = _a2 * s2 + _du * bc1[i].x; \
    s3 = _a3 * s3 + _du * bc1[i].z; \
    float _p  = s0 * bc0[i].y + s1 * bc0[i].w; \
    float _p2 = s2 * bc1[i].y + s3 * bc1[i].w; \
    _p += _p2; \
    _p += __int_as_float(__builtin_amdgcn_mov_dpp(__float_as_int(_p), 0xB1, 0xF, 0xF, true)); \
    _p += __int_as_float(__builtin_amdgcn_mov_dpp(__float_as_int(_p), 0x4E, 0xF, 0xF, true)); \
    if (n3 == 0) { \
        float _g = __int_as_float(uv[i] & 0xFFFF0000u); \
        py[(i) * 1024] = __float2bfloat16((_p + _u * Dd) * _g); \
    } }

    LOADSLOT(0) LOADSLOT(1) LOADSLOT(2) LOADSLOT(3)
    LOADSLOT(4) LOADSLOT(5) LOADSLOT(6) LOADSLOT(7)
    pu += 8 * 1024; pd += 8 * 1024; pb += 8 * 32;

    for (int g = 0; g < 23; ++g) {
        STEP(0) LOADSLOT(0)
        STEP(1) LOADSLOT(1)
        STEP(2) LOADSLOT(2)
        STEP(3) LOADSLOT(3)
        STEP(4) LOADSLOT(4)
        STEP(5) LOADSLOT(5)
        STEP(6) LOADSLOT(6)
        STEP(7) LOADSLOT(7)
        pu += 8 * 1024; pd += 8 * 1024; pb += 8 * 32; py += 8 * 1024;
    }
    STEP(0) LOADSLOT(0)
    STEP(1) LOADSLOT(1)
    STEP(2) LOADSLOT(2)
    STEP(3) LOADSLOT(3)
    STEP(4) STEP(5) STEP(6) STEP(7)
    py += 8 * 1024;
    STEP(0) STEP(1) STEP(2) STEP(3)
#undef LOADSLOT
#undef STEP
}

// ---------------------------------------------------------------------------
// two-phase mean.  Phase A: grid (8,16): block (q,b) sums rows q*25..q*25+24
// (clamped to 196) -> hmp[b][q][512].
__global__ __launch_bounds__(256) void mean_part_kernel(
    const float* __restrict__ h, float* __restrict__ hmp)
{
    int q = blockIdx.x, b = blockIdx.y;
    int l0 = q * 25;
    int l1 = min(l0 + 25, L_SEQ);
    const float* hb = h + ((size_t)b * L_SEQ + l0) * D_MODEL;
    #pragma unroll
    for (int half = 0; half < 2; ++half) {
        int c = threadIdx.x + half * 256;
        float acc = 0.f;
        for (int l = l0; l < l1; ++l) {
            acc += hb[c];
            hb += D_MODEL;
        }
        hb -= (size_t)(l1 - l0) * D_MODEL;
        hmp[((size_t)b * 8 + q) * D_MODEL + c] = acc;
    }
}

// head: phase B reduce 8 partials into LDS, then out[b][c].  grid (4,16)
__global__ __launch_bounds__(256) void head_kernel(
    const float* __restrict__ hmp, const float* __restrict__ head_w,
    const float* __restrict__ head_b, float* __restrict__ out)
{
    __shared__ float hmr[D_MODEL];
    int tid = threadIdx.x;
    int b = blockIdx.y;
    const float* hp = hmp + (size_t)b * 8 * D_MODEL;
    #pragma unroll
    for (int half = 0; half < 2; ++half) {
        int c = tid + half * 256;
        float acc = 0.f;
        #pragma unroll
        for (int q = 0; q < 8; ++q) acc += hp[q * D_MODEL + c];
        hmr[c] = acc * (1.f / L_SEQ);
    }
    __syncthreads();
    int c = blockIdx.x * 256 + tid;
    if (c >= N_CLASSES) return;
    float acc = head_b[c];
    #pragma unroll 8
    for (int k = 0; k < D_MODEL; ++k)
        acc += hmr[k] * head_w[(size_t)k * N_CLASSES + c];
    out[(size_t)b * N_CLASSES + c] = acc;
}

// ---------------------------------------------------------------------------
extern "C" void kernel_launch(void* const* d_in, const int* in_sizes, int n_in,
                              void* d_out, int out_size, void* d_ws, size_t ws_size,
                              hipStream_t stream) {
    const float* x         = (const float*)d_in[0];
    const float* patch_w   = (const float*)d_in[1];
    const float* patch_b   = (const float*)d_in[2];
    const float* norm_w    = (const float*)d_in[3];
    const float* in_proj_w = (const float*)d_in[4];
    const float* conv_w    = (const float*)d_in[5];
    const float* x_proj_w  = (const float*)d_in[6];
    const float* dt_proj_w = (const float*)d_in[7];
    const float* dt_proj_b = (const float*)d_in[8];
    const float* A_log     = (const float*)d_in[9];
    const float* Dv        = (const float*)d_in[10];
    const float* out_proj_w= (const float*)d_in[11];
    const float* head_w    = (const float*)d_in[12];
    const float* head_b    = (const float*)d_in[13];
    float* out = (float*)d_out;

    char* base = (char*)d_ws;
    size_t off = 0;
    auto alloc = [&](size_t bytes) -> void* {
        void* p = base + off;
        off += (bytes + 255) & ~(size_t)255;
        return p;
    };
    float* pos   = (float*)alloc((size_t)L_SEQ * D_MODEL * 4);
    bf16*  pwT   = (bf16*) alloc((size_t)D_MODEL * PATCH_DIM * 2);
    bf16*  inT   = (bf16*) alloc((size_t)N_LAYERS * 2 * D_INNER * D_MODEL * 2);
    bf16*  WtBig = (bf16*) alloc((size_t)N_LAYERS * NBIG * D_INNER * 2);
    bf16*  opT   = (bf16*) alloc((size_t)N_LAYERS * D_MODEL * D_INNER * 2);
    float* cwT   = (float*)alloc((size_t)N_LAYERS * 4 * D_INNER * 4);
    float* h     = (float*)alloc((size_t)ROWS * D_MODEL * 4);
    bf16*  xn    = (bf16*) alloc((size_t)ROWSP * D_MODEL * 2);
    char*  reg0  = (char*) alloc((size_t)ROWSP * 2 * D_INNER * 2);
    bf16*  p     = (bf16*)reg0;
    bf16*  xr    = (bf16*)reg0;
    bf16*  xs    = (bf16*) alloc((size_t)ROWSP * D_INNER * 2);
    unsigned int* ug = (unsigned int*)alloc((size_t)ROWSP * D_INNER * 4);
    float* delta = (float*)alloc((size_t)ROWSP * D_INNER * 4);
    float* bcb   = (float*)alloc((size_t)ROWS * 32 * 4);
    bf16*  yb    = (bf16*) alloc((size_t)ROWSP * D_INNER * 2);
    float* hmp   = (float*)alloc((size_t)BATCH * 8 * D_MODEL * 4);

    // ---- prologue + batched weight prep ----
    patchify_kernel<<<ROWS, 256, 0, stream>>>(x, p);
    smallprep_kernel<<<968, 256, 0, stream>>>(pos, x_proj_w, WtBig, conv_w, cwT);
    transpose_bf16_kernel<<<dim3(16, 24), 256, 0, stream>>>(
        patch_w, pwT, PATCH_DIM, D_MODEL, D_MODEL, 0, 0);
    transpose_bf16_kernel<<<dim3(64, 16, N_LAYERS), 256, 0, stream>>>(
        in_proj_w, inT, D_MODEL, 2 * D_INNER, 2 * D_INNER,
        (size_t)D_MODEL * 2 * D_INNER, (size_t)2 * D_INNER * D_MODEL);
    transpose_bf16_kernel<<<dim3(16, 32, N_LAYERS), 256, 0, stream>>>(
        out_proj_w, opT, D_INNER, D_MODEL, D_MODEL,
        (size_t)D_INNER * D_MODEL, (size_t)D_MODEL * D_INNER);
    wcomb_kernel<<<dim3(32, 32, N_LAYERS), 256, 0, stream>>>(
        x_proj_w, dt_proj_w, WtBig);

    // h = p @ patch_w + patch_b + pos   (BM=32, grid 400)
    gemm64<2, 32><<<(D_MODEL / 128) * (ROWSP / 32), 256, 0, stream>>>(
        p, pwT, PATCH_DIM, D_MODEL / 128, D_MODEL, ROWS, D_MODEL,
        h, nullptr, patch_b, pos, nullptr);

    for (int layer = 0; layer < N_LAYERS; ++layer) {
        rmsnorm_kernel<<<ROWS / 4, 256, 0, stream>>>(h, norm_w + layer * D_MODEL, xn);

        // xr = xn @ in_proj  [3136,2048] bf16   (BM=64, grid 800)
        gemm64<0, 64><<<(2 * D_INNER / 128) * (ROWSP / 64), 256, 0, stream>>>(
            xn, inT + (size_t)layer * 2 * D_INNER * D_MODEL,
            D_MODEL, 2 * D_INNER / 128, 2 * D_INNER, ROWS, 2 * D_INNER,
            nullptr, xr, nullptr, nullptr, nullptr);

        conv_silu_kernel<<<(ROWS * 128 + 255) / 256, 256, 0, stream>>>(
            xr, cwT + (size_t)layer * 4 * D_INNER, xs, ug);

        // delta = softplus(xs @ W_comb + dtb); bc interleaved   (BM=64, grid 450)
        gemm64<4, 64><<<(NBIG / 128) * (ROWSP / 64), 256, 0, stream>>>(
            xs, WtBig + (size_t)layer * NBIG * D_INNER,
            D_INNER, NBIG / 128, 1056, ROWS, 0,
            delta, nullptr, dt_proj_b + (size_t)layer * D_INNER, nullptr, bcb);

        // state-parallel scan + gate -> yb bf16  (grid 256)
        scan_sp_kernel<<<BATCH * (D_INNER / 64), 256, 0, stream>>>(
            ug, delta, bcb,
            A_log + (size_t)layer * D_INNER * D_STATE,
            Dv + (size_t)layer * D_INNER, yb);

        // h += yb @ out_proj   (BM=32, grid 400)
        gemm64<3, 32><<<(D_MODEL / 128) * (ROWSP / 32), 256, 0, stream>>>(
            yb, opT + (size_t)layer * D_MODEL * D_INNER,
            D_INNER, D_MODEL / 128, D_MODEL, ROWS, D_MODEL,
            h, nullptr, nullptr, nullptr, nullptr);
    }

    mean_part_kernel<<<dim3(8, BATCH), 256, 0, stream>>>(h, hmp);
    head_kernel<<<dim3(4, BATCH), 256, 0, stream>>>(hmp, head_w, head_b, out);
}